// Round 1
// baseline (1774.681 us; speedup 1.0000x reference)
//
#include <hip/hip_runtime.h>

#define N_NODES 50000
#define E_EDGES 200000
#define R_REL 3
#define D_IN 128
#define D_HID 128
#define D_OUT 64

// ---------------- degree / norm kernels ----------------

__global__ __launch_bounds__(256) void k_zero_i32(int* __restrict__ p, int n) {
    int i = blockIdx.x * 256 + threadIdx.x;
    if (i < n) p[i] = 0;
}

__global__ __launch_bounds__(256) void k_count_deg(const int* __restrict__ src,
                                                   const int* __restrict__ dst,
                                                   int* __restrict__ deg_out,
                                                   int* __restrict__ deg_in) {
    int i = blockIdx.x * 256 + threadIdx.x;  // over R*E
    if (i >= R_REL * E_EDGES) return;
    int r = i / E_EDGES;
    int s = src[i];
    int d = dst[i];
    atomicAdd(&deg_out[r * N_NODES + s], 1);
    atomicAdd(&deg_in[r * N_NODES + d], 1);
}

// in-place: int degree -> float rsqrt(max(deg,1))
__global__ __launch_bounds__(256) void k_norm(const int* __restrict__ di,
                                              float* __restrict__ fo, int n) {
    int i = blockIdx.x * 256 + threadIdx.x;
    if (i >= n) return;
    int d = di[i];
    float df = (float)(d > 1 ? d : 1);
    fo[i] = rsqrtf(df);
}

// ---------------- bias init / relu ----------------

__global__ __launch_bounds__(256) void k_init_h1(const float* __restrict__ b1,
                                                 float* __restrict__ h1) {
    int i = blockIdx.x * 256 + threadIdx.x;
    if (i >= N_NODES * D_HID) return;
    int f = i & (D_HID - 1);
    h1[i] = b1[f] + b1[D_HID + f] + b1[2 * D_HID + f];
}

__global__ __launch_bounds__(256) void k_init_h2(const float* __restrict__ b2,
                                                 float* __restrict__ h2) {
    int i = blockIdx.x * 256 + threadIdx.x;
    if (i >= N_NODES * D_OUT) return;
    int f = i & (D_OUT - 1);
    h2[i] = b2[f] + b2[D_OUT + f] + b2[2 * D_OUT + f];
}

__global__ __launch_bounds__(256) void k_relu(float* __restrict__ h, int n) {
    int i = blockIdx.x * 256 + threadIdx.x;
    if (i < n) h[i] = fmaxf(h[i], 0.0f);
}

// ---------------- GEMM: C[M,128] = A[M,128] @ W[128,128] ----------------
// BM=64, BN=128, BK=32; 256 threads; thread tile 2 rows x 16 cols (4 float4, 32-col stride)
__global__ __launch_bounds__(256) void k_gemm_n128(const float* __restrict__ A,
                                                   const float* __restrict__ W,
                                                   float* __restrict__ C, int M) {
    __shared__ float sA[64][33];
    __shared__ float sW[32][128];
    int t = threadIdx.x;
    int row0 = blockIdx.x * 64;
    int rgrp = t >> 3;   // 0..31
    int cgrp = t & 7;    // 0..7
    float4 acc0[4], acc1[4];
#pragma unroll
    for (int j = 0; j < 4; j++) {
        acc0[j] = make_float4(0.f, 0.f, 0.f, 0.f);
        acc1[j] = make_float4(0.f, 0.f, 0.f, 0.f);
    }
    for (int k0 = 0; k0 < 128; k0 += 32) {
        // load A chunk (64x32): 512 float4s
#pragma unroll
        for (int i = 0; i < 2; i++) {
            int idx = t + i * 256;     // 0..511
            int row = idx >> 3;
            int kg = idx & 7;
            float4 v = make_float4(0.f, 0.f, 0.f, 0.f);
            int gr = row0 + row;
            if (gr < M) v = *(const float4*)&A[gr * 128 + k0 + kg * 4];
            sA[row][kg * 4 + 0] = v.x;
            sA[row][kg * 4 + 1] = v.y;
            sA[row][kg * 4 + 2] = v.z;
            sA[row][kg * 4 + 3] = v.w;
        }
        // load W chunk (32x128): 1024 float4s
#pragma unroll
        for (int i = 0; i < 4; i++) {
            int idx = t + i * 256;     // 0..1023
            int row = idx >> 5;        // 0..31
            int cg = idx & 31;
            *(float4*)&sW[row][cg * 4] = *(const float4*)&W[(k0 + row) * 128 + cg * 4];
        }
        __syncthreads();
#pragma unroll
        for (int k = 0; k < 32; k++) {
            float xa = sA[rgrp * 2 + 0][k];
            float xb = sA[rgrp * 2 + 1][k];
#pragma unroll
            for (int j = 0; j < 4; j++) {
                float4 w = *(const float4*)&sW[k][cgrp * 4 + 32 * j];
                acc0[j].x += xa * w.x; acc0[j].y += xa * w.y;
                acc0[j].z += xa * w.z; acc0[j].w += xa * w.w;
                acc1[j].x += xb * w.x; acc1[j].y += xb * w.y;
                acc1[j].z += xb * w.z; acc1[j].w += xb * w.w;
            }
        }
        __syncthreads();
    }
    int gr0 = row0 + rgrp * 2;
    if (gr0 < M) {
#pragma unroll
        for (int j = 0; j < 4; j++)
            *(float4*)&C[gr0 * 128 + cgrp * 4 + 32 * j] = acc0[j];
    }
    if (gr0 + 1 < M) {
#pragma unroll
        for (int j = 0; j < 4; j++)
            *(float4*)&C[(gr0 + 1) * 128 + cgrp * 4 + 32 * j] = acc1[j];
    }
}

// ---------------- GEMM: C[M,64] = A[M,128] @ W[128,64] ----------------
// BM=64, BN=64, BK=32; 256 threads; thread tile 1 row x 16 cols
__global__ __launch_bounds__(256) void k_gemm_n64(const float* __restrict__ A,
                                                  const float* __restrict__ W,
                                                  float* __restrict__ C, int M) {
    __shared__ float sA[64][33];
    __shared__ float sW[32][64];
    int t = threadIdx.x;
    int row0 = blockIdx.x * 64;
    int row = t >> 2;    // 0..63
    int cgrp = t & 3;    // 0..3
    float4 acc[4];
#pragma unroll
    for (int j = 0; j < 4; j++) acc[j] = make_float4(0.f, 0.f, 0.f, 0.f);
    for (int k0 = 0; k0 < 128; k0 += 32) {
#pragma unroll
        for (int i = 0; i < 2; i++) {
            int idx = t + i * 256;
            int arow = idx >> 3;
            int kg = idx & 7;
            float4 v = make_float4(0.f, 0.f, 0.f, 0.f);
            int gr = row0 + arow;
            if (gr < M) v = *(const float4*)&A[gr * 128 + k0 + kg * 4];
            sA[arow][kg * 4 + 0] = v.x;
            sA[arow][kg * 4 + 1] = v.y;
            sA[arow][kg * 4 + 2] = v.z;
            sA[arow][kg * 4 + 3] = v.w;
        }
        // W chunk 32x64 = 512 float4
#pragma unroll
        for (int i = 0; i < 2; i++) {
            int idx = t + i * 256;     // 0..511
            int wrow = idx >> 4;       // 0..31
            int cg = idx & 15;
            *(float4*)&sW[wrow][cg * 4] = *(const float4*)&W[(k0 + wrow) * 64 + cg * 4];
        }
        __syncthreads();
#pragma unroll
        for (int k = 0; k < 32; k++) {
            float xa = sA[row][k];
#pragma unroll
            for (int j = 0; j < 4; j++) {
                float4 w = *(const float4*)&sW[k][cgrp * 4 + 16 * j];
                acc[j].x += xa * w.x; acc[j].y += xa * w.y;
                acc[j].z += xa * w.z; acc[j].w += xa * w.w;
            }
        }
        __syncthreads();
    }
    int gr = row0 + row;
    if (gr < M) {
#pragma unroll
        for (int j = 0; j < 4; j++)
            *(float4*)&C[gr * 64 + cgrp * 4 + 16 * j] = acc[j];
    }
}

// ---------------- edge scatter (atomic) ----------------
// 32 lanes per edge, 128 feats
__global__ __launch_bounds__(256) void k_scatter128(const int* __restrict__ src,
                                                    const int* __restrict__ dst,
                                                    const float* __restrict__ nsrc,
                                                    const float* __restrict__ ndst,
                                                    const float* __restrict__ xw,
                                                    float* __restrict__ h) {
    int tid = blockIdx.x * 256 + threadIdx.x;
    int e = tid >> 5;
    if (e >= E_EDGES) return;
    int lane = tid & 31;
    int s = src[e], d = dst[e];
    float c = nsrc[s] * ndst[d];
    float4 v = *(const float4*)&xw[s * 128 + lane * 4];
    float* hp = &h[d * 128 + lane * 4];
    atomicAdd(hp + 0, v.x * c);
    atomicAdd(hp + 1, v.y * c);
    atomicAdd(hp + 2, v.z * c);
    atomicAdd(hp + 3, v.w * c);
}

// 16 lanes per edge, 64 feats
__global__ __launch_bounds__(256) void k_scatter64(const int* __restrict__ src,
                                                   const int* __restrict__ dst,
                                                   const float* __restrict__ nsrc,
                                                   const float* __restrict__ ndst,
                                                   const float* __restrict__ xw,
                                                   float* __restrict__ h) {
    int tid = blockIdx.x * 256 + threadIdx.x;
    int e = tid >> 4;
    if (e >= E_EDGES) return;
    int lane = tid & 15;
    int s = src[e], d = dst[e];
    float c = nsrc[s] * ndst[d];
    float4 v = *(const float4*)&xw[s * 64 + lane * 4];
    float* hp = &h[d * 64 + lane * 4];
    atomicAdd(hp + 0, v.x * c);
    atomicAdd(hp + 1, v.y * c);
    atomicAdd(hp + 2, v.z * c);
    atomicAdd(hp + 3, v.w * c);
}

// ---------------- predictor ----------------
// 16 lanes per pair; pairs [0,E) = pos (src0/dst0), [E,2E) = neg
__global__ __launch_bounds__(256) void k_predict(const int* __restrict__ sa,
                                                 const int* __restrict__ sb,
                                                 const int* __restrict__ na,
                                                 const int* __restrict__ nb,
                                                 const float* __restrict__ h2,
                                                 float* __restrict__ out) {
    int tid = blockIdx.x * 256 + threadIdx.x;
    int p = tid >> 4;
    if (p >= 2 * E_EDGES) return;
    int lane = tid & 15;
    int ia, ib;
    if (p < E_EDGES) { ia = sa[p]; ib = sb[p]; }
    else             { ia = na[p - E_EDGES]; ib = nb[p - E_EDGES]; }
    float4 va = *(const float4*)&h2[ia * 64 + lane * 4];
    float4 vb = *(const float4*)&h2[ib * 64 + lane * 4];
    float d = va.x * vb.x + va.y * vb.y + va.z * vb.z + va.w * vb.w;
    d += __shfl_xor(d, 1);
    d += __shfl_xor(d, 2);
    d += __shfl_xor(d, 4);
    d += __shfl_xor(d, 8);
    if (lane == 0) out[p] = d;
}

// ---------------- launch ----------------

extern "C" void kernel_launch(void* const* d_in, const int* in_sizes, int n_in,
                              void* d_out, int out_size, void* d_ws, size_t ws_size,
                              hipStream_t stream) {
    (void)in_sizes; (void)n_in; (void)out_size; (void)ws_size;
    const float* x       = (const float*)d_in[0];
    const int*   src     = (const int*)d_in[1];
    const int*   dst     = (const int*)d_in[2];
    const int*   neg_src = (const int*)d_in[3];
    const int*   neg_dst = (const int*)d_in[4];
    const float* W1      = (const float*)d_in[5];
    const float* b1      = (const float*)d_in[6];
    const float* W2      = (const float*)d_in[7];
    const float* b2      = (const float*)d_in[8];
    float* out = (float*)d_out;
    float* ws  = (float*)d_ws;

    float* norm_out = ws;                      // [3*50000]
    float* norm_in  = ws + 150000;             // [3*50000]
    float* h1       = ws + 300000;             // [50000*128]
    float* h2       = ws + 6700000;            // [50000*64]
    float* xw       = ws + 9900000;            // [50000*128] (reused layer2)
    int* deg_i      = (int*)ws;                // aliases norm_out+norm_in (300000 ints)

    const int NB_NODE128 = (N_NODES * D_HID + 255) / 256;   // 25000
    const int NB_NODE64  = (N_NODES * D_OUT + 255) / 256;   // 12500
    const int NB_GEMM    = (N_NODES + 63) / 64;             // 782

    k_zero_i32<<<(300000 + 255) / 256, 256, 0, stream>>>(deg_i, 300000);
    k_count_deg<<<(R_REL * E_EDGES + 255) / 256, 256, 0, stream>>>(
        src, dst, deg_i, deg_i + R_REL * N_NODES);
    k_norm<<<(300000 + 255) / 256, 256, 0, stream>>>(deg_i, ws, 300000);

    // ---- layer 1 ----
    k_init_h1<<<NB_NODE128, 256, 0, stream>>>(b1, h1);
    for (int r = 0; r < R_REL; r++) {
        k_gemm_n128<<<NB_GEMM, 256, 0, stream>>>(x, W1 + r * D_IN * D_HID, xw, N_NODES);
        k_scatter128<<<(E_EDGES * 32 + 255) / 256, 256, 0, stream>>>(
            src + r * E_EDGES, dst + r * E_EDGES,
            norm_out + r * N_NODES, norm_in + r * N_NODES, xw, h1);
    }
    k_relu<<<NB_NODE128, 256, 0, stream>>>(h1, N_NODES * D_HID);

    // ---- layer 2 ----
    k_init_h2<<<NB_NODE64, 256, 0, stream>>>(b2, h2);
    for (int r = 0; r < R_REL; r++) {
        k_gemm_n64<<<NB_GEMM, 256, 0, stream>>>(h1, W2 + r * D_HID * D_OUT, xw, N_NODES);
        k_scatter64<<<(E_EDGES * 16 + 255) / 256, 256, 0, stream>>>(
            src + r * E_EDGES, dst + r * E_EDGES,
            norm_out + r * N_NODES, norm_in + r * N_NODES, xw, h2);
    }

    // ---- predictor ----
    k_predict<<<(2 * E_EDGES * 16 + 255) / 256, 256, 0, stream>>>(
        src, dst, neg_src, neg_dst, h2, out);
}

// Round 2
// 497.911 us; speedup vs baseline: 3.5643x; 3.5643x over previous
//
#include <hip/hip_runtime.h>

#define N_NODES 50000
#define E_EDGES 200000
#define R_REL 3
#define D_IN 128
#define D_HID 128
#define D_OUT 64
#define N_SCAN (R_REL * N_NODES)          // 150000
#define SCAN_NB ((N_SCAN + 1023) / 1024)  // 147

// ---------------- degree / norm ----------------

__global__ __launch_bounds__(256) void k_zero_i32(int* __restrict__ p, int n) {
    int i = blockIdx.x * 256 + threadIdx.x;
    if (i < n) p[i] = 0;
}

__global__ __launch_bounds__(256) void k_count_deg(const int* __restrict__ src,
                                                   const int* __restrict__ dst,
                                                   int* __restrict__ deg_out,
                                                   int* __restrict__ deg_in) {
    int i = blockIdx.x * 256 + threadIdx.x;  // over R*E
    if (i >= R_REL * E_EDGES) return;
    int r = i / E_EDGES;
    atomicAdd(&deg_out[r * N_NODES + src[i]], 1);
    atomicAdd(&deg_in[r * N_NODES + dst[i]], 1);
}

// in-place int degree -> float rsqrt(max(deg,1))
__global__ __launch_bounds__(256) void k_norm(const int* __restrict__ di,
                                              float* __restrict__ fo, int n) {
    int i = blockIdx.x * 256 + threadIdx.x;
    if (i >= n) return;
    int d = di[i];
    fo[i] = rsqrtf((float)(d > 1 ? d : 1));
}

// ---------------- exclusive scan over deg_in (150000 ints) ----------------

__global__ __launch_bounds__(256) void k_scan1(const int* __restrict__ deg,
                                               int* __restrict__ partials) {
    __shared__ int sd[256];
    int t = threadIdx.x;
    int base = blockIdx.x * 1024 + t * 4;
    int s = 0;
#pragma unroll
    for (int k = 0; k < 4; k++) {
        int i = base + k;
        if (i < N_SCAN) s += deg[i];
    }
    sd[t] = s;
    __syncthreads();
    for (int off = 128; off > 0; off >>= 1) {
        if (t < off) sd[t] += sd[t + off];
        __syncthreads();
    }
    if (t == 0) partials[blockIdx.x] = sd[0];
}

__global__ __launch_bounds__(256) void k_scan2(int* __restrict__ partials,
                                               int* __restrict__ csr_off) {
    __shared__ int sd[256];
    int t = threadIdx.x;
    int v = (t < SCAN_NB) ? partials[t] : 0;
    sd[t] = v;
    __syncthreads();
    for (int off = 1; off < 256; off <<= 1) {
        int a = (t >= off) ? sd[t - off] : 0;
        __syncthreads();
        sd[t] += a;
        __syncthreads();
    }
    partials[t] = sd[t] - v;  // exclusive
    if (t == 255) csr_off[N_SCAN] = sd[255];  // total (= R*E)
}

__global__ __launch_bounds__(256) void k_scan3(const int* __restrict__ deg,
                                               const int* __restrict__ partials,
                                               int* __restrict__ csr_off,
                                               int* __restrict__ cursor) {
    __shared__ int sd[256];
    int t = threadIdx.x;
    int base = blockIdx.x * 1024 + t * 4;
    int v[4];
    int tsum = 0;
#pragma unroll
    for (int k = 0; k < 4; k++) {
        int i = base + k;
        v[k] = (i < N_SCAN) ? deg[i] : 0;
        tsum += v[k];
    }
    sd[t] = tsum;
    __syncthreads();
    for (int off = 1; off < 256; off <<= 1) {
        int a = (t >= off) ? sd[t - off] : 0;
        __syncthreads();
        sd[t] += a;
        __syncthreads();
    }
    int run = partials[blockIdx.x] + sd[t] - tsum;
#pragma unroll
    for (int k = 0; k < 4; k++) {
        int i = base + k;
        if (i < N_SCAN) {
            csr_off[i] = run;
            cursor[i] = run;
            run += v[k];
        }
    }
}

// ---------------- edge binning ----------------

__global__ __launch_bounds__(256) void k_bin(const int* __restrict__ src,
                                             const int* __restrict__ dst,
                                             const float* __restrict__ norm_out,
                                             int* __restrict__ cursor,
                                             int* __restrict__ csr_src,
                                             float* __restrict__ csr_coef) {
    int i = blockIdx.x * 256 + threadIdx.x;  // over R*E
    if (i >= R_REL * E_EDGES) return;
    int r = i / E_EDGES;
    int s = src[i];
    int d = dst[i];
    int pos = atomicAdd(&cursor[r * N_NODES + d], 1);
    csr_src[pos] = s;
    csr_coef[pos] = norm_out[r * N_NODES + s];
}

// ---------------- bias init / relu ----------------

__global__ __launch_bounds__(256) void k_init_h1(const float* __restrict__ b1,
                                                 float* __restrict__ h1) {
    int i = blockIdx.x * 256 + threadIdx.x;
    if (i >= N_NODES * D_HID) return;
    int f = i & (D_HID - 1);
    h1[i] = b1[f] + b1[D_HID + f] + b1[2 * D_HID + f];
}

__global__ __launch_bounds__(256) void k_init_h2(const float* __restrict__ b2,
                                                 float* __restrict__ h2) {
    int i = blockIdx.x * 256 + threadIdx.x;
    if (i >= N_NODES * D_OUT) return;
    int f = i & (D_OUT - 1);
    h2[i] = b2[f] + b2[D_OUT + f] + b2[2 * D_OUT + f];
}

__global__ __launch_bounds__(256) void k_relu(float* __restrict__ h, int n) {
    int i = blockIdx.x * 256 + threadIdx.x;
    if (i < n) h[i] = fmaxf(h[i], 0.0f);
}

// ---------------- CSR aggregation (no atomics) ----------------
// One wave (64 lanes) per dst node; 128 feats = float2/lane. agg = norm_in * sum(coef * x[src]).
__global__ __launch_bounds__(256) void k_agg128(const int* __restrict__ csr_off,
                                                const int* __restrict__ csr_src,
                                                const float* __restrict__ csr_coef,
                                                const float* __restrict__ norm_in,
                                                const float* __restrict__ x,
                                                float* __restrict__ agg) {
    int w = (blockIdx.x * 256 + threadIdx.x) >> 6;
    if (w >= N_NODES) return;
    int lane = threadIdx.x & 63;
    int beg = csr_off[w], end = csr_off[w + 1];
    float ax = 0.f, ay = 0.f;
    for (int j = beg; j < end; j++) {
        int s = csr_src[j];
        float c = csr_coef[j];
        float2 v = *(const float2*)&x[s * 128 + lane * 2];
        ax += c * v.x;
        ay += c * v.y;
    }
    float ni = norm_in[w];
    float2 o;
    o.x = ax * ni;
    o.y = ay * ni;
    *(float2*)&agg[w * 128 + lane * 2] = o;
}

// One wave per dst node; 64 feats = 1 float/lane. h2 += norm_in * sum(coef * xw2[src]).
__global__ __launch_bounds__(256) void k_agg64(const int* __restrict__ csr_off,
                                               const int* __restrict__ csr_src,
                                               const float* __restrict__ csr_coef,
                                               const float* __restrict__ norm_in,
                                               const float* __restrict__ xw2,
                                               float* __restrict__ h2) {
    int w = (blockIdx.x * 256 + threadIdx.x) >> 6;
    if (w >= N_NODES) return;
    int lane = threadIdx.x & 63;
    int beg = csr_off[w], end = csr_off[w + 1];
    float a = 0.f;
    for (int j = beg; j < end; j++) {
        int s = csr_src[j];
        float c = csr_coef[j];
        a += c * xw2[s * 64 + lane];
    }
    h2[w * 64 + lane] += norm_in[w] * a;
}

// ---------------- GEMM: C[M,128] += A[M,128] @ W[128,128] ----------------
__global__ __launch_bounds__(256) void k_gemm_n128_acc(const float* __restrict__ A,
                                                       const float* __restrict__ W,
                                                       float* __restrict__ C, int M) {
    __shared__ float sA[64][33];
    __shared__ float sW[32][128];
    int t = threadIdx.x;
    int row0 = blockIdx.x * 64;
    int rgrp = t >> 3;   // 0..31
    int cgrp = t & 7;    // 0..7
    float4 acc0[4], acc1[4];
#pragma unroll
    for (int j = 0; j < 4; j++) {
        acc0[j] = make_float4(0.f, 0.f, 0.f, 0.f);
        acc1[j] = make_float4(0.f, 0.f, 0.f, 0.f);
    }
    for (int k0 = 0; k0 < 128; k0 += 32) {
#pragma unroll
        for (int i = 0; i < 2; i++) {
            int idx = t + i * 256;
            int row = idx >> 3;
            int kg = idx & 7;
            float4 v = make_float4(0.f, 0.f, 0.f, 0.f);
            int gr = row0 + row;
            if (gr < M) v = *(const float4*)&A[gr * 128 + k0 + kg * 4];
            sA[row][kg * 4 + 0] = v.x;
            sA[row][kg * 4 + 1] = v.y;
            sA[row][kg * 4 + 2] = v.z;
            sA[row][kg * 4 + 3] = v.w;
        }
#pragma unroll
        for (int i = 0; i < 4; i++) {
            int idx = t + i * 256;
            int row = idx >> 5;
            int cg = idx & 31;
            *(float4*)&sW[row][cg * 4] = *(const float4*)&W[(k0 + row) * 128 + cg * 4];
        }
        __syncthreads();
#pragma unroll
        for (int k = 0; k < 32; k++) {
            float xa = sA[rgrp * 2 + 0][k];
            float xb = sA[rgrp * 2 + 1][k];
#pragma unroll
            for (int j = 0; j < 4; j++) {
                float4 w = *(const float4*)&sW[k][cgrp * 4 + 32 * j];
                acc0[j].x += xa * w.x; acc0[j].y += xa * w.y;
                acc0[j].z += xa * w.z; acc0[j].w += xa * w.w;
                acc1[j].x += xb * w.x; acc1[j].y += xb * w.y;
                acc1[j].z += xb * w.z; acc1[j].w += xb * w.w;
            }
        }
        __syncthreads();
    }
    int gr0 = row0 + rgrp * 2;
    if (gr0 < M) {
#pragma unroll
        for (int j = 0; j < 4; j++) {
            float4 c = *(const float4*)&C[gr0 * 128 + cgrp * 4 + 32 * j];
            c.x += acc0[j].x; c.y += acc0[j].y; c.z += acc0[j].z; c.w += acc0[j].w;
            *(float4*)&C[gr0 * 128 + cgrp * 4 + 32 * j] = c;
        }
    }
    if (gr0 + 1 < M) {
#pragma unroll
        for (int j = 0; j < 4; j++) {
            float4 c = *(const float4*)&C[(gr0 + 1) * 128 + cgrp * 4 + 32 * j];
            c.x += acc1[j].x; c.y += acc1[j].y; c.z += acc1[j].z; c.w += acc1[j].w;
            *(float4*)&C[(gr0 + 1) * 128 + cgrp * 4 + 32 * j] = c;
        }
    }
}

// ---------------- GEMM: C[M,64] = A[M,128] @ W[128,64] ----------------
__global__ __launch_bounds__(256) void k_gemm_n64(const float* __restrict__ A,
                                                  const float* __restrict__ W,
                                                  float* __restrict__ C, int M) {
    __shared__ float sA[64][33];
    __shared__ float sW[32][64];
    int t = threadIdx.x;
    int row0 = blockIdx.x * 64;
    int row = t >> 2;
    int cgrp = t & 3;
    float4 acc[4];
#pragma unroll
    for (int j = 0; j < 4; j++) acc[j] = make_float4(0.f, 0.f, 0.f, 0.f);
    for (int k0 = 0; k0 < 128; k0 += 32) {
#pragma unroll
        for (int i = 0; i < 2; i++) {
            int idx = t + i * 256;
            int arow = idx >> 3;
            int kg = idx & 7;
            float4 v = make_float4(0.f, 0.f, 0.f, 0.f);
            int gr = row0 + arow;
            if (gr < M) v = *(const float4*)&A[gr * 128 + k0 + kg * 4];
            sA[arow][kg * 4 + 0] = v.x;
            sA[arow][kg * 4 + 1] = v.y;
            sA[arow][kg * 4 + 2] = v.z;
            sA[arow][kg * 4 + 3] = v.w;
        }
#pragma unroll
        for (int i = 0; i < 2; i++) {
            int idx = t + i * 256;
            int wrow = idx >> 4;
            int cg = idx & 15;
            *(float4*)&sW[wrow][cg * 4] = *(const float4*)&W[(k0 + wrow) * 64 + cg * 4];
        }
        __syncthreads();
#pragma unroll
        for (int k = 0; k < 32; k++) {
            float xa = sA[row][k];
#pragma unroll
            for (int j = 0; j < 4; j++) {
                float4 w = *(const float4*)&sW[k][cgrp * 4 + 16 * j];
                acc[j].x += xa * w.x; acc[j].y += xa * w.y;
                acc[j].z += xa * w.z; acc[j].w += xa * w.w;
            }
        }
        __syncthreads();
    }
    int gr = row0 + row;
    if (gr < M) {
#pragma unroll
        for (int j = 0; j < 4; j++)
            *(float4*)&C[gr * 64 + cgrp * 4 + 16 * j] = acc[j];
    }
}

// ---------------- predictor ----------------
__global__ __launch_bounds__(256) void k_predict(const int* __restrict__ sa,
                                                 const int* __restrict__ sb,
                                                 const int* __restrict__ na,
                                                 const int* __restrict__ nb,
                                                 const float* __restrict__ h2,
                                                 float* __restrict__ out) {
    int tid = blockIdx.x * 256 + threadIdx.x;
    int p = tid >> 4;
    if (p >= 2 * E_EDGES) return;
    int lane = tid & 15;
    int ia, ib;
    if (p < E_EDGES) { ia = sa[p]; ib = sb[p]; }
    else             { ia = na[p - E_EDGES]; ib = nb[p - E_EDGES]; }
    float4 va = *(const float4*)&h2[ia * 64 + lane * 4];
    float4 vb = *(const float4*)&h2[ib * 64 + lane * 4];
    float d = va.x * vb.x + va.y * vb.y + va.z * vb.z + va.w * vb.w;
    d += __shfl_xor(d, 1);
    d += __shfl_xor(d, 2);
    d += __shfl_xor(d, 4);
    d += __shfl_xor(d, 8);
    if (lane == 0) out[p] = d;
}

// ---------------- launch ----------------

extern "C" void kernel_launch(void* const* d_in, const int* in_sizes, int n_in,
                              void* d_out, int out_size, void* d_ws, size_t ws_size,
                              hipStream_t stream) {
    (void)in_sizes; (void)n_in; (void)out_size; (void)ws_size;
    const float* x       = (const float*)d_in[0];
    const int*   src     = (const int*)d_in[1];
    const int*   dst     = (const int*)d_in[2];
    const int*   neg_src = (const int*)d_in[3];
    const int*   neg_dst = (const int*)d_in[4];
    const float* W1      = (const float*)d_in[5];
    const float* b1      = (const float*)d_in[6];
    const float* W2      = (const float*)d_in[7];
    const float* b2      = (const float*)d_in[8];
    float* out = (float*)d_out;
    float* ws  = (float*)d_ws;

    // layout (floats):
    // 0        : deg/norm  [300000]  (deg_out->norm_out at 0, deg_in->norm_in at 150000)
    // 300000   : csr_off   [150016 ints]
    // 450016   : cursor    [150016 ints]
    // 600032   : partials  [288 ints]
    // 600320   : csr_src   [600000 ints]
    // 1200320  : csr_coef  [600000 floats]
    // 1800320  : bufA      [6400000]  (layer1 agg; layer2: xw2 @ +0 [3.2M], h2 @ +3.2M)
    // 8200320  : h1        [6400000]
    int*   deg_i    = (int*)ws;
    float* norm_out = ws;
    float* norm_in  = ws + N_SCAN;
    int*   csr_off  = (int*)(ws + 300000);
    int*   cursor   = (int*)(ws + 450016);
    int*   partials = (int*)(ws + 600032);
    int*   csr_src  = (int*)(ws + 600320);
    float* csr_coef = ws + 1200320;
    float* bufA     = ws + 1800320;
    float* h1       = ws + 8200320;
    float* agg      = bufA;              // layer 1
    float* xw2      = bufA;              // layer 2
    float* h2       = bufA + 3200000;    // layer 2

    const int NB_RE      = (R_REL * E_EDGES + 255) / 256;
    const int NB_NODE128 = (N_NODES * D_HID + 255) / 256;
    const int NB_NODE64  = (N_NODES * D_OUT + 255) / 256;
    const int NB_GEMM    = (N_NODES + 63) / 64;
    const int NB_WAVE    = (N_NODES * 64 + 255) / 256;  // 1 wave per node

    // degrees + CSR build
    k_zero_i32<<<(2 * N_SCAN + 255) / 256, 256, 0, stream>>>(deg_i, 2 * N_SCAN);
    k_count_deg<<<NB_RE, 256, 0, stream>>>(src, dst, deg_i, deg_i + N_SCAN);
    k_scan1<<<SCAN_NB, 256, 0, stream>>>(deg_i + N_SCAN, partials);
    k_scan2<<<1, 256, 0, stream>>>(partials, csr_off);
    k_scan3<<<SCAN_NB, 256, 0, stream>>>(deg_i + N_SCAN, partials, csr_off, cursor);
    k_norm<<<(2 * N_SCAN + 255) / 256, 256, 0, stream>>>(deg_i, ws, 2 * N_SCAN);
    k_bin<<<NB_RE, 256, 0, stream>>>(src, dst, norm_out, cursor, csr_src, csr_coef);

    // ---- layer 1: aggregate x per relation, then h1 += agg @ W1_r ----
    k_init_h1<<<NB_NODE128, 256, 0, stream>>>(b1, h1);
    for (int r = 0; r < R_REL; r++) {
        k_agg128<<<NB_WAVE, 256, 0, stream>>>(csr_off + r * N_NODES, csr_src, csr_coef,
                                              norm_in + r * N_NODES, x, agg);
        k_gemm_n128_acc<<<NB_GEMM, 256, 0, stream>>>(agg, W1 + r * D_IN * D_HID, h1, N_NODES);
    }
    k_relu<<<NB_NODE128, 256, 0, stream>>>(h1, N_NODES * D_HID);

    // ---- layer 2: xw2 = h1 @ W2_r, then h2 += aggregate(xw2) ----
    k_init_h2<<<NB_NODE64, 256, 0, stream>>>(b2, h2);
    for (int r = 0; r < R_REL; r++) {
        k_gemm_n64<<<NB_GEMM, 256, 0, stream>>>(h1, W2 + r * D_HID * D_OUT, xw2, N_NODES);
        k_agg64<<<NB_WAVE, 256, 0, stream>>>(csr_off + r * N_NODES, csr_src, csr_coef,
                                             norm_in + r * N_NODES, xw2, h2);
    }

    // ---- predictor ----
    k_predict<<<(2 * E_EDGES * 16 + 255) / 256, 256, 0, stream>>>(
        src, dst, neg_src, neg_dst, h2, out);
}

// Round 3
// 440.470 us; speedup vs baseline: 4.0291x; 1.1304x over previous
//
#include <hip/hip_runtime.h>

#define N_NODES 50000
#define E_EDGES 200000
#define R_REL 3
#define D_IN 128
#define D_HID 128
#define D_OUT 64
#define N_SCAN (R_REL * N_NODES)          // 150000
#define SCAN_NB ((N_SCAN + 1023) / 1024)  // 147

// ---------------- degree / norm ----------------

__global__ __launch_bounds__(256) void k_zero_i32(int* __restrict__ p, int n) {
    int i = blockIdx.x * 256 + threadIdx.x;
    if (i < n) p[i] = 0;
}

__global__ __launch_bounds__(256) void k_count_deg(const int* __restrict__ src,
                                                   const int* __restrict__ dst,
                                                   int* __restrict__ deg_out,
                                                   int* __restrict__ deg_in) {
    int i = blockIdx.x * 256 + threadIdx.x;  // over R*E
    if (i >= R_REL * E_EDGES) return;
    int r = i / E_EDGES;
    atomicAdd(&deg_out[r * N_NODES + src[i]], 1);
    atomicAdd(&deg_in[r * N_NODES + dst[i]], 1);
}

__global__ __launch_bounds__(256) void k_norm(const int* __restrict__ di,
                                              float* __restrict__ fo, int n) {
    int i = blockIdx.x * 256 + threadIdx.x;
    if (i >= n) return;
    int d = di[i];
    fo[i] = rsqrtf((float)(d > 1 ? d : 1));
}

// ---------------- exclusive scan over deg_in (150000 ints) ----------------

__global__ __launch_bounds__(256) void k_scan1(const int* __restrict__ deg,
                                               int* __restrict__ partials) {
    __shared__ int sd[256];
    int t = threadIdx.x;
    int base = blockIdx.x * 1024 + t * 4;
    int s = 0;
#pragma unroll
    for (int k = 0; k < 4; k++) {
        int i = base + k;
        if (i < N_SCAN) s += deg[i];
    }
    sd[t] = s;
    __syncthreads();
    for (int off = 128; off > 0; off >>= 1) {
        if (t < off) sd[t] += sd[t + off];
        __syncthreads();
    }
    if (t == 0) partials[blockIdx.x] = sd[0];
}

__global__ __launch_bounds__(256) void k_scan2(int* __restrict__ partials,
                                               int* __restrict__ csr_off) {
    __shared__ int sd[256];
    int t = threadIdx.x;
    int v = (t < SCAN_NB) ? partials[t] : 0;
    sd[t] = v;
    __syncthreads();
    for (int off = 1; off < 256; off <<= 1) {
        int a = (t >= off) ? sd[t - off] : 0;
        __syncthreads();
        sd[t] += a;
        __syncthreads();
    }
    partials[t] = sd[t] - v;  // exclusive
    if (t == 255) csr_off[N_SCAN] = sd[255];
}

__global__ __launch_bounds__(256) void k_scan3(const int* __restrict__ deg,
                                               const int* __restrict__ partials,
                                               int* __restrict__ csr_off,
                                               int* __restrict__ cursor) {
    __shared__ int sd[256];
    int t = threadIdx.x;
    int base = blockIdx.x * 1024 + t * 4;
    int v[4];
    int tsum = 0;
#pragma unroll
    for (int k = 0; k < 4; k++) {
        int i = base + k;
        v[k] = (i < N_SCAN) ? deg[i] : 0;
        tsum += v[k];
    }
    sd[t] = tsum;
    __syncthreads();
    for (int off = 1; off < 256; off <<= 1) {
        int a = (t >= off) ? sd[t - off] : 0;
        __syncthreads();
        sd[t] += a;
        __syncthreads();
    }
    int run = partials[blockIdx.x] + sd[t] - tsum;
#pragma unroll
    for (int k = 0; k < 4; k++) {
        int i = base + k;
        if (i < N_SCAN) {
            csr_off[i] = run;
            cursor[i] = run;
            run += v[k];
        }
    }
}

// ---------------- edge binning ----------------

__global__ __launch_bounds__(256) void k_bin(const int* __restrict__ src,
                                             const int* __restrict__ dst,
                                             const float* __restrict__ norm_out,
                                             int* __restrict__ cursor,
                                             int* __restrict__ csr_src,
                                             float* __restrict__ csr_coef) {
    int i = blockIdx.x * 256 + threadIdx.x;  // over R*E
    if (i >= R_REL * E_EDGES) return;
    int r = i / E_EDGES;
    int s = src[i];
    int d = dst[i];
    int pos = atomicAdd(&cursor[r * N_NODES + d], 1);
    csr_src[pos] = s;
    csr_coef[pos] = norm_out[r * N_NODES + s];
}

// ---------------- CSR aggregation layer 1 ----------------
// One wave per dst node; 128 feats = float2/lane.
__global__ __launch_bounds__(256) void k_agg128(const int* __restrict__ csr_off,
                                                const int* __restrict__ csr_src,
                                                const float* __restrict__ csr_coef,
                                                const float* __restrict__ norm_in,
                                                const float* __restrict__ x,
                                                float* __restrict__ agg) {
    int w = (blockIdx.x * 256 + threadIdx.x) >> 6;
    if (w >= N_NODES) return;
    int lane = threadIdx.x & 63;
    int beg = csr_off[w], end = csr_off[w + 1];
    float ax = 0.f, ay = 0.f;
    for (int j = beg; j < end; j++) {
        int s = csr_src[j];
        float c = csr_coef[j];
        float2 v = *(const float2*)&x[s * 128 + lane * 2];
        ax += c * v.x;
        ay += c * v.y;
    }
    float ni = norm_in[w];
    float2 o;
    o.x = ax * ni;
    o.y = ay * ni;
    *(float2*)&agg[w * 128 + lane * 2] = o;
}

// ---------------- GEMM128: C[M,128] (128x128x32 tile, 4x16/thread) ----------------
// MODE 0: C = acc + bias_sum(b)   (b = b1 [3,128])
// MODE 1: C += acc
// MODE 2: C = relu(C + acc)
template <int MODE>
__global__ __launch_bounds__(256) void k_gemm128(const float* __restrict__ A,
                                                 const float* __restrict__ W,
                                                 const float* __restrict__ bias,
                                                 float* __restrict__ C, int M) {
    __shared__ float sA[128][33];
    __shared__ float sW[32][128];
    int t = threadIdx.x;
    int row0 = blockIdx.x * 128;
    int rgrp = t >> 3;   // 0..31 -> rows rgrp*4 + i
    int cgrp = t & 7;    // cols cgrp*4 + 32*j
    float4 acc[4][4];
#pragma unroll
    for (int i = 0; i < 4; i++)
#pragma unroll
        for (int j = 0; j < 4; j++) acc[i][j] = make_float4(0.f, 0.f, 0.f, 0.f);

    for (int k0 = 0; k0 < 128; k0 += 32) {
#pragma unroll
        for (int i = 0; i < 4; i++) {
            int idx = t + i * 256;       // 0..1023
            int row = idx >> 3;          // 0..127
            int kg = idx & 7;
            float4 v = make_float4(0.f, 0.f, 0.f, 0.f);
            int gr = row0 + row;
            if (gr < M) v = *(const float4*)&A[gr * 128 + k0 + kg * 4];
            sA[row][kg * 4 + 0] = v.x;
            sA[row][kg * 4 + 1] = v.y;
            sA[row][kg * 4 + 2] = v.z;
            sA[row][kg * 4 + 3] = v.w;
        }
#pragma unroll
        for (int i = 0; i < 4; i++) {
            int idx = t + i * 256;       // 0..1023
            int wr = idx >> 5;           // 0..31
            int cg = idx & 31;
            *(float4*)&sW[wr][cg * 4] = *(const float4*)&W[(k0 + wr) * 128 + cg * 4];
        }
        __syncthreads();
#pragma unroll
        for (int k = 0; k < 32; k++) {
            float a0 = sA[rgrp * 4 + 0][k];
            float a1 = sA[rgrp * 4 + 1][k];
            float a2 = sA[rgrp * 4 + 2][k];
            float a3 = sA[rgrp * 4 + 3][k];
#pragma unroll
            for (int j = 0; j < 4; j++) {
                float4 w = *(const float4*)&sW[k][cgrp * 4 + 32 * j];
                acc[0][j].x += a0 * w.x; acc[0][j].y += a0 * w.y; acc[0][j].z += a0 * w.z; acc[0][j].w += a0 * w.w;
                acc[1][j].x += a1 * w.x; acc[1][j].y += a1 * w.y; acc[1][j].z += a1 * w.z; acc[1][j].w += a1 * w.w;
                acc[2][j].x += a2 * w.x; acc[2][j].y += a2 * w.y; acc[2][j].z += a2 * w.z; acc[2][j].w += a2 * w.w;
                acc[3][j].x += a3 * w.x; acc[3][j].y += a3 * w.y; acc[3][j].z += a3 * w.z; acc[3][j].w += a3 * w.w;
            }
        }
        __syncthreads();
    }
#pragma unroll
    for (int i = 0; i < 4; i++) {
        int gr = row0 + rgrp * 4 + i;
        if (gr >= M) continue;
#pragma unroll
        for (int j = 0; j < 4; j++) {
            int col = cgrp * 4 + 32 * j;
            float4 v = acc[i][j];
            if (MODE == 0) {
                v.x += bias[col + 0] + bias[128 + col + 0] + bias[256 + col + 0];
                v.y += bias[col + 1] + bias[128 + col + 1] + bias[256 + col + 1];
                v.z += bias[col + 2] + bias[128 + col + 2] + bias[256 + col + 2];
                v.w += bias[col + 3] + bias[128 + col + 3] + bias[256 + col + 3];
            } else {
                float4 c = *(const float4*)&C[gr * 128 + col];
                v.x += c.x; v.y += c.y; v.z += c.z; v.w += c.w;
                if (MODE == 2) {
                    v.x = fmaxf(v.x, 0.f); v.y = fmaxf(v.y, 0.f);
                    v.z = fmaxf(v.z, 0.f); v.w = fmaxf(v.w, 0.f);
                }
            }
            *(float4*)&C[gr * 128 + col] = v;
        }
    }
}

// ---------------- GEMM192: xw[M,192] = A[M,128] @ concat_cols(W2[3,128,64]) ----------------
__global__ __launch_bounds__(256) void k_gemm192(const float* __restrict__ A,
                                                 const float* __restrict__ W2,
                                                 float* __restrict__ C, int M) {
    __shared__ float sA[128][33];
    __shared__ float sW[32][192];
    int t = threadIdx.x;
    int row0 = blockIdx.x * 128;
    int rgrp = t >> 3;   // 0..31 -> rows rgrp*4 + i
    int cgrp = t & 7;    // cols cgrp*4 + 32*j, j=0..5
    float4 acc[4][6];
#pragma unroll
    for (int i = 0; i < 4; i++)
#pragma unroll
        for (int j = 0; j < 6; j++) acc[i][j] = make_float4(0.f, 0.f, 0.f, 0.f);

    for (int k0 = 0; k0 < 128; k0 += 32) {
#pragma unroll
        for (int i = 0; i < 4; i++) {
            int idx = t + i * 256;
            int row = idx >> 3;
            int kg = idx & 7;
            float4 v = make_float4(0.f, 0.f, 0.f, 0.f);
            int gr = row0 + row;
            if (gr < M) v = *(const float4*)&A[gr * 128 + k0 + kg * 4];
            sA[row][kg * 4 + 0] = v.x;
            sA[row][kg * 4 + 1] = v.y;
            sA[row][kg * 4 + 2] = v.z;
            sA[row][kg * 4 + 3] = v.w;
        }
        // W tile: 32 x 192 = 1536 float4, 6 per thread; col q -> W2[q>>6][k][q&63]
#pragma unroll
        for (int i = 0; i < 6; i++) {
            int idx = t + i * 256;       // 0..1535
            int wr = idx / 48;           // 0..31
            int cq = idx - wr * 48;      // 0..47
            int col = cq * 4;
            int r = col >> 6;
            int cl = col & 63;
            *(float4*)&sW[wr][col] =
                *(const float4*)&W2[r * (D_HID * D_OUT) + (k0 + wr) * 64 + cl];
        }
        __syncthreads();
#pragma unroll
        for (int k = 0; k < 32; k++) {
            float a0 = sA[rgrp * 4 + 0][k];
            float a1 = sA[rgrp * 4 + 1][k];
            float a2 = sA[rgrp * 4 + 2][k];
            float a3 = sA[rgrp * 4 + 3][k];
#pragma unroll
            for (int j = 0; j < 6; j++) {
                float4 w = *(const float4*)&sW[k][cgrp * 4 + 32 * j];
                acc[0][j].x += a0 * w.x; acc[0][j].y += a0 * w.y; acc[0][j].z += a0 * w.z; acc[0][j].w += a0 * w.w;
                acc[1][j].x += a1 * w.x; acc[1][j].y += a1 * w.y; acc[1][j].z += a1 * w.z; acc[1][j].w += a1 * w.w;
                acc[2][j].x += a2 * w.x; acc[2][j].y += a2 * w.y; acc[2][j].z += a2 * w.z; acc[2][j].w += a2 * w.w;
                acc[3][j].x += a3 * w.x; acc[3][j].y += a3 * w.y; acc[3][j].z += a3 * w.z; acc[3][j].w += a3 * w.w;
            }
        }
        __syncthreads();
    }
#pragma unroll
    for (int i = 0; i < 4; i++) {
        int gr = row0 + rgrp * 4 + i;
        if (gr >= M) continue;
#pragma unroll
        for (int j = 0; j < 6; j++)
            *(float4*)&C[gr * 192 + cgrp * 4 + 32 * j] = acc[i][j];
    }
}

// ---------------- fused layer-2 aggregation: all 3 relations + bias ----------------
__global__ __launch_bounds__(256) void k_agg64f(const int* __restrict__ csr_off,
                                                const int* __restrict__ csr_src,
                                                const float* __restrict__ csr_coef,
                                                const float* __restrict__ norm_in,
                                                const float* __restrict__ xw,   // [N,192]
                                                const float* __restrict__ b2,   // [3,64]
                                                float* __restrict__ h2) {       // [N,64]
    int w = (blockIdx.x * 256 + threadIdx.x) >> 6;
    if (w >= N_NODES) return;
    int lane = threadIdx.x & 63;
    float acc = b2[lane] + b2[64 + lane] + b2[128 + lane];
#pragma unroll
    for (int r = 0; r < R_REL; r++) {
        int beg = csr_off[r * N_NODES + w], end = csr_off[r * N_NODES + w + 1];
        float a = 0.f;
        for (int j = beg; j < end; j++) {
            int s = csr_src[j];
            float c = csr_coef[j];
            a += c * xw[s * 192 + r * 64 + lane];
        }
        acc += norm_in[r * N_NODES + w] * a;
    }
    h2[w * 64 + lane] = acc;
}

// ---------------- fallback layer-2 kernels (small ws) ----------------

__global__ __launch_bounds__(256) void k_init_h2(const float* __restrict__ b2,
                                                 float* __restrict__ h2) {
    int i = blockIdx.x * 256 + threadIdx.x;
    if (i >= N_NODES * D_OUT) return;
    int f = i & (D_OUT - 1);
    h2[i] = b2[f] + b2[D_OUT + f] + b2[2 * D_OUT + f];
}

__global__ __launch_bounds__(256) void k_gemm_n64(const float* __restrict__ A,
                                                  const float* __restrict__ W,
                                                  float* __restrict__ C, int M) {
    __shared__ float sA[64][33];
    __shared__ float sW[32][64];
    int t = threadIdx.x;
    int row0 = blockIdx.x * 64;
    int row = t >> 2;
    int cgrp = t & 3;
    float4 acc[4];
#pragma unroll
    for (int j = 0; j < 4; j++) acc[j] = make_float4(0.f, 0.f, 0.f, 0.f);
    for (int k0 = 0; k0 < 128; k0 += 32) {
#pragma unroll
        for (int i = 0; i < 2; i++) {
            int idx = t + i * 256;
            int arow = idx >> 3;
            int kg = idx & 7;
            float4 v = make_float4(0.f, 0.f, 0.f, 0.f);
            int gr = row0 + arow;
            if (gr < M) v = *(const float4*)&A[gr * 128 + kg * 4 + k0];
            sA[arow][kg * 4 + 0] = v.x;
            sA[arow][kg * 4 + 1] = v.y;
            sA[arow][kg * 4 + 2] = v.z;
            sA[arow][kg * 4 + 3] = v.w;
        }
#pragma unroll
        for (int i = 0; i < 2; i++) {
            int idx = t + i * 256;
            int wrow = idx >> 4;
            int cg = idx & 15;
            *(float4*)&sW[wrow][cg * 4] = *(const float4*)&W[(k0 + wrow) * 64 + cg * 4];
        }
        __syncthreads();
#pragma unroll
        for (int k = 0; k < 32; k++) {
            float xa = sA[row][k];
#pragma unroll
            for (int j = 0; j < 4; j++) {
                float4 w = *(const float4*)&sW[k][cgrp * 4 + 16 * j];
                acc[j].x += xa * w.x; acc[j].y += xa * w.y;
                acc[j].z += xa * w.z; acc[j].w += xa * w.w;
            }
        }
        __syncthreads();
    }
    int gr = row0 + row;
    if (gr < M) {
#pragma unroll
        for (int j = 0; j < 4; j++)
            *(float4*)&C[gr * 64 + cgrp * 4 + 16 * j] = acc[j];
    }
}

__global__ __launch_bounds__(256) void k_agg64(const int* __restrict__ csr_off,
                                               const int* __restrict__ csr_src,
                                               const float* __restrict__ csr_coef,
                                               const float* __restrict__ norm_in,
                                               const float* __restrict__ xw2,
                                               float* __restrict__ h2) {
    int w = (blockIdx.x * 256 + threadIdx.x) >> 6;
    if (w >= N_NODES) return;
    int lane = threadIdx.x & 63;
    int beg = csr_off[w], end = csr_off[w + 1];
    float a = 0.f;
    for (int j = beg; j < end; j++) {
        int s = csr_src[j];
        float c = csr_coef[j];
        a += c * xw2[s * 64 + lane];
    }
    h2[w * 64 + lane] += norm_in[w] * a;
}

// ---------------- predictor ----------------
__global__ __launch_bounds__(256) void k_predict(const int* __restrict__ sa,
                                                 const int* __restrict__ sb,
                                                 const int* __restrict__ na,
                                                 const int* __restrict__ nb,
                                                 const float* __restrict__ h2,
                                                 float* __restrict__ out) {
    int tid = blockIdx.x * 256 + threadIdx.x;
    int p = tid >> 4;
    if (p >= 2 * E_EDGES) return;
    int lane = tid & 15;
    int ia, ib;
    if (p < E_EDGES) { ia = sa[p]; ib = sb[p]; }
    else             { ia = na[p - E_EDGES]; ib = nb[p - E_EDGES]; }
    float4 va = *(const float4*)&h2[ia * 64 + lane * 4];
    float4 vb = *(const float4*)&h2[ib * 64 + lane * 4];
    float d = va.x * vb.x + va.y * vb.y + va.z * vb.z + va.w * vb.w;
    d += __shfl_xor(d, 1);
    d += __shfl_xor(d, 2);
    d += __shfl_xor(d, 4);
    d += __shfl_xor(d, 8);
    if (lane == 0) out[p] = d;
}

// ---------------- launch ----------------

extern "C" void kernel_launch(void* const* d_in, const int* in_sizes, int n_in,
                              void* d_out, int out_size, void* d_ws, size_t ws_size,
                              hipStream_t stream) {
    (void)in_sizes; (void)n_in; (void)out_size;
    const float* x       = (const float*)d_in[0];
    const int*   src     = (const int*)d_in[1];
    const int*   dst     = (const int*)d_in[2];
    const int*   neg_src = (const int*)d_in[3];
    const int*   neg_dst = (const int*)d_in[4];
    const float* W1      = (const float*)d_in[5];
    const float* b1      = (const float*)d_in[6];
    const float* W2      = (const float*)d_in[7];
    const float* b2      = (const float*)d_in[8];
    float* out = (float*)d_out;
    float* ws  = (float*)d_ws;

    // layout (float offsets):
    // 0        : deg/norm  [300000]
    // 300000   : csr_off   [150016 ints]
    // 450016   : cursor    [150016 ints]
    // 600032   : partials  [288 ints]
    // 600320   : csr_src   [600000 ints]
    // 1200320  : csr_coef  [600000]
    // 1800320  : agg       [6400000]   (L1; L2-fused: h2 here; L2-fallback: xw2 + h2)
    // 8200320  : h1        [6400000]
    // 14600320 : xw2_all   [9600000]   (fused path only; total 24200320 floats)
    int*   deg_i    = (int*)ws;
    float* norm_out = ws;
    float* norm_in  = ws + N_SCAN;
    int*   csr_off  = (int*)(ws + 300000);
    int*   cursor   = (int*)(ws + 450016);
    int*   partials = (int*)(ws + 600032);
    int*   csr_src  = (int*)(ws + 600320);
    float* csr_coef = ws + 1200320;
    float* agg      = ws + 1800320;
    float* h1       = ws + 8200320;

    const int NB_RE    = (R_REL * E_EDGES + 255) / 256;
    const int NB_G128  = (N_NODES + 127) / 128;
    const int NB_WAVE  = (N_NODES * 64 + 255) / 256;

    // degrees + CSR build
    k_zero_i32<<<(2 * N_SCAN + 255) / 256, 256, 0, stream>>>(deg_i, 2 * N_SCAN);
    k_count_deg<<<NB_RE, 256, 0, stream>>>(src, dst, deg_i, deg_i + N_SCAN);
    k_scan1<<<SCAN_NB, 256, 0, stream>>>(deg_i + N_SCAN, partials);
    k_scan2<<<1, 256, 0, stream>>>(partials, csr_off);
    k_scan3<<<SCAN_NB, 256, 0, stream>>>(deg_i + N_SCAN, partials, csr_off, cursor);
    k_norm<<<(2 * N_SCAN + 255) / 256, 256, 0, stream>>>(deg_i, ws, 2 * N_SCAN);
    k_bin<<<NB_RE, 256, 0, stream>>>(src, dst, norm_out, cursor, csr_src, csr_coef);

    // ---- layer 1: per relation agg then fused-epilogue GEMM into h1 ----
    for (int r = 0; r < R_REL; r++) {
        k_agg128<<<NB_WAVE, 256, 0, stream>>>(csr_off + r * N_NODES, csr_src, csr_coef,
                                              norm_in + r * N_NODES, x, agg);
        if (r == 0)
            k_gemm128<0><<<NB_G128, 256, 0, stream>>>(agg, W1, b1, h1, N_NODES);
        else if (r == 1)
            k_gemm128<1><<<NB_G128, 256, 0, stream>>>(agg, W1 + D_IN * D_HID, b1, h1, N_NODES);
        else
            k_gemm128<2><<<NB_G128, 256, 0, stream>>>(agg, W1 + 2 * D_IN * D_HID, b1, h1, N_NODES);
    }

    // ---- layer 2 ----
    const size_t need_fused = (size_t)24200320 * sizeof(float);
    float* h2;
    if (ws_size >= need_fused) {
        float* xw2_all = ws + 14600320;
        h2 = agg;  // agg dead after layer 1
        k_gemm192<<<NB_G128, 256, 0, stream>>>(h1, W2, xw2_all, N_NODES);
        k_agg64f<<<NB_WAVE, 256, 0, stream>>>(csr_off, csr_src, csr_coef,
                                              norm_in, xw2_all, b2, h2);
    } else {
        float* xw2 = agg;
        h2 = agg + 3200000;
        k_init_h2<<<(N_NODES * D_OUT + 255) / 256, 256, 0, stream>>>(b2, h2);
        for (int r = 0; r < R_REL; r++) {
            k_gemm_n64<<<(N_NODES + 63) / 64, 256, 0, stream>>>(
                h1, W2 + r * D_HID * D_OUT, xw2, N_NODES);
            k_agg64<<<NB_WAVE, 256, 0, stream>>>(csr_off + r * N_NODES, csr_src, csr_coef,
                                                 norm_in + r * N_NODES, xw2, h2);
        }
    }

    // ---- predictor ----
    k_predict<<<(2 * E_EDGES * 16 + 255) / 256, 256, 0, stream>>>(
        src, dst, neg_src, neg_dst, h2, out);
}

// Round 4
// 349.997 us; speedup vs baseline: 5.0706x; 1.2585x over previous
//
#include <hip/hip_runtime.h>

#define N_NODES 50000
#define E_EDGES 200000
#define R_REL 3
#define D_IN 128
#define D_HID 128
#define D_OUT 64
#define N_SCAN (R_REL * N_NODES)          // 150000
#define SCAN_NB ((N_SCAN + 1023) / 1024)  // 147

typedef __attribute__((ext_vector_type(8))) short bf16x8;
typedef __attribute__((ext_vector_type(4))) float f32x4;

__device__ inline unsigned short f2bf(float v) {
    union { float f; unsigned int u; } x; x.f = v;
    unsigned int r = x.u + 0x7fffu + ((x.u >> 16) & 1u);
    return (unsigned short)(r >> 16);
}
__device__ inline float bf2f(unsigned short h) {
    union { unsigned int u; float f; } x; x.u = ((unsigned int)h) << 16; return x.f;
}

// ---------------- degree / norm ----------------

__global__ __launch_bounds__(256) void k_zero_i32(int* __restrict__ p, int n) {
    int i = blockIdx.x * 256 + threadIdx.x;
    if (i < n) p[i] = 0;
}

__global__ __launch_bounds__(256) void k_count_deg(const int* __restrict__ src,
                                                   const int* __restrict__ dst,
                                                   int* __restrict__ deg_out,
                                                   int* __restrict__ deg_in) {
    int i = blockIdx.x * 256 + threadIdx.x;  // over R*E
    if (i >= R_REL * E_EDGES) return;
    int r = i / E_EDGES;
    atomicAdd(&deg_out[r * N_NODES + src[i]], 1);
    atomicAdd(&deg_in[r * N_NODES + dst[i]], 1);
}

__global__ __launch_bounds__(256) void k_norm(const int* __restrict__ di,
                                              float* __restrict__ fo, int n) {
    int i = blockIdx.x * 256 + threadIdx.x;
    if (i >= n) return;
    int d = di[i];
    fo[i] = rsqrtf((float)(d > 1 ? d : 1));
}

// ---------------- exclusive scan over deg_in (150000 ints) ----------------

__global__ __launch_bounds__(256) void k_scan1(const int* __restrict__ deg,
                                               int* __restrict__ partials) {
    __shared__ int sd[256];
    int t = threadIdx.x;
    int base = blockIdx.x * 1024 + t * 4;
    int s = 0;
#pragma unroll
    for (int k = 0; k < 4; k++) {
        int i = base + k;
        if (i < N_SCAN) s += deg[i];
    }
    sd[t] = s;
    __syncthreads();
    for (int off = 128; off > 0; off >>= 1) {
        if (t < off) sd[t] += sd[t + off];
        __syncthreads();
    }
    if (t == 0) partials[blockIdx.x] = sd[0];
}

__global__ __launch_bounds__(256) void k_scan2(int* __restrict__ partials,
                                               int* __restrict__ csr_off) {
    __shared__ int sd[256];
    int t = threadIdx.x;
    int v = (t < SCAN_NB) ? partials[t] : 0;
    sd[t] = v;
    __syncthreads();
    for (int off = 1; off < 256; off <<= 1) {
        int a = (t >= off) ? sd[t - off] : 0;
        __syncthreads();
        sd[t] += a;
        __syncthreads();
    }
    partials[t] = sd[t] - v;  // exclusive
    if (t == 255) csr_off[N_SCAN] = sd[255];
}

__global__ __launch_bounds__(256) void k_scan3(const int* __restrict__ deg,
                                               const int* __restrict__ partials,
                                               int* __restrict__ csr_off,
                                               int* __restrict__ cursor) {
    __shared__ int sd[256];
    int t = threadIdx.x;
    int base = blockIdx.x * 1024 + t * 4;
    int v[4];
    int tsum = 0;
#pragma unroll
    for (int k = 0; k < 4; k++) {
        int i = base + k;
        v[k] = (i < N_SCAN) ? deg[i] : 0;
        tsum += v[k];
    }
    sd[t] = tsum;
    __syncthreads();
    for (int off = 1; off < 256; off <<= 1) {
        int a = (t >= off) ? sd[t - off] : 0;
        __syncthreads();
        sd[t] += a;
        __syncthreads();
    }
    int run = partials[blockIdx.x] + sd[t] - tsum;
#pragma unroll
    for (int k = 0; k < 4; k++) {
        int i = base + k;
        if (i < N_SCAN) {
            csr_off[i] = run;
            cursor[i] = run;
            run += v[k];
        }
    }
}

// ---------------- edge binning ----------------

__global__ __launch_bounds__(256) void k_bin(const int* __restrict__ src,
                                             const int* __restrict__ dst,
                                             const float* __restrict__ norm_out,
                                             int* __restrict__ cursor,
                                             int* __restrict__ csr_src,
                                             float* __restrict__ csr_coef) {
    int i = blockIdx.x * 256 + threadIdx.x;  // over R*E
    if (i >= R_REL * E_EDGES) return;
    int r = i / E_EDGES;
    int s = src[i];
    int d = dst[i];
    int pos = atomicAdd(&cursor[r * N_NODES + d], 1);
    csr_src[pos] = s;
    csr_coef[pos] = norm_out[r * N_NODES + s];
}

// ---------------- weight prep: transpose + bf16 split ----------------
// w1t[r][c][k] (c<128,k<128), w2t[col][k] (col<192,k<128), bsum[128]
__global__ __launch_bounds__(256) void k_wprep(const float* __restrict__ W1,
                                               const float* __restrict__ W2,
                                               const float* __restrict__ b1,
                                               unsigned short* __restrict__ w1t_h,
                                               unsigned short* __restrict__ w1t_l,
                                               unsigned short* __restrict__ w2t_h,
                                               unsigned short* __restrict__ w2t_l,
                                               float* __restrict__ bsum) {
    int i = blockIdx.x * 256 + threadIdx.x;
    if (i < R_REL * D_IN * D_HID) {  // 49152
        int r = i >> 14;
        int kk = (i >> 7) & 127;
        int c = i & 127;
        float v = W1[i];
        unsigned short h = f2bf(v);
        unsigned short l = f2bf(v - bf2f(h));
        int o = r * 16384 + c * 128 + kk;
        w1t_h[o] = h;
        w1t_l[o] = l;
    }
    if (i < R_REL * D_HID * D_OUT) {  // 24576
        int r = i >> 13;
        int kk = (i >> 6) & 127;
        int cl = i & 63;
        float v = W2[i];
        unsigned short h = f2bf(v);
        unsigned short l = f2bf(v - bf2f(h));
        int o = (r * 64 + cl) * 128 + kk;
        w2t_h[o] = h;
        w2t_l[o] = l;
    }
    if (i < 128) bsum[i] = b1[i] + b1[128 + i] + b1[256 + i];
}

// ---------------- CSR aggregation layer 1 (fp32) ----------------
__global__ __launch_bounds__(256) void k_agg128(const int* __restrict__ csr_off,
                                                const int* __restrict__ csr_src,
                                                const float* __restrict__ csr_coef,
                                                const float* __restrict__ norm_in,
                                                const float* __restrict__ x,
                                                float* __restrict__ agg) {
    int w = (blockIdx.x * 256 + threadIdx.x) >> 6;
    if (w >= N_NODES) return;
    int lane = threadIdx.x & 63;
    int beg = csr_off[w], end = csr_off[w + 1];
    float ax = 0.f, ay = 0.f;
    for (int j = beg; j < end; j++) {
        int s = csr_src[j];
        float c = csr_coef[j];
        float2 v = *(const float2*)&x[s * 128 + lane * 2];
        ax += c * v.x;
        ay += c * v.y;
    }
    float ni = norm_in[w];
    float2 o;
    o.x = ax * ni;
    o.y = ay * ni;
    *(float2*)&agg[w * 128 + lane * 2] = o;
}

// ---------------- MFMA split-bf16 GEMM, layer 1 ----------------
// C[M,128] (+)= A[M,128] @ W1_r[128,128]; 64x128 tile, 4 waves (2x2), K-steps of 32.
// MODE 0: h1f = acc + bsum ; MODE 1: h1f += acc ; MODE 2: relu(h1f+acc) -> split h1h/h1l
template <int MODE>
__global__ __launch_bounds__(256) void k_mm1(const float* __restrict__ A,
                                             const unsigned short* __restrict__ wt_h,
                                             const unsigned short* __restrict__ wt_l,
                                             const float* __restrict__ bsum,
                                             float* __restrict__ h1f,
                                             unsigned short* __restrict__ h1h,
                                             unsigned short* __restrict__ h1l,
                                             int M) {
    __shared__ short sAh[2048], sAl[2048];     // [4 kg][64 row][8]
    __shared__ short sWh[4096], sWl[4096];     // [4 kg][128 col][8]
    int t = threadIdx.x;
    int row0 = blockIdx.x * 64;
    int wid = t >> 6;
    int lane = t & 63;
    int lr = lane & 15;
    int lkg = lane >> 4;
    int wr = (wid & 1) * 32;
    int wc = (wid >> 1) * 64;

    f32x4 acc[2][4];
#pragma unroll
    for (int i = 0; i < 2; i++)
#pragma unroll
        for (int j = 0; j < 4; j++) acc[i][j] = (f32x4)(0.f);

    int arow = t >> 2;       // 0..63
    int akg = t & 3;         // 0..3

    for (int k0 = 0; k0 < 128; k0 += 32) {
        // stage A (fp32 -> bf16 hi/lo)
        {
            int gr = row0 + arow;
            float v[8];
            if (gr < M) {
                float4 p0 = *(const float4*)&A[gr * 128 + k0 + akg * 8];
                float4 p1 = *(const float4*)&A[gr * 128 + k0 + akg * 8 + 4];
                v[0] = p0.x; v[1] = p0.y; v[2] = p0.z; v[3] = p0.w;
                v[4] = p1.x; v[5] = p1.y; v[6] = p1.z; v[7] = p1.w;
            } else {
#pragma unroll
                for (int e = 0; e < 8; e++) v[e] = 0.f;
            }
            short hh[8], ll[8];
#pragma unroll
            for (int e = 0; e < 8; e++) {
                unsigned short h = f2bf(v[e]);
                hh[e] = (short)h;
                ll[e] = (short)f2bf(v[e] - bf2f(h));
            }
            int cidx = akg * 64 + arow;
            *(bf16x8*)&sAh[cidx * 8] = *(bf16x8*)hh;
            *(bf16x8*)&sAl[cidx * 8] = *(bf16x8*)ll;
        }
        // stage W (pre-split bf16)
#pragma unroll
        for (int itr = 0; itr < 2; itr++) {
            int cc = t + itr * 256;       // 0..511
            int col = cc >> 2;
            int kg = cc & 3;
            int go = col * 128 + k0 + kg * 8;
            int cidx = kg * 128 + col;
            *(bf16x8*)&sWh[cidx * 8] = *(const bf16x8*)&wt_h[go];
            *(bf16x8*)&sWl[cidx * 8] = *(const bf16x8*)&wt_l[go];
        }
        __syncthreads();
        bf16x8 ah[2], al[2], bh[4], bl[4];
#pragma unroll
        for (int i = 0; i < 2; i++) {
            int cidx = lkg * 64 + wr + i * 16 + lr;
            ah[i] = *(const bf16x8*)&sAh[cidx * 8];
            al[i] = *(const bf16x8*)&sAl[cidx * 8];
        }
#pragma unroll
        for (int j = 0; j < 4; j++) {
            int cidx = lkg * 128 + wc + j * 16 + lr;
            bh[j] = *(const bf16x8*)&sWh[cidx * 8];
            bl[j] = *(const bf16x8*)&sWl[cidx * 8];
        }
#pragma unroll
        for (int i = 0; i < 2; i++)
#pragma unroll
            for (int j = 0; j < 4; j++) {
                acc[i][j] = __builtin_amdgcn_mfma_f32_16x16x32_bf16(ah[i], bh[j], acc[i][j], 0, 0, 0);
                acc[i][j] = __builtin_amdgcn_mfma_f32_16x16x32_bf16(ah[i], bl[j], acc[i][j], 0, 0, 0);
                acc[i][j] = __builtin_amdgcn_mfma_f32_16x16x32_bf16(al[i], bh[j], acc[i][j], 0, 0, 0);
            }
        __syncthreads();
    }
    // epilogue
#pragma unroll
    for (int i = 0; i < 2; i++)
#pragma unroll
        for (int q = 0; q < 4; q++) {
            int gr = row0 + wr + i * 16 + lkg * 4 + q;
            if (gr >= M) continue;
#pragma unroll
            for (int j = 0; j < 4; j++) {
                int gc = wc + j * 16 + lr;
                float v = acc[i][j][q];
                if (MODE == 0) {
                    h1f[gr * 128 + gc] = v + bsum[gc];
                } else if (MODE == 1) {
                    h1f[gr * 128 + gc] += v;
                } else {
                    float u = fmaxf(h1f[gr * 128 + gc] + v, 0.f);
                    unsigned short h = f2bf(u);
                    h1h[gr * 128 + gc] = h;
                    h1l[gr * 128 + gc] = f2bf(u - bf2f(h));
                }
            }
        }
}

// ---------------- MFMA split-bf16 GEMM, layer 2 ----------------
// xw2[M,192] = h1[M,128] @ W2cat[128,192]; 64x192 tile, 4 waves (2x2), wave 32x96.
__global__ __launch_bounds__(256) void k_mm2(const unsigned short* __restrict__ h1h,
                                             const unsigned short* __restrict__ h1l,
                                             const unsigned short* __restrict__ wt_h,
                                             const unsigned short* __restrict__ wt_l,
                                             float* __restrict__ xw2, int M) {
    __shared__ short sAh[2048], sAl[2048];     // [4 kg][64 row][8]
    __shared__ short sWh[6144], sWl[6144];     // [4 kg][192 col][8]
    int t = threadIdx.x;
    int row0 = blockIdx.x * 64;
    int wid = t >> 6;
    int lane = t & 63;
    int lr = lane & 15;
    int lkg = lane >> 4;
    int wr = (wid & 1) * 32;
    int wc = (wid >> 1) * 96;

    f32x4 acc[2][6];
#pragma unroll
    for (int i = 0; i < 2; i++)
#pragma unroll
        for (int j = 0; j < 6; j++) acc[i][j] = (f32x4)(0.f);

    int arow = t >> 2;
    int akg = t & 3;

    for (int k0 = 0; k0 < 128; k0 += 32) {
        {
            int gr = row0 + arow;
            int cidx = akg * 64 + arow;
            if (gr < M) {
                int go = gr * 128 + k0 + akg * 8;
                *(bf16x8*)&sAh[cidx * 8] = *(const bf16x8*)&h1h[go];
                *(bf16x8*)&sAl[cidx * 8] = *(const bf16x8*)&h1l[go];
            } else {
                *(bf16x8*)&sAh[cidx * 8] = (bf16x8)(short)0;
                *(bf16x8*)&sAl[cidx * 8] = (bf16x8)(short)0;
            }
        }
#pragma unroll
        for (int itr = 0; itr < 3; itr++) {
            int cc = t + itr * 256;       // 0..767
            int col = cc >> 2;
            int kg = cc & 3;
            int go = col * 128 + k0 + kg * 8;
            int cidx = kg * 192 + col;
            *(bf16x8*)&sWh[cidx * 8] = *(const bf16x8*)&wt_h[go];
            *(bf16x8*)&sWl[cidx * 8] = *(const bf16x8*)&wt_l[go];
        }
        __syncthreads();
        bf16x8 ah[2], al[2];
#pragma unroll
        for (int i = 0; i < 2; i++) {
            int cidx = lkg * 64 + wr + i * 16 + lr;
            ah[i] = *(const bf16x8*)&sAh[cidx * 8];
            al[i] = *(const bf16x8*)&sAl[cidx * 8];
        }
#pragma unroll
        for (int j = 0; j < 6; j++) {
            int cidx = lkg * 192 + wc + j * 16 + lr;
            bf16x8 bh = *(const bf16x8*)&sWh[cidx * 8];
            bf16x8 bl = *(const bf16x8*)&sWl[cidx * 8];
#pragma unroll
            for (int i = 0; i < 2; i++) {
                acc[i][j] = __builtin_amdgcn_mfma_f32_16x16x32_bf16(ah[i], bh, acc[i][j], 0, 0, 0);
                acc[i][j] = __builtin_amdgcn_mfma_f32_16x16x32_bf16(ah[i], bl, acc[i][j], 0, 0, 0);
                acc[i][j] = __builtin_amdgcn_mfma_f32_16x16x32_bf16(al[i], bh, acc[i][j], 0, 0, 0);
            }
        }
        __syncthreads();
    }
#pragma unroll
    for (int i = 0; i < 2; i++)
#pragma unroll
        for (int q = 0; q < 4; q++) {
            int gr = row0 + wr + i * 16 + lkg * 4 + q;
            if (gr >= M) continue;
#pragma unroll
            for (int j = 0; j < 6; j++) {
                int gc = wc + j * 16 + lr;
                xw2[gr * 192 + gc] = acc[i][j][q];
            }
        }
}

// ---------------- fused layer-2 aggregation ----------------
__global__ __launch_bounds__(256) void k_agg64f(const int* __restrict__ csr_off,
                                                const int* __restrict__ csr_src,
                                                const float* __restrict__ csr_coef,
                                                const float* __restrict__ norm_in,
                                                const float* __restrict__ xw,   // [N,192]
                                                const float* __restrict__ b2,   // [3,64]
                                                float* __restrict__ h2) {       // [N,64]
    int w = (blockIdx.x * 256 + threadIdx.x) >> 6;
    if (w >= N_NODES) return;
    int lane = threadIdx.x & 63;
    float acc = b2[lane] + b2[64 + lane] + b2[128 + lane];
#pragma unroll
    for (int r = 0; r < R_REL; r++) {
        int beg = csr_off[r * N_NODES + w], end = csr_off[r * N_NODES + w + 1];
        float a = 0.f;
        for (int j = beg; j < end; j++) {
            int s = csr_src[j];
            float c = csr_coef[j];
            a += c * xw[s * 192 + r * 64 + lane];
        }
        acc += norm_in[r * N_NODES + w] * a;
    }
    h2[w * 64 + lane] = acc;
}

// ---------------- predictor ----------------
__global__ __launch_bounds__(256) void k_predict(const int* __restrict__ sa,
                                                 const int* __restrict__ sb,
                                                 const int* __restrict__ na,
                                                 const int* __restrict__ nb,
                                                 const float* __restrict__ h2,
                                                 float* __restrict__ out) {
    int tid = blockIdx.x * 256 + threadIdx.x;
    int p = tid >> 4;
    if (p >= 2 * E_EDGES) return;
    int lane = tid & 15;
    int ia, ib;
    if (p < E_EDGES) { ia = sa[p]; ib = sb[p]; }
    else             { ia = na[p - E_EDGES]; ib = nb[p - E_EDGES]; }
    float4 va = *(const float4*)&h2[ia * 64 + lane * 4];
    float4 vb = *(const float4*)&h2[ib * 64 + lane * 4];
    float d = va.x * vb.x + va.y * vb.y + va.z * vb.z + va.w * vb.w;
    d += __shfl_xor(d, 1);
    d += __shfl_xor(d, 2);
    d += __shfl_xor(d, 4);
    d += __shfl_xor(d, 8);
    if (lane == 0) out[p] = d;
}

// ---------------- launch ----------------

extern "C" void kernel_launch(void* const* d_in, const int* in_sizes, int n_in,
                              void* d_out, int out_size, void* d_ws, size_t ws_size,
                              hipStream_t stream) {
    (void)in_sizes; (void)n_in; (void)out_size; (void)ws_size;
    const float* x       = (const float*)d_in[0];
    const int*   src     = (const int*)d_in[1];
    const int*   dst     = (const int*)d_in[2];
    const int*   neg_src = (const int*)d_in[3];
    const int*   neg_dst = (const int*)d_in[4];
    const float* W1      = (const float*)d_in[5];
    const float* b1      = (const float*)d_in[6];
    const float* W2      = (const float*)d_in[7];
    const float* b2      = (const float*)d_in[8];
    float* out = (float*)d_out;
    float* ws  = (float*)d_ws;

    // float-offset layout (total 21,074,176 floats = 84.3 MB):
    // 0        : deg/norm [300000]
    // 300000   : csr_off [150016]   450016: cursor [150016]   600032: partials [288]
    // 600320   : csr_src [600000]   1200320: csr_coef [600000]
    // 1800320  : w1t_h [24576f]     1824896: w1t_l [24576f]
    // 1849472  : w2t_h [12288f]     1861760: w2t_l [12288f]   1874048: bsum [128]
    // 1874176  : agg [6.4M] / (L2: xw2 [9.6M] @here, h2 [3.2M] @11474176)
    // 8274176  : h1f [6.4M] (dead after mm1<2>)
    // 14674176 : h1h [3.2Mf = 6.4M bf16]    17874176: h1l [3.2Mf]
    int*   deg_i    = (int*)ws;
    float* norm_out = ws;
    float* norm_in  = ws + N_SCAN;
    int*   csr_off  = (int*)(ws + 300000);
    int*   cursor   = (int*)(ws + 450016);
    int*   partials = (int*)(ws + 600032);
    int*   csr_src  = (int*)(ws + 600320);
    float* csr_coef = ws + 1200320;
    unsigned short* w1t_h = (unsigned short*)(ws + 1800320);
    unsigned short* w1t_l = (unsigned short*)(ws + 1824896);
    unsigned short* w2t_h = (unsigned short*)(ws + 1849472);
    unsigned short* w2t_l = (unsigned short*)(ws + 1861760);
    float* bsum     = ws + 1874048;
    float* agg      = ws + 1874176;
    float* xw2      = ws + 1874176;
    float* h2       = ws + 11474176;
    float* h1f      = ws + 8274176;
    unsigned short* h1h = (unsigned short*)(ws + 14674176);
    unsigned short* h1l = (unsigned short*)(ws + 17874176);

    const int NB_RE   = (R_REL * E_EDGES + 255) / 256;
    const int NB_WAVE = (N_NODES * 64 + 255) / 256;     // 12500
    const int NB_MM   = (N_NODES + 63) / 64;            // 782

    // preprocessing
    k_zero_i32<<<(2 * N_SCAN + 255) / 256, 256, 0, stream>>>(deg_i, 2 * N_SCAN);
    k_wprep<<<192, 256, 0, stream>>>(W1, W2, b1, w1t_h, w1t_l, w2t_h, w2t_l, bsum);
    k_count_deg<<<NB_RE, 256, 0, stream>>>(src, dst, deg_i, deg_i + N_SCAN);
    k_scan1<<<SCAN_NB, 256, 0, stream>>>(deg_i + N_SCAN, partials);
    k_scan2<<<1, 256, 0, stream>>>(partials, csr_off);
    k_scan3<<<SCAN_NB, 256, 0, stream>>>(deg_i + N_SCAN, partials, csr_off, cursor);
    k_norm<<<(2 * N_SCAN + 255) / 256, 256, 0, stream>>>(deg_i, ws, 2 * N_SCAN);
    k_bin<<<NB_RE, 256, 0, stream>>>(src, dst, norm_out, cursor, csr_src, csr_coef);

    // ---- layer 1: agg (fp32) then split-bf16 MFMA GEMM into h1 ----
    for (int r = 0; r < R_REL; r++) {
        k_agg128<<<NB_WAVE, 256, 0, stream>>>(csr_off + r * N_NODES, csr_src, csr_coef,
                                              norm_in + r * N_NODES, x, agg);
        if (r == 0)
            k_mm1<0><<<NB_MM, 256, 0, stream>>>(agg, w1t_h, w1t_l, bsum, h1f, h1h, h1l, N_NODES);
        else if (r == 1)
            k_mm1<1><<<NB_MM, 256, 0, stream>>>(agg, w1t_h + 16384, w1t_l + 16384, bsum, h1f, h1h, h1l, N_NODES);
        else
            k_mm1<2><<<NB_MM, 256, 0, stream>>>(agg, w1t_h + 32768, w1t_l + 32768, bsum, h1f, h1h, h1l, N_NODES);
    }

    // ---- layer 2: one GEMM [N,128]@[128,192] then fused aggregation ----
    k_mm2<<<NB_MM, 256, 0, stream>>>(h1h, h1l, w2t_h, w2t_l, xw2, N_NODES);
    k_agg64f<<<NB_WAVE, 256, 0, stream>>>(csr_off, csr_src, csr_coef, norm_in, xw2, b2, h2);

    // ---- predictor ----
    k_predict<<<(2 * E_EDGES * 16 + 255) / 256, 256, 0, stream>>>(
        src, dst, neg_src, neg_dst, h2, out);
}

// Round 5
// 305.008 us; speedup vs baseline: 5.8185x; 1.1475x over previous
//
#include <hip/hip_runtime.h>

#define N_NODES 50000
#define E_EDGES 200000
#define R_REL 3
#define D_IN 128
#define D_HID 128
#define D_OUT 64
#define N_SCAN (R_REL * N_NODES)          // 150000
#define SCAN_NB ((N_SCAN + 1023) / 1024)  // 147

typedef __attribute__((ext_vector_type(8))) short bf16x8;
typedef __attribute__((ext_vector_type(4))) float f32x4;

__device__ inline unsigned short f2bf(float v) {
    union { float f; unsigned int u; } x; x.f = v;
    unsigned int r = x.u + 0x7fffu + ((x.u >> 16) & 1u);
    return (unsigned short)(r >> 16);
}
__device__ inline float bf2f(unsigned short h) {
    union { unsigned int u; float f; } x; x.u = ((unsigned int)h) << 16; return x.f;
}
__device__ inline float bf_lo(unsigned int p) {
    union { unsigned int u; float f; } x; x.u = p << 16; return x.f;
}
__device__ inline float bf_hi(unsigned int p) {
    union { unsigned int u; float f; } x; x.u = p & 0xffff0000u; return x.f;
}

// ---------------- degree / norm ----------------

__global__ __launch_bounds__(256) void k_zero_i32(int* __restrict__ p, int n) {
    int i = blockIdx.x * 256 + threadIdx.x;
    if (i < n) p[i] = 0;
}

__global__ __launch_bounds__(256) void k_count_deg(const int* __restrict__ src,
                                                   const int* __restrict__ dst,
                                                   int* __restrict__ deg_out,
                                                   int* __restrict__ deg_in) {
    int i = blockIdx.x * 256 + threadIdx.x;  // over R*E
    if (i >= R_REL * E_EDGES) return;
    int r = i / E_EDGES;
    atomicAdd(&deg_out[r * N_NODES + src[i]], 1);
    atomicAdd(&deg_in[r * N_NODES + dst[i]], 1);
}

__global__ __launch_bounds__(256) void k_norm(const int* __restrict__ di,
                                              float* __restrict__ fo, int n) {
    int i = blockIdx.x * 256 + threadIdx.x;
    if (i >= n) return;
    int d = di[i];
    fo[i] = rsqrtf((float)(d > 1 ? d : 1));
}

// ---------------- exclusive scan over deg_in (150000 ints) ----------------

__global__ __launch_bounds__(256) void k_scan1(const int* __restrict__ deg,
                                               int* __restrict__ partials) {
    __shared__ int sd[256];
    int t = threadIdx.x;
    int base = blockIdx.x * 1024 + t * 4;
    int s = 0;
#pragma unroll
    for (int k = 0; k < 4; k++) {
        int i = base + k;
        if (i < N_SCAN) s += deg[i];
    }
    sd[t] = s;
    __syncthreads();
    for (int off = 128; off > 0; off >>= 1) {
        if (t < off) sd[t] += sd[t + off];
        __syncthreads();
    }
    if (t == 0) partials[blockIdx.x] = sd[0];
}

__global__ __launch_bounds__(256) void k_scan2(int* __restrict__ partials,
                                               int* __restrict__ csr_off) {
    __shared__ int sd[256];
    int t = threadIdx.x;
    int v = (t < SCAN_NB) ? partials[t] : 0;
    sd[t] = v;
    __syncthreads();
    for (int off = 1; off < 256; off <<= 1) {
        int a = (t >= off) ? sd[t - off] : 0;
        __syncthreads();
        sd[t] += a;
        __syncthreads();
    }
    partials[t] = sd[t] - v;  // exclusive
    if (t == 255) csr_off[N_SCAN] = sd[255];
}

__global__ __launch_bounds__(256) void k_scan3(const int* __restrict__ deg,
                                               const int* __restrict__ partials,
                                               int* __restrict__ csr_off,
                                               int* __restrict__ cursor) {
    __shared__ int sd[256];
    int t = threadIdx.x;
    int base = blockIdx.x * 1024 + t * 4;
    int v[4];
    int tsum = 0;
#pragma unroll
    for (int k = 0; k < 4; k++) {
        int i = base + k;
        v[k] = (i < N_SCAN) ? deg[i] : 0;
        tsum += v[k];
    }
    sd[t] = tsum;
    __syncthreads();
    for (int off = 1; off < 256; off <<= 1) {
        int a = (t >= off) ? sd[t - off] : 0;
        __syncthreads();
        sd[t] += a;
        __syncthreads();
    }
    int run = partials[blockIdx.x] + sd[t] - tsum;
#pragma unroll
    for (int k = 0; k < 4; k++) {
        int i = base + k;
        if (i < N_SCAN) {
            csr_off[i] = run;
            cursor[i] = run;
            run += v[k];
        }
    }
}

// ---------------- edge binning ----------------

__global__ __launch_bounds__(256) void k_bin(const int* __restrict__ src,
                                             const int* __restrict__ dst,
                                             const float* __restrict__ norm_out,
                                             int* __restrict__ cursor,
                                             int* __restrict__ csr_src,
                                             float* __restrict__ csr_coef) {
    int i = blockIdx.x * 256 + threadIdx.x;  // over R*E
    if (i >= R_REL * E_EDGES) return;
    int r = i / E_EDGES;
    int s = src[i];
    int d = dst[i];
    int pos = atomicAdd(&cursor[r * N_NODES + d], 1);
    csr_src[pos] = s;
    csr_coef[pos] = norm_out[r * N_NODES + s];
}

// ---------------- weight prep: transpose + bf16 split ----------------
__global__ __launch_bounds__(256) void k_wprep(const float* __restrict__ W1,
                                               const float* __restrict__ W2,
                                               const float* __restrict__ b1,
                                               unsigned short* __restrict__ w1t_h,
                                               unsigned short* __restrict__ w1t_l,
                                               unsigned short* __restrict__ w2t_h,
                                               unsigned short* __restrict__ w2t_l,
                                               float* __restrict__ bsum) {
    int i = blockIdx.x * 256 + threadIdx.x;
    if (i < R_REL * D_IN * D_HID) {  // 49152
        int r = i >> 14;
        int kk = (i >> 7) & 127;
        int c = i & 127;
        float v = W1[i];
        unsigned short h = f2bf(v);
        unsigned short l = f2bf(v - bf2f(h));
        int o = r * 16384 + c * 128 + kk;
        w1t_h[o] = h;
        w1t_l[o] = l;
    }
    if (i < R_REL * D_HID * D_OUT) {  // 24576
        int r = i >> 13;
        int kk = (i >> 6) & 127;
        int cl = i & 63;
        float v = W2[i];
        unsigned short h = f2bf(v);
        unsigned short l = f2bf(v - bf2f(h));
        int o = (r * 64 + cl) * 128 + kk;
        w2t_h[o] = h;
        w2t_l[o] = l;
    }
    if (i < 128) bsum[i] = b1[i] + b1[128 + i] + b1[256 + i];
}

// ---------------- x -> bf16 table ----------------
__global__ __launch_bounds__(256) void k_xprep(const float* __restrict__ x,
                                               unsigned int* __restrict__ xb) {
    int i = blockIdx.x * 256 + threadIdx.x;  // over N*128/4 = 1.6M
    if (i >= N_NODES * 32) return;
    float4 v = ((const float4*)x)[i];
    uint2 u;
    u.x = ((unsigned int)f2bf(v.y) << 16) | f2bf(v.x);
    u.y = ((unsigned int)f2bf(v.w) << 16) | f2bf(v.z);
    ((uint2*)xb)[i] = u;
}

// ---------------- CSR aggregation layer 1 (bf16 gather, fp32 accum) ----------------
// One wave per dst node; lane handles feats 2*lane, 2*lane+1 (one packed uint).
__global__ __launch_bounds__(256) void k_agg128(const int* __restrict__ csr_off,
                                                const int* __restrict__ csr_src,
                                                const float* __restrict__ csr_coef,
                                                const float* __restrict__ norm_in,
                                                const unsigned int* __restrict__ xb,
                                                float* __restrict__ agg) {
    int w = (blockIdx.x * 256 + threadIdx.x) >> 6;
    if (w >= N_NODES) return;
    int lane = threadIdx.x & 63;
    const unsigned int* tab = xb + lane;     // row stride 64 uints
    int beg = csr_off[w], end = csr_off[w + 1];
    float ax = 0.f, ay = 0.f;
    int j = beg;
    for (; j + 4 <= end; j += 4) {
        int s0 = csr_src[j + 0], s1 = csr_src[j + 1];
        int s2 = csr_src[j + 2], s3 = csr_src[j + 3];
        float c0 = csr_coef[j + 0], c1 = csr_coef[j + 1];
        float c2 = csr_coef[j + 2], c3 = csr_coef[j + 3];
        unsigned int p0 = tab[s0 * 64], p1 = tab[s1 * 64];
        unsigned int p2 = tab[s2 * 64], p3 = tab[s3 * 64];
        ax += c0 * bf_lo(p0); ay += c0 * bf_hi(p0);
        ax += c1 * bf_lo(p1); ay += c1 * bf_hi(p1);
        ax += c2 * bf_lo(p2); ay += c2 * bf_hi(p2);
        ax += c3 * bf_lo(p3); ay += c3 * bf_hi(p3);
    }
    for (; j < end; j++) {
        float c = csr_coef[j];
        unsigned int p = tab[csr_src[j] * 64];
        ax += c * bf_lo(p);
        ay += c * bf_hi(p);
    }
    float ni = norm_in[w];
    float2 o;
    o.x = ax * ni;
    o.y = ay * ni;
    *(float2*)&agg[w * 128 + lane * 2] = o;
}

// ---------------- MFMA split-bf16 GEMM, layer 1 ----------------
// MODE 0: h1f = acc + bsum ; MODE 1: h1f += acc ; MODE 2: relu(h1f+acc) -> split h1h/h1l
template <int MODE>
__global__ __launch_bounds__(256) void k_mm1(const float* __restrict__ A,
                                             const unsigned short* __restrict__ wt_h,
                                             const unsigned short* __restrict__ wt_l,
                                             const float* __restrict__ bsum,
                                             float* __restrict__ h1f,
                                             unsigned short* __restrict__ h1h,
                                             unsigned short* __restrict__ h1l,
                                             int M) {
    __shared__ short sAh[2048], sAl[2048];     // [4 kg][64 row][8]
    __shared__ short sWh[4096], sWl[4096];     // [4 kg][128 col][8]
    int t = threadIdx.x;
    int row0 = blockIdx.x * 64;
    int wid = t >> 6;
    int lane = t & 63;
    int lr = lane & 15;
    int lkg = lane >> 4;
    int wr = (wid & 1) * 32;
    int wc = (wid >> 1) * 64;

    f32x4 acc[2][4];
#pragma unroll
    for (int i = 0; i < 2; i++)
#pragma unroll
        for (int j = 0; j < 4; j++) acc[i][j] = (f32x4)(0.f);

    int arow = t >> 2;       // 0..63
    int akg = t & 3;         // 0..3

    for (int k0 = 0; k0 < 128; k0 += 32) {
        {
            int gr = row0 + arow;
            float v[8];
            if (gr < M) {
                float4 p0 = *(const float4*)&A[gr * 128 + k0 + akg * 8];
                float4 p1 = *(const float4*)&A[gr * 128 + k0 + akg * 8 + 4];
                v[0] = p0.x; v[1] = p0.y; v[2] = p0.z; v[3] = p0.w;
                v[4] = p1.x; v[5] = p1.y; v[6] = p1.z; v[7] = p1.w;
            } else {
#pragma unroll
                for (int e = 0; e < 8; e++) v[e] = 0.f;
            }
            short hh[8], ll[8];
#pragma unroll
            for (int e = 0; e < 8; e++) {
                unsigned short h = f2bf(v[e]);
                hh[e] = (short)h;
                ll[e] = (short)f2bf(v[e] - bf2f(h));
            }
            int cidx = akg * 64 + arow;
            *(bf16x8*)&sAh[cidx * 8] = *(bf16x8*)hh;
            *(bf16x8*)&sAl[cidx * 8] = *(bf16x8*)ll;
        }
#pragma unroll
        for (int itr = 0; itr < 2; itr++) {
            int cc = t + itr * 256;       // 0..511
            int col = cc >> 2;
            int kg = cc & 3;
            int go = col * 128 + k0 + kg * 8;
            int cidx = kg * 128 + col;
            *(bf16x8*)&sWh[cidx * 8] = *(const bf16x8*)&wt_h[go];
            *(bf16x8*)&sWl[cidx * 8] = *(const bf16x8*)&wt_l[go];
        }
        __syncthreads();
        bf16x8 ah[2], al[2], bh[4], bl[4];
#pragma unroll
        for (int i = 0; i < 2; i++) {
            int cidx = lkg * 64 + wr + i * 16 + lr;
            ah[i] = *(const bf16x8*)&sAh[cidx * 8];
            al[i] = *(const bf16x8*)&sAl[cidx * 8];
        }
#pragma unroll
        for (int j = 0; j < 4; j++) {
            int cidx = lkg * 128 + wc + j * 16 + lr;
            bh[j] = *(const bf16x8*)&sWh[cidx * 8];
            bl[j] = *(const bf16x8*)&sWl[cidx * 8];
        }
#pragma unroll
        for (int i = 0; i < 2; i++)
#pragma unroll
            for (int j = 0; j < 4; j++) {
                acc[i][j] = __builtin_amdgcn_mfma_f32_16x16x32_bf16(ah[i], bh[j], acc[i][j], 0, 0, 0);
                acc[i][j] = __builtin_amdgcn_mfma_f32_16x16x32_bf16(ah[i], bl[j], acc[i][j], 0, 0, 0);
                acc[i][j] = __builtin_amdgcn_mfma_f32_16x16x32_bf16(al[i], bh[j], acc[i][j], 0, 0, 0);
            }
        __syncthreads();
    }
#pragma unroll
    for (int i = 0; i < 2; i++)
#pragma unroll
        for (int q = 0; q < 4; q++) {
            int gr = row0 + wr + i * 16 + lkg * 4 + q;
            if (gr >= M) continue;
#pragma unroll
            for (int j = 0; j < 4; j++) {
                int gc = wc + j * 16 + lr;
                float v = acc[i][j][q];
                if (MODE == 0) {
                    h1f[gr * 128 + gc] = v + bsum[gc];
                } else if (MODE == 1) {
                    h1f[gr * 128 + gc] += v;
                } else {
                    float u = fmaxf(h1f[gr * 128 + gc] + v, 0.f);
                    unsigned short h = f2bf(u);
                    h1h[gr * 128 + gc] = h;
                    h1l[gr * 128 + gc] = f2bf(u - bf2f(h));
                }
            }
        }
}

// ---------------- MFMA split-bf16 GEMM, layer 2 (bf16 output) ----------------
__global__ __launch_bounds__(256) void k_mm2(const unsigned short* __restrict__ h1h,
                                             const unsigned short* __restrict__ h1l,
                                             const unsigned short* __restrict__ wt_h,
                                             const unsigned short* __restrict__ wt_l,
                                             unsigned short* __restrict__ xwb2, int M) {
    __shared__ short sAh[2048], sAl[2048];
    __shared__ short sWh[6144], sWl[6144];
    int t = threadIdx.x;
    int row0 = blockIdx.x * 64;
    int wid = t >> 6;
    int lane = t & 63;
    int lr = lane & 15;
    int lkg = lane >> 4;
    int wr = (wid & 1) * 32;
    int wc = (wid >> 1) * 96;

    f32x4 acc[2][6];
#pragma unroll
    for (int i = 0; i < 2; i++)
#pragma unroll
        for (int j = 0; j < 6; j++) acc[i][j] = (f32x4)(0.f);

    int arow = t >> 2;
    int akg = t & 3;

    for (int k0 = 0; k0 < 128; k0 += 32) {
        {
            int gr = row0 + arow;
            int cidx = akg * 64 + arow;
            if (gr < M) {
                int go = gr * 128 + k0 + akg * 8;
                *(bf16x8*)&sAh[cidx * 8] = *(const bf16x8*)&h1h[go];
                *(bf16x8*)&sAl[cidx * 8] = *(const bf16x8*)&h1l[go];
            } else {
                *(bf16x8*)&sAh[cidx * 8] = (bf16x8)(short)0;
                *(bf16x8*)&sAl[cidx * 8] = (bf16x8)(short)0;
            }
        }
#pragma unroll
        for (int itr = 0; itr < 3; itr++) {
            int cc = t + itr * 256;       // 0..767
            int col = cc >> 2;
            int kg = cc & 3;
            int go = col * 128 + k0 + kg * 8;
            int cidx = kg * 192 + col;
            *(bf16x8*)&sWh[cidx * 8] = *(const bf16x8*)&wt_h[go];
            *(bf16x8*)&sWl[cidx * 8] = *(const bf16x8*)&wt_l[go];
        }
        __syncthreads();
        bf16x8 ah[2], al[2];
#pragma unroll
        for (int i = 0; i < 2; i++) {
            int cidx = lkg * 64 + wr + i * 16 + lr;
            ah[i] = *(const bf16x8*)&sAh[cidx * 8];
            al[i] = *(const bf16x8*)&sAl[cidx * 8];
        }
#pragma unroll
        for (int j = 0; j < 6; j++) {
            int cidx = lkg * 192 + wc + j * 16 + lr;
            bf16x8 bh = *(const bf16x8*)&sWh[cidx * 8];
            bf16x8 bl = *(const bf16x8*)&sWl[cidx * 8];
#pragma unroll
            for (int i = 0; i < 2; i++) {
                acc[i][j] = __builtin_amdgcn_mfma_f32_16x16x32_bf16(ah[i], bh, acc[i][j], 0, 0, 0);
                acc[i][j] = __builtin_amdgcn_mfma_f32_16x16x32_bf16(ah[i], bl, acc[i][j], 0, 0, 0);
                acc[i][j] = __builtin_amdgcn_mfma_f32_16x16x32_bf16(al[i], bh, acc[i][j], 0, 0, 0);
            }
        }
        __syncthreads();
    }
#pragma unroll
    for (int i = 0; i < 2; i++)
#pragma unroll
        for (int q = 0; q < 4; q++) {
            int gr = row0 + wr + i * 16 + lkg * 4 + q;
            if (gr >= M) continue;
#pragma unroll
            for (int j = 0; j < 6; j++) {
                int gc = wc + j * 16 + lr;
                xwb2[gr * 192 + gc] = f2bf(acc[i][j][q]);
            }
        }
}

// ---------------- fused layer-2 aggregation (bf16 gather) ----------------
__global__ __launch_bounds__(256) void k_agg64f(const int* __restrict__ csr_off,
                                                const int* __restrict__ csr_src,
                                                const float* __restrict__ csr_coef,
                                                const float* __restrict__ norm_in,
                                                const unsigned short* __restrict__ xwb,
                                                const float* __restrict__ b2,
                                                float* __restrict__ h2) {
    int w = (blockIdx.x * 256 + threadIdx.x) >> 6;
    if (w >= N_NODES) return;
    int lane = threadIdx.x & 63;
    float acc = b2[lane] + b2[64 + lane] + b2[128 + lane];
#pragma unroll
    for (int r = 0; r < R_REL; r++) {
        const unsigned short* tab = xwb + r * 64 + lane;
        int beg = csr_off[r * N_NODES + w], end = csr_off[r * N_NODES + w + 1];
        float a = 0.f;
        int j = beg;
        for (; j + 4 <= end; j += 4) {
            int s0 = csr_src[j + 0], s1 = csr_src[j + 1];
            int s2 = csr_src[j + 2], s3 = csr_src[j + 3];
            float c0 = csr_coef[j + 0], c1 = csr_coef[j + 1];
            float c2 = csr_coef[j + 2], c3 = csr_coef[j + 3];
            float v0 = bf2f(tab[s0 * 192]);
            float v1 = bf2f(tab[s1 * 192]);
            float v2 = bf2f(tab[s2 * 192]);
            float v3 = bf2f(tab[s3 * 192]);
            a += c0 * v0; a += c1 * v1; a += c2 * v2; a += c3 * v3;
        }
        for (; j < end; j++) a += csr_coef[j] * bf2f(tab[csr_src[j] * 192]);
        acc += norm_in[r * N_NODES + w] * a;
    }
    h2[w * 64 + lane] = acc;
}

// ---------------- predictor ----------------
__global__ __launch_bounds__(256) void k_predict(const int* __restrict__ sa,
                                                 const int* __restrict__ sb,
                                                 const int* __restrict__ na,
                                                 const int* __restrict__ nb,
                                                 const float* __restrict__ h2,
                                                 float* __restrict__ out) {
    int tid = blockIdx.x * 256 + threadIdx.x;
    int p = tid >> 4;
    if (p >= 2 * E_EDGES) return;
    int lane = tid & 15;
    int ia, ib;
    if (p < E_EDGES) { ia = sa[p]; ib = sb[p]; }
    else             { ia = na[p - E_EDGES]; ib = nb[p - E_EDGES]; }
    float4 va = *(const float4*)&h2[ia * 64 + lane * 4];
    float4 vb = *(const float4*)&h2[ib * 64 + lane * 4];
    float d = va.x * vb.x + va.y * vb.y + va.z * vb.z + va.w * vb.w;
    d += __shfl_xor(d, 1);
    d += __shfl_xor(d, 2);
    d += __shfl_xor(d, 4);
    d += __shfl_xor(d, 8);
    if (lane == 0) out[p] = d;
}

// ---------------- launch ----------------

extern "C" void kernel_launch(void* const* d_in, const int* in_sizes, int n_in,
                              void* d_out, int out_size, void* d_ws, size_t ws_size,
                              hipStream_t stream) {
    (void)in_sizes; (void)n_in; (void)out_size; (void)ws_size;
    const float* x       = (const float*)d_in[0];
    const int*   src     = (const int*)d_in[1];
    const int*   dst     = (const int*)d_in[2];
    const int*   neg_src = (const int*)d_in[3];
    const int*   neg_dst = (const int*)d_in[4];
    const float* W1      = (const float*)d_in[5];
    const float* b1      = (const float*)d_in[6];
    const float* W2      = (const float*)d_in[7];
    const float* b2      = (const float*)d_in[8];
    float* out = (float*)d_out;
    float* ws  = (float*)d_ws;

    // float-offset layout (total 21,074,176 floats = 84.3 MB):
    // 0        : deg/norm [300000]
    // 300000   : csr_off [150016]   450016: cursor [150016]   600032: partials [288]
    // 600320   : csr_src [600000]   1200320: csr_coef [600000]
    // 1800320  : w1t_h/w1t_l/w2t_h/w2t_l/bsum  -> through 1874176
    // 1874176  : agg [6.4M]         (layer 2: xwb2 bf16 [4.8Mf] aliases here)
    // 8274176  : h1f [6.4M]         (layer 2: h2 [3.2Mf] aliases here)
    // 14674176 : h1h [3.2Mf]
    // 17874176 : h1l [3.2Mf]        (xb bf16 [3.2Mf] aliases here; xb dead before
    //                                mm1<2> writes h1l)
    int*   deg_i    = (int*)ws;
    float* norm_out = ws;
    float* norm_in  = ws + N_SCAN;
    int*   csr_off  = (int*)(ws + 300000);
    int*   cursor   = (int*)(ws + 450016);
    int*   partials = (int*)(ws + 600032);
    int*   csr_src  = (int*)(ws + 600320);
    float* csr_coef = ws + 1200320;
    unsigned short* w1t_h = (unsigned short*)(ws + 1800320);
    unsigned short* w1t_l = (unsigned short*)(ws + 1824896);
    unsigned short* w2t_h = (unsigned short*)(ws + 1849472);
    unsigned short* w2t_l = (unsigned short*)(ws + 1861760);
    float* bsum     = ws + 1874048;
    float* agg      = ws + 1874176;
    unsigned short* xwb2 = (unsigned short*)(ws + 1874176);
    float* h1f      = ws + 8274176;
    float* h2       = ws + 8274176;
    unsigned short* h1h = (unsigned short*)(ws + 14674176);
    unsigned short* h1l = (unsigned short*)(ws + 17874176);
    unsigned int*   xb  = (unsigned int*)(ws + 17874176);

    const int NB_RE   = (R_REL * E_EDGES + 255) / 256;
    const int NB_WAVE = (N_NODES * 64 + 255) / 256;     // 12500
    const int NB_MM   = (N_NODES + 63) / 64;            // 782

    // preprocessing
    k_zero_i32<<<(2 * N_SCAN + 255) / 256, 256, 0, stream>>>(deg_i, 2 * N_SCAN);
    k_wprep<<<192, 256, 0, stream>>>(W1, W2, b1, w1t_h, w1t_l, w2t_h, w2t_l, bsum);
    k_xprep<<<(N_NODES * 32 + 255) / 256, 256, 0, stream>>>(x, xb);
    k_count_deg<<<NB_RE, 256, 0, stream>>>(src, dst, deg_i, deg_i + N_SCAN);
    k_scan1<<<SCAN_NB, 256, 0, stream>>>(deg_i + N_SCAN, partials);
    k_scan2<<<1, 256, 0, stream>>>(partials, csr_off);
    k_scan3<<<SCAN_NB, 256, 0, stream>>>(deg_i + N_SCAN, partials, csr_off, cursor);
    k_norm<<<(2 * N_SCAN + 255) / 256, 256, 0, stream>>>(deg_i, ws, 2 * N_SCAN);
    k_bin<<<NB_RE, 256, 0, stream>>>(src, dst, norm_out, cursor, csr_src, csr_coef);

    // ---- layer 1: agg (bf16 gather) then split-bf16 MFMA GEMM into h1 ----
    for (int r = 0; r < R_REL; r++) {
        k_agg128<<<NB_WAVE, 256, 0, stream>>>(csr_off + r * N_NODES, csr_src, csr_coef,
                                              norm_in + r * N_NODES, xb, agg);
        if (r == 0)
            k_mm1<0><<<NB_MM, 256, 0, stream>>>(agg, w1t_h, w1t_l, bsum, h1f, h1h, h1l, N_NODES);
        else if (r == 1)
            k_mm1<1><<<NB_MM, 256, 0, stream>>>(agg, w1t_h + 16384, w1t_l + 16384, bsum, h1f, h1h, h1l, N_NODES);
        else
            k_mm1<2><<<NB_MM, 256, 0, stream>>>(agg, w1t_h + 32768, w1t_l + 32768, bsum, h1f, h1h, h1l, N_NODES);
    }

    // ---- layer 2: GEMM [N,128]@[128,192] -> bf16, then fused aggregation ----
    k_mm2<<<NB_MM, 256, 0, stream>>>(h1h, h1l, w2t_h, w2t_l, xwb2, N_NODES);
    k_agg64f<<<NB_WAVE, 256, 0, stream>>>(csr_off, csr_src, csr_coef, norm_in, xwb2, b2, h2);

    // ---- predictor ----
    k_predict<<<(2 * E_EDGES * 16 + 255) / 256, 256, 0, stream>>>(
        src, dst, neg_src, neg_dst, h2, out);
}

// Round 6
// 299.563 us; speedup vs baseline: 5.9242x; 1.0182x over previous
//
#include <hip/hip_runtime.h>

#define N_NODES 50000
#define E_EDGES 200000
#define R_REL 3
#define D_IN 128
#define D_HID 128
#define D_OUT 64
#define N_SCAN (R_REL * N_NODES)          // 150000
#define SCAN_NB ((N_SCAN + 1023) / 1024)  // 147
#define NCPY 8

typedef __attribute__((ext_vector_type(8))) short bf16x8;
typedef __attribute__((ext_vector_type(4))) float f32x4;

__device__ inline unsigned short f2bf(float v) {
    union { float f; unsigned int u; } x; x.f = v;
    unsigned int r = x.u + 0x7fffu + ((x.u >> 16) & 1u);
    return (unsigned short)(r >> 16);
}
__device__ inline float bf2f(unsigned short h) {
    union { unsigned int u; float f; } x; x.u = ((unsigned int)h) << 16; return x.f;
}
__device__ inline float bf_lo(unsigned int p) {
    union { unsigned int u; float f; } x; x.u = p << 16; return x.f;
}
__device__ inline float bf_hi(unsigned int p) {
    union { unsigned int u; float f; } x; x.u = p & 0xffff0000u; return x.f;
}

// ---------------- prep: zero priv hists + x->bf16 + weight transpose/split ----------------
__global__ __launch_bounds__(256) void k_prep(const float* __restrict__ x,
                                              const float* __restrict__ W1,
                                              const float* __restrict__ W2,
                                              const float* __restrict__ b1,
                                              int* __restrict__ deg_priv,
                                              unsigned int* __restrict__ xb,
                                              unsigned short* __restrict__ w1t_h,
                                              unsigned short* __restrict__ w1t_l,
                                              unsigned short* __restrict__ w2t_h,
                                              unsigned short* __restrict__ w2t_l,
                                              float* __restrict__ bsum) {
    int i = blockIdx.x * 256 + threadIdx.x;   // up to 2.4M
    if (i < NCPY * 2 * N_SCAN) deg_priv[i] = 0;
    if (i < N_NODES * 32) {
        float4 v = ((const float4*)x)[i];
        uint2 u;
        u.x = ((unsigned int)f2bf(v.y) << 16) | f2bf(v.x);
        u.y = ((unsigned int)f2bf(v.w) << 16) | f2bf(v.z);
        ((uint2*)xb)[i] = u;
    }
    if (i < R_REL * D_IN * D_HID) {  // 49152
        int r = i >> 14;
        int kk = (i >> 7) & 127;
        int c = i & 127;
        float v = W1[i];
        unsigned short h = f2bf(v);
        unsigned short l = f2bf(v - bf2f(h));
        int o = r * 16384 + c * 128 + kk;
        w1t_h[o] = h;
        w1t_l[o] = l;
    }
    if (i < R_REL * D_HID * D_OUT) {  // 24576
        int r = i >> 13;
        int kk = (i >> 6) & 127;
        int cl = i & 63;
        float v = W2[i];
        unsigned short h = f2bf(v);
        unsigned short l = f2bf(v - bf2f(h));
        int o = (r * 64 + cl) * 128 + kk;
        w2t_h[o] = h;
        w2t_l[o] = l;
    }
    if (i < 128) bsum[i] = b1[i] + b1[128 + i] + b1[256 + i];
}

// ---------------- degree count into XCD-private copies ----------------
__global__ __launch_bounds__(256) void k_count(const int* __restrict__ src,
                                               const int* __restrict__ dst,
                                               int* __restrict__ deg_priv) {
    int i = blockIdx.x * 256 + threadIdx.x;  // over R*E
    if (i >= R_REL * E_EDGES) return;
    int* p = deg_priv + (blockIdx.x & (NCPY - 1)) * (2 * N_SCAN);
    int r = i / E_EDGES;
    atomicAdd(&p[r * N_NODES + src[i]], 1);
    atomicAdd(&p[N_SCAN + r * N_NODES + dst[i]], 1);
}

// ---------------- reduce copies -> norms, deg_in, per-copy prefix ----------------
__global__ __launch_bounds__(256) void k_rednorm(const int* __restrict__ deg_priv,
                                                 float* __restrict__ norm_out,
                                                 float* __restrict__ norm_in,
                                                 int* __restrict__ deg_in,
                                                 int* __restrict__ pfx) {
    int b = blockIdx.x * 256 + threadIdx.x;
    if (b >= N_SCAN) return;
    int dout = 0;
#pragma unroll
    for (int c = 0; c < NCPY; c++) dout += deg_priv[c * (2 * N_SCAN) + b];
    int run = 0;
#pragma unroll
    for (int c = 0; c < NCPY; c++) {
        int v = deg_priv[c * (2 * N_SCAN) + N_SCAN + b];
        pfx[c * N_SCAN + b] = run;
        run += v;
    }
    deg_in[b] = run;
    norm_out[b] = rsqrtf((float)(dout > 1 ? dout : 1));
    norm_in[b] = rsqrtf((float)(run > 1 ? run : 1));
}

// ---------------- exclusive scan over deg_in (150000 ints) ----------------

__global__ __launch_bounds__(256) void k_scan1(const int* __restrict__ deg,
                                               int* __restrict__ partials) {
    __shared__ int sd[256];
    int t = threadIdx.x;
    int base = blockIdx.x * 1024 + t * 4;
    int s = 0;
#pragma unroll
    for (int k = 0; k < 4; k++) {
        int i = base + k;
        if (i < N_SCAN) s += deg[i];
    }
    sd[t] = s;
    __syncthreads();
    for (int off = 128; off > 0; off >>= 1) {
        if (t < off) sd[t] += sd[t + off];
        __syncthreads();
    }
    if (t == 0) partials[blockIdx.x] = sd[0];
}

__global__ __launch_bounds__(256) void k_scan2(int* __restrict__ partials,
                                               int* __restrict__ csr_off) {
    __shared__ int sd[256];
    int t = threadIdx.x;
    int v = (t < SCAN_NB) ? partials[t] : 0;
    sd[t] = v;
    __syncthreads();
    for (int off = 1; off < 256; off <<= 1) {
        int a = (t >= off) ? sd[t - off] : 0;
        __syncthreads();
        sd[t] += a;
        __syncthreads();
    }
    partials[t] = sd[t] - v;  // exclusive
    if (t == 255) csr_off[N_SCAN] = sd[255];
}

// also converts pfx -> private cursors (pfx += global offset)
__global__ __launch_bounds__(256) void k_scan3(const int* __restrict__ deg,
                                               const int* __restrict__ partials,
                                               int* __restrict__ csr_off,
                                               int* __restrict__ pfx) {
    __shared__ int sd[256];
    int t = threadIdx.x;
    int base = blockIdx.x * 1024 + t * 4;
    int v[4];
    int tsum = 0;
#pragma unroll
    for (int k = 0; k < 4; k++) {
        int i = base + k;
        v[k] = (i < N_SCAN) ? deg[i] : 0;
        tsum += v[k];
    }
    sd[t] = tsum;
    __syncthreads();
    for (int off = 1; off < 256; off <<= 1) {
        int a = (t >= off) ? sd[t - off] : 0;
        __syncthreads();
        sd[t] += a;
        __syncthreads();
    }
    int run = partials[blockIdx.x] + sd[t] - tsum;
#pragma unroll
    for (int k = 0; k < 4; k++) {
        int i = base + k;
        if (i < N_SCAN) {
            csr_off[i] = run;
#pragma unroll
            for (int c = 0; c < NCPY; c++) pfx[c * N_SCAN + i] += run;
            run += v[k];
        }
    }
}

// ---------------- edge binning with private cursors, packed (src,coef) ----------------
__global__ __launch_bounds__(256) void k_bin(const int* __restrict__ src,
                                             const int* __restrict__ dst,
                                             const float* __restrict__ norm_out,
                                             int* __restrict__ cursor,
                                             uint2* __restrict__ csr) {
    int i = blockIdx.x * 256 + threadIdx.x;  // over R*E
    if (i >= R_REL * E_EDGES) return;
    int* cur = cursor + (blockIdx.x & (NCPY - 1)) * N_SCAN;
    int r = i / E_EDGES;
    int s = src[i];
    int d = dst[i];
    int pos = atomicAdd(&cur[r * N_NODES + d], 1);
    uint2 e;
    e.x = (unsigned int)s;
    e.y = __float_as_uint(norm_out[r * N_NODES + s]);
    csr[pos] = e;
}

// ---------------- CSR aggregation layer 1 (bf16 gather, fp32 accum) ----------------
__global__ __launch_bounds__(256) void k_agg128(const int* __restrict__ csr_off,
                                                const uint2* __restrict__ csr,
                                                const float* __restrict__ norm_in,
                                                const unsigned int* __restrict__ xb,
                                                float* __restrict__ agg) {
    int w = (blockIdx.x * 256 + threadIdx.x) >> 6;
    if (w >= N_NODES) return;
    int lane = threadIdx.x & 63;
    const unsigned int* tab = xb + lane;     // row stride 64 uints
    int beg = csr_off[w], end = csr_off[w + 1];
    float ax = 0.f, ay = 0.f;
    int j = beg;
    for (; j + 4 <= end; j += 4) {
        uint2 e0 = csr[j + 0], e1 = csr[j + 1];
        uint2 e2 = csr[j + 2], e3 = csr[j + 3];
        unsigned int p0 = tab[e0.x * 64], p1 = tab[e1.x * 64];
        unsigned int p2 = tab[e2.x * 64], p3 = tab[e3.x * 64];
        float c0 = __uint_as_float(e0.y), c1 = __uint_as_float(e1.y);
        float c2 = __uint_as_float(e2.y), c3 = __uint_as_float(e3.y);
        ax += c0 * bf_lo(p0); ay += c0 * bf_hi(p0);
        ax += c1 * bf_lo(p1); ay += c1 * bf_hi(p1);
        ax += c2 * bf_lo(p2); ay += c2 * bf_hi(p2);
        ax += c3 * bf_lo(p3); ay += c3 * bf_hi(p3);
    }
    for (; j < end; j++) {
        uint2 e = csr[j];
        float c = __uint_as_float(e.y);
        unsigned int p = tab[e.x * 64];
        ax += c * bf_lo(p);
        ay += c * bf_hi(p);
    }
    float ni = norm_in[w];
    float2 o;
    o.x = ax * ni;
    o.y = ay * ni;
    *(float2*)&agg[w * 128 + lane * 2] = o;
}

// ---------------- MFMA split-bf16 GEMM, layer 1 ----------------
// MODE 0: h1f = acc + bsum ; MODE 1: h1f += acc ; MODE 2: relu(h1f+acc) -> split h1h/h1l
template <int MODE>
__global__ __launch_bounds__(256) void k_mm1(const float* __restrict__ A,
                                             const unsigned short* __restrict__ wt_h,
                                             const unsigned short* __restrict__ wt_l,
                                             const float* __restrict__ bsum,
                                             float* __restrict__ h1f,
                                             unsigned short* __restrict__ h1h,
                                             unsigned short* __restrict__ h1l,
                                             int M) {
    __shared__ short sAh[2048], sAl[2048];     // [4 kg][64 row][8]
    __shared__ short sWh[4096], sWl[4096];     // [4 kg][128 col][8]
    int t = threadIdx.x;
    int row0 = blockIdx.x * 64;
    int wid = t >> 6;
    int lane = t & 63;
    int lr = lane & 15;
    int lkg = lane >> 4;
    int wr = (wid & 1) * 32;
    int wc = (wid >> 1) * 64;

    f32x4 acc[2][4];
#pragma unroll
    for (int i = 0; i < 2; i++)
#pragma unroll
        for (int j = 0; j < 4; j++) acc[i][j] = (f32x4)(0.f);

    int arow = t >> 2;       // 0..63
    int akg = t & 3;         // 0..3

    for (int k0 = 0; k0 < 128; k0 += 32) {
        {
            int gr = row0 + arow;
            float v[8];
            if (gr < M) {
                float4 p0 = *(const float4*)&A[gr * 128 + k0 + akg * 8];
                float4 p1 = *(const float4*)&A[gr * 128 + k0 + akg * 8 + 4];
                v[0] = p0.x; v[1] = p0.y; v[2] = p0.z; v[3] = p0.w;
                v[4] = p1.x; v[5] = p1.y; v[6] = p1.z; v[7] = p1.w;
            } else {
#pragma unroll
                for (int e = 0; e < 8; e++) v[e] = 0.f;
            }
            short hh[8], ll[8];
#pragma unroll
            for (int e = 0; e < 8; e++) {
                unsigned short h = f2bf(v[e]);
                hh[e] = (short)h;
                ll[e] = (short)f2bf(v[e] - bf2f(h));
            }
            int cidx = akg * 64 + arow;
            *(bf16x8*)&sAh[cidx * 8] = *(bf16x8*)hh;
            *(bf16x8*)&sAl[cidx * 8] = *(bf16x8*)ll;
        }
#pragma unroll
        for (int itr = 0; itr < 2; itr++) {
            int cc = t + itr * 256;       // 0..511
            int col = cc >> 2;
            int kg = cc & 3;
            int go = col * 128 + k0 + kg * 8;
            int cidx = kg * 128 + col;
            *(bf16x8*)&sWh[cidx * 8] = *(const bf16x8*)&wt_h[go];
            *(bf16x8*)&sWl[cidx * 8] = *(const bf16x8*)&wt_l[go];
        }
        __syncthreads();
        bf16x8 ah[2], al[2], bh[4], bl[4];
#pragma unroll
        for (int i = 0; i < 2; i++) {
            int cidx = lkg * 64 + wr + i * 16 + lr;
            ah[i] = *(const bf16x8*)&sAh[cidx * 8];
            al[i] = *(const bf16x8*)&sAl[cidx * 8];
        }
#pragma unroll
        for (int j = 0; j < 4; j++) {
            int cidx = lkg * 128 + wc + j * 16 + lr;
            bh[j] = *(const bf16x8*)&sWh[cidx * 8];
            bl[j] = *(const bf16x8*)&sWl[cidx * 8];
        }
#pragma unroll
        for (int i = 0; i < 2; i++)
#pragma unroll
            for (int j = 0; j < 4; j++) {
                acc[i][j] = __builtin_amdgcn_mfma_f32_16x16x32_bf16(ah[i], bh[j], acc[i][j], 0, 0, 0);
                acc[i][j] = __builtin_amdgcn_mfma_f32_16x16x32_bf16(ah[i], bl[j], acc[i][j], 0, 0, 0);
                acc[i][j] = __builtin_amdgcn_mfma_f32_16x16x32_bf16(al[i], bh[j], acc[i][j], 0, 0, 0);
            }
        __syncthreads();
    }
#pragma unroll
    for (int i = 0; i < 2; i++)
#pragma unroll
        for (int q = 0; q < 4; q++) {
            int gr = row0 + wr + i * 16 + lkg * 4 + q;
            if (gr >= M) continue;
#pragma unroll
            for (int j = 0; j < 4; j++) {
                int gc = wc + j * 16 + lr;
                float v = acc[i][j][q];
                if (MODE == 0) {
                    h1f[gr * 128 + gc] = v + bsum[gc];
                } else if (MODE == 1) {
                    h1f[gr * 128 + gc] += v;
                } else {
                    float u = fmaxf(h1f[gr * 128 + gc] + v, 0.f);
                    unsigned short h = f2bf(u);
                    h1h[gr * 128 + gc] = h;
                    h1l[gr * 128 + gc] = f2bf(u - bf2f(h));
                }
            }
        }
}

// ---------------- MFMA split-bf16 GEMM, layer 2 (bf16 output) ----------------
__global__ __launch_bounds__(256) void k_mm2(const unsigned short* __restrict__ h1h,
                                             const unsigned short* __restrict__ h1l,
                                             const unsigned short* __restrict__ wt_h,
                                             const unsigned short* __restrict__ wt_l,
                                             unsigned short* __restrict__ xwb2, int M) {
    __shared__ short sAh[2048], sAl[2048];
    __shared__ short sWh[6144], sWl[6144];
    int t = threadIdx.x;
    int row0 = blockIdx.x * 64;
    int wid = t >> 6;
    int lane = t & 63;
    int lr = lane & 15;
    int lkg = lane >> 4;
    int wr = (wid & 1) * 32;
    int wc = (wid >> 1) * 96;

    f32x4 acc[2][6];
#pragma unroll
    for (int i = 0; i < 2; i++)
#pragma unroll
        for (int j = 0; j < 6; j++) acc[i][j] = (f32x4)(0.f);

    int arow = t >> 2;
    int akg = t & 3;

    for (int k0 = 0; k0 < 128; k0 += 32) {
        {
            int gr = row0 + arow;
            int cidx = akg * 64 + arow;
            if (gr < M) {
                int go = gr * 128 + k0 + akg * 8;
                *(bf16x8*)&sAh[cidx * 8] = *(const bf16x8*)&h1h[go];
                *(bf16x8*)&sAl[cidx * 8] = *(const bf16x8*)&h1l[go];
            } else {
                *(bf16x8*)&sAh[cidx * 8] = (bf16x8)(short)0;
                *(bf16x8*)&sAl[cidx * 8] = (bf16x8)(short)0;
            }
        }
#pragma unroll
        for (int itr = 0; itr < 3; itr++) {
            int cc = t + itr * 256;       // 0..767
            int col = cc >> 2;
            int kg = cc & 3;
            int go = col * 128 + k0 + kg * 8;
            int cidx = kg * 192 + col;
            *(bf16x8*)&sWh[cidx * 8] = *(const bf16x8*)&wt_h[go];
            *(bf16x8*)&sWl[cidx * 8] = *(const bf16x8*)&wt_l[go];
        }
        __syncthreads();
        bf16x8 ah[2], al[2];
#pragma unroll
        for (int i = 0; i < 2; i++) {
            int cidx = lkg * 64 + wr + i * 16 + lr;
            ah[i] = *(const bf16x8*)&sAh[cidx * 8];
            al[i] = *(const bf16x8*)&sAl[cidx * 8];
        }
#pragma unroll
        for (int j = 0; j < 6; j++) {
            int cidx = lkg * 192 + wc + j * 16 + lr;
            bf16x8 bh = *(const bf16x8*)&sWh[cidx * 8];
            bf16x8 bl = *(const bf16x8*)&sWl[cidx * 8];
#pragma unroll
            for (int i = 0; i < 2; i++) {
                acc[i][j] = __builtin_amdgcn_mfma_f32_16x16x32_bf16(ah[i], bh, acc[i][j], 0, 0, 0);
                acc[i][j] = __builtin_amdgcn_mfma_f32_16x16x32_bf16(ah[i], bl, acc[i][j], 0, 0, 0);
                acc[i][j] = __builtin_amdgcn_mfma_f32_16x16x32_bf16(al[i], bh, acc[i][j], 0, 0, 0);
            }
        }
        __syncthreads();
    }
#pragma unroll
    for (int i = 0; i < 2; i++)
#pragma unroll
        for (int q = 0; q < 4; q++) {
            int gr = row0 + wr + i * 16 + lkg * 4 + q;
            if (gr >= M) continue;
#pragma unroll
            for (int j = 0; j < 6; j++) {
                int gc = wc + j * 16 + lr;
                xwb2[gr * 192 + gc] = f2bf(acc[i][j][q]);
            }
        }
}

// ---------------- fused layer-2 aggregation (bf16 gather) ----------------
__global__ __launch_bounds__(256) void k_agg64f(const int* __restrict__ csr_off,
                                                const uint2* __restrict__ csr,
                                                const float* __restrict__ norm_in,
                                                const unsigned short* __restrict__ xwb,
                                                const float* __restrict__ b2,
                                                float* __restrict__ h2) {
    int w = (blockIdx.x * 256 + threadIdx.x) >> 6;
    if (w >= N_NODES) return;
    int lane = threadIdx.x & 63;
    float acc = b2[lane] + b2[64 + lane] + b2[128 + lane];
#pragma unroll
    for (int r = 0; r < R_REL; r++) {
        const unsigned short* tab = xwb + r * 64 + lane;
        int beg = csr_off[r * N_NODES + w], end = csr_off[r * N_NODES + w + 1];
        float a = 0.f;
        int j = beg;
        for (; j + 4 <= end; j += 4) {
            uint2 e0 = csr[j + 0], e1 = csr[j + 1];
            uint2 e2 = csr[j + 2], e3 = csr[j + 3];
            float v0 = bf2f(tab[e0.x * 192]);
            float v1 = bf2f(tab[e1.x * 192]);
            float v2 = bf2f(tab[e2.x * 192]);
            float v3 = bf2f(tab[e3.x * 192]);
            a += __uint_as_float(e0.y) * v0;
            a += __uint_as_float(e1.y) * v1;
            a += __uint_as_float(e2.y) * v2;
            a += __uint_as_float(e3.y) * v3;
        }
        for (; j < end; j++) {
            uint2 e = csr[j];
            a += __uint_as_float(e.y) * bf2f(tab[e.x * 192]);
        }
        acc += norm_in[r * N_NODES + w] * a;
    }
    h2[w * 64 + lane] = acc;
}

// ---------------- predictor ----------------
__global__ __launch_bounds__(256) void k_predict(const int* __restrict__ sa,
                                                 const int* __restrict__ sb,
                                                 const int* __restrict__ na,
                                                 const int* __restrict__ nb,
                                                 const float* __restrict__ h2,
                                                 float* __restrict__ out) {
    int tid = blockIdx.x * 256 + threadIdx.x;
    int p = tid >> 4;
    if (p >= 2 * E_EDGES) return;
    int lane = tid & 15;
    int ia, ib;
    if (p < E_EDGES) { ia = sa[p]; ib = sb[p]; }
    else             { ia = na[p - E_EDGES]; ib = nb[p - E_EDGES]; }
    float4 va = *(const float4*)&h2[ia * 64 + lane * 4];
    float4 vb = *(const float4*)&h2[ib * 64 + lane * 4];
    float d = va.x * vb.x + va.y * vb.y + va.z * vb.z + va.w * vb.w;
    d += __shfl_xor(d, 1);
    d += __shfl_xor(d, 2);
    d += __shfl_xor(d, 4);
    d += __shfl_xor(d, 8);
    if (lane == 0) out[p] = d;
}

// ---------------- launch ----------------

extern "C" void kernel_launch(void* const* d_in, const int* in_sizes, int n_in,
                              void* d_out, int out_size, void* d_ws, size_t ws_size,
                              hipStream_t stream) {
    (void)in_sizes; (void)n_in; (void)out_size; (void)ws_size;
    const float* x       = (const float*)d_in[0];
    const int*   src     = (const int*)d_in[1];
    const int*   dst     = (const int*)d_in[2];
    const int*   neg_src = (const int*)d_in[3];
    const int*   neg_dst = (const int*)d_in[4];
    const float* W1      = (const float*)d_in[5];
    const float* b1      = (const float*)d_in[6];
    const float* W2      = (const float*)d_in[7];
    const float* b2      = (const float*)d_in[8];
    float* out = (float*)d_out;
    float* ws  = (float*)d_ws;

    // float-offset layout (total 22,274,176 floats = 89.1 MB; ws >= 96.8 MB proven):
    // 0        : norm_out [150000]   150000: norm_in [150000]
    // 300000   : deg_in int [150000]
    // 450016   : csr_off [150016]    600032: partials [288]
    // 600320   : pfx/cursor [8*150000 = 1.2M]
    // 1800320  : csr packed uint2 [600000 -> 1.2M units]
    // 3000320  : w1t_h [24576] 3024896: w1t_l [24576] 3049472: w2t_h [12288]
    // 3061760  : w2t_l [12288] 3074048: bsum [128]
    // 3074176  : agg [6.4M]     (aliases: deg_priv 2.4M ints early; xwb2 4.8M late)
    // 9474176  : h1f [6.4M]     (alias: h2 3.2M late)
    // 15874176 : h1h [3.2M]
    // 19074176 : h1l [3.2M]     (alias: xb 3.2M early; dead before mm1<2> writes h1l)
    float* norm_out = ws;
    float* norm_in  = ws + N_SCAN;
    int*   deg_in   = (int*)(ws + 300000);
    int*   csr_off  = (int*)(ws + 450016);
    int*   partials = (int*)(ws + 600032);
    int*   pfx      = (int*)(ws + 600320);
    uint2* csr      = (uint2*)(ws + 1800320);
    unsigned short* w1t_h = (unsigned short*)(ws + 3000320);
    unsigned short* w1t_l = (unsigned short*)(ws + 3024896);
    unsigned short* w2t_h = (unsigned short*)(ws + 3049472);
    unsigned short* w2t_l = (unsigned short*)(ws + 3061760);
    float* bsum     = ws + 3074048;
    float* agg      = ws + 3074176;
    int*   deg_priv = (int*)(ws + 3074176);
    unsigned short* xwb2 = (unsigned short*)(ws + 3074176);
    float* h1f      = ws + 9474176;
    float* h2       = ws + 9474176;
    unsigned short* h1h = (unsigned short*)(ws + 15874176);
    unsigned short* h1l = (unsigned short*)(ws + 19074176);
    unsigned int*   xb  = (unsigned int*)(ws + 19074176);

    const int NB_RE   = (R_REL * E_EDGES + 255) / 256;   // 2344
    const int NB_WAVE = (N_NODES * 64 + 255) / 256;      // 12500
    const int NB_MM   = (N_NODES + 63) / 64;             // 782

    // preprocessing
    k_prep<<<(NCPY * 2 * N_SCAN + 255) / 256, 256, 0, stream>>>(
        x, W1, W2, b1, deg_priv, xb, w1t_h, w1t_l, w2t_h, w2t_l, bsum);
    k_count<<<NB_RE, 256, 0, stream>>>(src, dst, deg_priv);
    k_rednorm<<<(N_SCAN + 255) / 256, 256, 0, stream>>>(deg_priv, norm_out, norm_in,
                                                        deg_in, pfx);
    k_scan1<<<SCAN_NB, 256, 0, stream>>>(deg_in, partials);
    k_scan2<<<1, 256, 0, stream>>>(partials, csr_off);
    k_scan3<<<SCAN_NB, 256, 0, stream>>>(deg_in, partials, csr_off, pfx);
    k_bin<<<NB_RE, 256, 0, stream>>>(src, dst, norm_out, pfx, csr);

    // ---- layer 1: agg (bf16 gather) then split-bf16 MFMA GEMM into h1 ----
    for (int r = 0; r < R_REL; r++) {
        k_agg128<<<NB_WAVE, 256, 0, stream>>>(csr_off + r * N_NODES, csr,
                                              norm_in + r * N_NODES, xb, agg);
        if (r == 0)
            k_mm1<0><<<NB_MM, 256, 0, stream>>>(agg, w1t_h, w1t_l, bsum, h1f, h1h, h1l, N_NODES);
        else if (r == 1)
            k_mm1<1><<<NB_MM, 256, 0, stream>>>(agg, w1t_h + 16384, w1t_l + 16384, bsum, h1f, h1h, h1l, N_NODES);
        else
            k_mm1<2><<<NB_MM, 256, 0, stream>>>(agg, w1t_h + 32768, w1t_l + 32768, bsum, h1f, h1h, h1l, N_NODES);
    }

    // ---- layer 2: GEMM [N,128]@[128,192] -> bf16, then fused aggregation ----
    k_mm2<<<NB_MM, 256, 0, stream>>>(h1h, h1l, w2t_h, w2t_l, xwb2, N_NODES);
    k_agg64f<<<NB_WAVE, 256, 0, stream>>>(csr_off, csr, norm_in, xwb2, b2, h2);

    // ---- predictor ----
    k_predict<<<(2 * E_EDGES * 16 + 255) / 256, 256, 0, stream>>>(
        src, dst, neg_src, neg_dst, h2, out);
}

// Round 7
// 272.235 us; speedup vs baseline: 6.5189x; 1.1004x over previous
//
#include <hip/hip_runtime.h>

#define N_NODES 50000
#define E_EDGES 200000
#define R_REL 3
#define D_IN 128
#define D_HID 128
#define D_OUT 64
#define N_SCAN (R_REL * N_NODES)          // 150000
#define BCAP 16
#define OVCAP 4096

typedef __attribute__((ext_vector_type(8))) short bf16x8;
typedef __attribute__((ext_vector_type(4))) float f32x4;

__device__ inline unsigned short f2bf(float v) {
    union { float f; unsigned int u; } x; x.f = v;
    unsigned int r = x.u + 0x7fffu + ((x.u >> 16) & 1u);
    return (unsigned short)(r >> 16);
}
__device__ inline float bf2f(unsigned short h) {
    union { unsigned int u; float f; } x; x.u = ((unsigned int)h) << 16; return x.f;
}
__device__ inline float bf_lo(unsigned int p) {
    union { unsigned int u; float f; } x; x.u = p << 16; return x.f;
}
__device__ inline float bf_hi(unsigned int p) {
    union { unsigned int u; float f; } x; x.u = p & 0xffff0000u; return x.f;
}

// ---------------- zero counters ----------------
__global__ __launch_bounds__(256) void k_zero_i32(int* __restrict__ p, int n) {
    int i = blockIdx.x * 256 + threadIdx.x;
    if (i < n) p[i] = 0;
}

// ---------------- fused: edge count+bucket scatter, x->bf16, weight prep ----------------
__global__ __launch_bounds__(256) void k_count_prep(const int* __restrict__ src,
                                                    const int* __restrict__ dst,
                                                    const float* __restrict__ x,
                                                    const float* __restrict__ W1,
                                                    const float* __restrict__ W2,
                                                    const float* __restrict__ b1,
                                                    int* __restrict__ deg_out,
                                                    int* __restrict__ cnt_in,
                                                    int* __restrict__ ov_cnt,
                                                    uint2* __restrict__ ovlist,
                                                    int* __restrict__ bucket,
                                                    unsigned int* __restrict__ xb,
                                                    unsigned short* __restrict__ w1t_h,
                                                    unsigned short* __restrict__ w1t_l,
                                                    unsigned short* __restrict__ w2t_h,
                                                    unsigned short* __restrict__ w2t_l,
                                                    float* __restrict__ bsum) {
    int i = blockIdx.x * 256 + threadIdx.x;
    // ---- streaming prep (independent of atomics) ----
    if (i < 400000) {  // 4 float4s each over N*128 floats
#pragma unroll
        for (int k = 0; k < 4; k++) {
            int q = i * 4 + k;
            float4 v = ((const float4*)x)[q];
            uint2 u;
            u.x = ((unsigned int)f2bf(v.y) << 16) | f2bf(v.x);
            u.y = ((unsigned int)f2bf(v.w) << 16) | f2bf(v.z);
            ((uint2*)xb)[q] = u;
        }
    }
    if (i < R_REL * D_IN * D_HID) {  // 49152
        int r = i >> 14;
        int kk = (i >> 7) & 127;
        int c = i & 127;
        float v = W1[i];
        unsigned short h = f2bf(v);
        unsigned short l = f2bf(v - bf2f(h));
        int o = r * 16384 + c * 128 + kk;
        w1t_h[o] = h;
        w1t_l[o] = l;
    }
    if (i < R_REL * D_HID * D_OUT) {  // 24576
        int r = i >> 13;
        int kk = (i >> 6) & 127;
        int cl = i & 63;
        float v = W2[i];
        unsigned short h = f2bf(v);
        unsigned short l = f2bf(v - bf2f(h));
        int o = (r * 64 + cl) * 128 + kk;
        w2t_h[o] = h;
        w2t_l[o] = l;
    }
    if (i < 128) bsum[i] = b1[i] + b1[128 + i] + b1[256 + i];
    // ---- edge pass: count + bucket scatter ----
    if (i < R_REL * E_EDGES) {
        int r = i / E_EDGES;
        int s = src[i];
        int d = dst[i];
        atomicAdd(&deg_out[r * N_NODES + s], 1);
        int bin = r * N_NODES + d;
        int pos = atomicAdd(&cnt_in[bin], 1);
        if (pos < BCAP) {
            bucket[bin * BCAP + pos] = s;
        } else {
            int oi = atomicAdd(ov_cnt, 1);
            if (oi < OVCAP) {
                uint2 e;
                e.x = (unsigned int)bin;
                e.y = (unsigned int)s;
                ovlist[oi] = e;
            }
        }
    }
}

// ---------------- norms from counts ----------------
__global__ __launch_bounds__(256) void k_rednorm(const int* __restrict__ deg_out,
                                                 const int* __restrict__ cnt_in,
                                                 float* __restrict__ norm_out,
                                                 float* __restrict__ norm_in) {
    int b = blockIdx.x * 256 + threadIdx.x;
    if (b >= N_SCAN) return;
    int o = deg_out[b];
    int d = cnt_in[b];
    norm_out[b] = rsqrtf((float)(o > 1 ? o : 1));
    norm_in[b] = rsqrtf((float)(d > 1 ? d : 1));
}

// ---------------- bucket aggregation layer 1 (bf16 gather, fp32 accum) ----------------
// One wave per dst node; lane handles feats 2*lane, 2*lane+1 (one packed uint).
__global__ __launch_bounds__(256) void k_agg128(const int* __restrict__ cnt_r,
                                                const int* __restrict__ bucket_r,
                                                const float* __restrict__ nout_r,
                                                const float* __restrict__ nin_r,
                                                const int* __restrict__ ov_cnt,
                                                const uint2* __restrict__ ovlist,
                                                int rbase,
                                                const unsigned int* __restrict__ xb,
                                                float* __restrict__ agg) {
    int w = (blockIdx.x * 256 + threadIdx.x) >> 6;
    if (w >= N_NODES) return;
    int lane = threadIdx.x & 63;
    const unsigned int* tab = xb + lane;     // row stride 64 uints
    int n = cnt_r[w];
    int nn = n < BCAP ? n : BCAP;
    float ax = 0.f, ay = 0.f;
    int j = 0;
    for (; j + 4 <= nn; j += 4) {
        uint4 s4 = *(const uint4*)&bucket_r[w * BCAP + j];
        float c0 = nout_r[s4.x], c1 = nout_r[s4.y];
        float c2 = nout_r[s4.z], c3 = nout_r[s4.w];
        unsigned int p0 = tab[s4.x * 64], p1 = tab[s4.y * 64];
        unsigned int p2 = tab[s4.z * 64], p3 = tab[s4.w * 64];
        ax += c0 * bf_lo(p0); ay += c0 * bf_hi(p0);
        ax += c1 * bf_lo(p1); ay += c1 * bf_hi(p1);
        ax += c2 * bf_lo(p2); ay += c2 * bf_hi(p2);
        ax += c3 * bf_lo(p3); ay += c3 * bf_hi(p3);
    }
    for (; j < nn; j++) {
        unsigned int s = (unsigned int)bucket_r[w * BCAP + j];
        float c = nout_r[s];
        unsigned int p = tab[s * 64];
        ax += c * bf_lo(p);
        ay += c * bf_hi(p);
    }
    int oc = *ov_cnt;
    if (oc > 0) {
        if (oc > OVCAP) oc = OVCAP;
        for (int k = 0; k < oc; k++) {
            uint2 e = ovlist[k];
            if ((int)e.x == rbase + w) {
                float c = nout_r[e.y];
                unsigned int p = tab[e.y * 64];
                ax += c * bf_lo(p);
                ay += c * bf_hi(p);
            }
        }
    }
    float ni = nin_r[w];
    float2 o;
    o.x = ax * ni;
    o.y = ay * ni;
    *(float2*)&agg[w * 128 + lane * 2] = o;
}

// ---------------- MFMA split-bf16 GEMM, layer 1 ----------------
// MODE 0: h1f = acc + bsum ; MODE 1: h1f += acc ; MODE 2: relu(h1f+acc) -> split h1h/h1l
template <int MODE>
__global__ __launch_bounds__(256) void k_mm1(const float* __restrict__ A,
                                             const unsigned short* __restrict__ wt_h,
                                             const unsigned short* __restrict__ wt_l,
                                             const float* __restrict__ bsum,
                                             float* __restrict__ h1f,
                                             unsigned short* __restrict__ h1h,
                                             unsigned short* __restrict__ h1l,
                                             int M) {
    __shared__ short sAh[2048], sAl[2048];     // [4 kg][64 row][8]
    __shared__ short sWh[4096], sWl[4096];     // [4 kg][128 col][8]
    int t = threadIdx.x;
    int row0 = blockIdx.x * 64;
    int wid = t >> 6;
    int lane = t & 63;
    int lr = lane & 15;
    int lkg = lane >> 4;
    int wr = (wid & 1) * 32;
    int wc = (wid >> 1) * 64;

    f32x4 acc[2][4];
#pragma unroll
    for (int i = 0; i < 2; i++)
#pragma unroll
        for (int j = 0; j < 4; j++) acc[i][j] = (f32x4)(0.f);

    int arow = t >> 2;       // 0..63
    int akg = t & 3;         // 0..3

    for (int k0 = 0; k0 < 128; k0 += 32) {
        {
            int gr = row0 + arow;
            float v[8];
            if (gr < M) {
                float4 p0 = *(const float4*)&A[gr * 128 + k0 + akg * 8];
                float4 p1 = *(const float4*)&A[gr * 128 + k0 + akg * 8 + 4];
                v[0] = p0.x; v[1] = p0.y; v[2] = p0.z; v[3] = p0.w;
                v[4] = p1.x; v[5] = p1.y; v[6] = p1.z; v[7] = p1.w;
            } else {
#pragma unroll
                for (int e = 0; e < 8; e++) v[e] = 0.f;
            }
            short hh[8], ll[8];
#pragma unroll
            for (int e = 0; e < 8; e++) {
                unsigned short h = f2bf(v[e]);
                hh[e] = (short)h;
                ll[e] = (short)f2bf(v[e] - bf2f(h));
            }
            int cidx = akg * 64 + arow;
            *(bf16x8*)&sAh[cidx * 8] = *(bf16x8*)hh;
            *(bf16x8*)&sAl[cidx * 8] = *(bf16x8*)ll;
        }
#pragma unroll
        for (int itr = 0; itr < 2; itr++) {
            int cc = t + itr * 256;       // 0..511
            int col = cc >> 2;
            int kg = cc & 3;
            int go = col * 128 + k0 + kg * 8;
            int cidx = kg * 128 + col;
            *(bf16x8*)&sWh[cidx * 8] = *(const bf16x8*)&wt_h[go];
            *(bf16x8*)&sWl[cidx * 8] = *(const bf16x8*)&wt_l[go];
        }
        __syncthreads();
        bf16x8 ah[2], al[2], bh[4], bl[4];
#pragma unroll
        for (int i = 0; i < 2; i++) {
            int cidx = lkg * 64 + wr + i * 16 + lr;
            ah[i] = *(const bf16x8*)&sAh[cidx * 8];
            al[i] = *(const bf16x8*)&sAl[cidx * 8];
        }
#pragma unroll
        for (int j = 0; j < 4; j++) {
            int cidx = lkg * 128 + wc + j * 16 + lr;
            bh[j] = *(const bf16x8*)&sWh[cidx * 8];
            bl[j] = *(const bf16x8*)&sWl[cidx * 8];
        }
#pragma unroll
        for (int i = 0; i < 2; i++)
#pragma unroll
            for (int j = 0; j < 4; j++) {
                acc[i][j] = __builtin_amdgcn_mfma_f32_16x16x32_bf16(ah[i], bh[j], acc[i][j], 0, 0, 0);
                acc[i][j] = __builtin_amdgcn_mfma_f32_16x16x32_bf16(ah[i], bl[j], acc[i][j], 0, 0, 0);
                acc[i][j] = __builtin_amdgcn_mfma_f32_16x16x32_bf16(al[i], bh[j], acc[i][j], 0, 0, 0);
            }
        __syncthreads();
    }
#pragma unroll
    for (int i = 0; i < 2; i++)
#pragma unroll
        for (int q = 0; q < 4; q++) {
            int gr = row0 + wr + i * 16 + lkg * 4 + q;
            if (gr >= M) continue;
#pragma unroll
            for (int j = 0; j < 4; j++) {
                int gc = wc + j * 16 + lr;
                float v = acc[i][j][q];
                if (MODE == 0) {
                    h1f[gr * 128 + gc] = v + bsum[gc];
                } else if (MODE == 1) {
                    h1f[gr * 128 + gc] += v;
                } else {
                    float u = fmaxf(h1f[gr * 128 + gc] + v, 0.f);
                    unsigned short h = f2bf(u);
                    h1h[gr * 128 + gc] = h;
                    h1l[gr * 128 + gc] = f2bf(u - bf2f(h));
                }
            }
        }
}

// ---------------- MFMA split-bf16 GEMM, layer 2 (bf16 out, norm_out folded) ----------------
__global__ __launch_bounds__(256) void k_mm2(const unsigned short* __restrict__ h1h,
                                             const unsigned short* __restrict__ h1l,
                                             const unsigned short* __restrict__ wt_h,
                                             const unsigned short* __restrict__ wt_l,
                                             const float* __restrict__ norm_out,
                                             unsigned short* __restrict__ xwb2, int M) {
    __shared__ short sAh[2048], sAl[2048];
    __shared__ short sWh[6144], sWl[6144];
    int t = threadIdx.x;
    int row0 = blockIdx.x * 64;
    int wid = t >> 6;
    int lane = t & 63;
    int lr = lane & 15;
    int lkg = lane >> 4;
    int wr = (wid & 1) * 32;
    int wc = (wid >> 1) * 96;

    f32x4 acc[2][6];
#pragma unroll
    for (int i = 0; i < 2; i++)
#pragma unroll
        for (int j = 0; j < 6; j++) acc[i][j] = (f32x4)(0.f);

    int arow = t >> 2;
    int akg = t & 3;

    for (int k0 = 0; k0 < 128; k0 += 32) {
        {
            int gr = row0 + arow;
            int cidx = akg * 64 + arow;
            if (gr < M) {
                int go = gr * 128 + k0 + akg * 8;
                *(bf16x8*)&sAh[cidx * 8] = *(const bf16x8*)&h1h[go];
                *(bf16x8*)&sAl[cidx * 8] = *(const bf16x8*)&h1l[go];
            } else {
                *(bf16x8*)&sAh[cidx * 8] = (bf16x8)(short)0;
                *(bf16x8*)&sAl[cidx * 8] = (bf16x8)(short)0;
            }
        }
#pragma unroll
        for (int itr = 0; itr < 3; itr++) {
            int cc = t + itr * 256;       // 0..767
            int col = cc >> 2;
            int kg = cc & 3;
            int go = col * 128 + k0 + kg * 8;
            int cidx = kg * 192 + col;
            *(bf16x8*)&sWh[cidx * 8] = *(const bf16x8*)&wt_h[go];
            *(bf16x8*)&sWl[cidx * 8] = *(const bf16x8*)&wt_l[go];
        }
        __syncthreads();
        bf16x8 ah[2], al[2];
#pragma unroll
        for (int i = 0; i < 2; i++) {
            int cidx = lkg * 64 + wr + i * 16 + lr;
            ah[i] = *(const bf16x8*)&sAh[cidx * 8];
            al[i] = *(const bf16x8*)&sAl[cidx * 8];
        }
#pragma unroll
        for (int j = 0; j < 6; j++) {
            int cidx = lkg * 192 + wc + j * 16 + lr;
            bf16x8 bh = *(const bf16x8*)&sWh[cidx * 8];
            bf16x8 bl = *(const bf16x8*)&sWl[cidx * 8];
#pragma unroll
            for (int i = 0; i < 2; i++) {
                acc[i][j] = __builtin_amdgcn_mfma_f32_16x16x32_bf16(ah[i], bh, acc[i][j], 0, 0, 0);
                acc[i][j] = __builtin_amdgcn_mfma_f32_16x16x32_bf16(ah[i], bl, acc[i][j], 0, 0, 0);
                acc[i][j] = __builtin_amdgcn_mfma_f32_16x16x32_bf16(al[i], bh, acc[i][j], 0, 0, 0);
            }
        }
        __syncthreads();
    }
#pragma unroll
    for (int i = 0; i < 2; i++)
#pragma unroll
        for (int q = 0; q < 4; q++) {
            int gr = row0 + wr + i * 16 + lkg * 4 + q;
            if (gr >= M) continue;
#pragma unroll
            for (int j = 0; j < 6; j++) {
                int gc = wc + j * 16 + lr;
                float sc = norm_out[(gc >> 6) * N_NODES + gr];
                xwb2[gr * 192 + gc] = f2bf(acc[i][j][q] * sc);
            }
        }
}

// ---------------- fused layer-2 aggregation (bf16 gather, coef pre-folded) ----------------
__global__ __launch_bounds__(256) void k_agg64f(const int* __restrict__ cnt_in,
                                                const int* __restrict__ bucket,
                                                const float* __restrict__ norm_in,
                                                const int* __restrict__ ov_cnt,
                                                const uint2* __restrict__ ovlist,
                                                const unsigned short* __restrict__ xwb,
                                                const float* __restrict__ b2,
                                                unsigned short* __restrict__ h2b) {
    int w = (blockIdx.x * 256 + threadIdx.x) >> 6;
    if (w >= N_NODES) return;
    int lane = threadIdx.x & 63;
    float acc = b2[lane] + b2[64 + lane] + b2[128 + lane];
    int oc = *ov_cnt;
    if (oc > OVCAP) oc = OVCAP;
#pragma unroll
    for (int r = 0; r < R_REL; r++) {
        const unsigned short* tab = xwb + r * 64 + lane;
        int bin = r * N_NODES + w;
        int n = cnt_in[bin];
        int nn = n < BCAP ? n : BCAP;
        float a = 0.f;
        int j = 0;
        for (; j + 4 <= nn; j += 4) {
            uint4 s4 = *(const uint4*)&bucket[bin * BCAP + j];
            float v0 = bf2f(tab[s4.x * 192]);
            float v1 = bf2f(tab[s4.y * 192]);
            float v2 = bf2f(tab[s4.z * 192]);
            float v3 = bf2f(tab[s4.w * 192]);
            a += v0 + v1 + v2 + v3;
        }
        for (; j < nn; j++) {
            unsigned int s = (unsigned int)bucket[bin * BCAP + j];
            a += bf2f(tab[s * 192]);
        }
        if (oc > 0) {
            for (int k = 0; k < oc; k++) {
                uint2 e = ovlist[k];
                if ((int)e.x == bin) a += bf2f(tab[e.y * 192]);
            }
        }
        acc += norm_in[bin] * a;
    }
    h2b[w * 64 + lane] = f2bf(acc);
}

// ---------------- predictor (bf16 h2) ----------------
__global__ __launch_bounds__(256) void k_predict(const int* __restrict__ sa,
                                                 const int* __restrict__ sb,
                                                 const int* __restrict__ na,
                                                 const int* __restrict__ nb,
                                                 const unsigned short* __restrict__ h2b,
                                                 float* __restrict__ out) {
    int tid = blockIdx.x * 256 + threadIdx.x;
    int p = tid >> 4;
    if (p >= 2 * E_EDGES) return;
    int lane = tid & 15;
    int ia, ib;
    if (p < E_EDGES) { ia = sa[p]; ib = sb[p]; }
    else             { ia = na[p - E_EDGES]; ib = nb[p - E_EDGES]; }
    uint2 ua = *(const uint2*)&h2b[ia * 64 + lane * 4];
    uint2 ub = *(const uint2*)&h2b[ib * 64 + lane * 4];
    float d = bf_lo(ua.x) * bf_lo(ub.x) + bf_hi(ua.x) * bf_hi(ub.x)
            + bf_lo(ua.y) * bf_lo(ub.y) + bf_hi(ua.y) * bf_hi(ub.y);
    d += __shfl_xor(d, 1);
    d += __shfl_xor(d, 2);
    d += __shfl_xor(d, 4);
    d += __shfl_xor(d, 8);
    if (lane == 0) out[p] = d;
}

// ---------------- launch ----------------

extern "C" void kernel_launch(void* const* d_in, const int* in_sizes, int n_in,
                              void* d_out, int out_size, void* d_ws, size_t ws_size,
                              hipStream_t stream) {
    (void)in_sizes; (void)n_in; (void)out_size; (void)ws_size;
    const float* x       = (const float*)d_in[0];
    const int*   src     = (const int*)d_in[1];
    const int*   dst     = (const int*)d_in[2];
    const int*   neg_src = (const int*)d_in[3];
    const int*   neg_dst = (const int*)d_in[4];
    const float* W1      = (const float*)d_in[5];
    const float* b1      = (const float*)d_in[6];
    const float* W2      = (const float*)d_in[7];
    const float* b2      = (const float*)d_in[8];
    float* out = (float*)d_out;
    float* ws  = (float*)d_ws;

    // float-offset layout (total 22,282,064 floats = 89.1 MB; >=96.8 MB proven):
    // 0        : norm_out [150000]   150000: norm_in [150000]
    // 300000   : deg_out int [150000]  450000: cnt_in int [150000]  600000: ov_cnt [16]
    // 600016   : ovlist uint2 [4096] = 8192 ints
    // 608208   : bucket int [150000*16 = 2.4M]
    // 3008208  : w1t_h [24576] 3032784: w1t_l [24576] 3057360: w2t_h [12288]
    // 3069648  : w2t_l [12288] 3081936: bsum [128]
    // 3082064  : agg [6.4M]      (alias: xwb2 bf16 4.8Mf late)
    // 9482064  : h1f [6.4M]      (alias: h2b bf16 1.6Mf late)
    // 15882064 : h1h [3.2M]
    // 19082064 : h1l [3.2M]      (alias: xb [3.2M] early; xb dead before mm1<2> writes h1l)
    float* norm_out = ws;
    float* norm_in  = ws + N_SCAN;
    int*   deg_out  = (int*)(ws + 300000);
    int*   cnt_in   = (int*)(ws + 450000);
    int*   ov_cnt   = (int*)(ws + 600000);
    uint2* ovlist   = (uint2*)(ws + 600016);
    int*   bucket   = (int*)(ws + 608208);
    unsigned short* w1t_h = (unsigned short*)(ws + 3008208);
    unsigned short* w1t_l = (unsigned short*)(ws + 3032784);
    unsigned short* w2t_h = (unsigned short*)(ws + 3057360);
    unsigned short* w2t_l = (unsigned short*)(ws + 3069648);
    float* bsum     = ws + 3081936;
    float* agg      = ws + 3082064;
    unsigned short* xwb2 = (unsigned short*)(ws + 3082064);
    float* h1f      = ws + 9482064;
    unsigned short* h2b  = (unsigned short*)(ws + 9482064);
    unsigned short* h1h  = (unsigned short*)(ws + 15882064);
    unsigned short* h1l  = (unsigned short*)(ws + 19082064);
    unsigned int*   xb   = (unsigned int*)(ws + 19082064);

    const int NB_CP   = (R_REL * E_EDGES + 255) / 256;   // 2344 (covers all prep ranges)
    const int NB_WAVE = (N_NODES * 64 + 255) / 256;      // 12500
    const int NB_MM   = (N_NODES + 63) / 64;             // 782

    // zero counters (deg_out, cnt_in, ov_cnt contiguous)
    k_zero_i32<<<(300016 + 255) / 256, 256, 0, stream>>>(deg_out, 300016);
    // fused count + bucket-scatter + prep
    k_count_prep<<<NB_CP, 256, 0, stream>>>(src, dst, x, W1, W2, b1,
                                            deg_out, cnt_in, ov_cnt, ovlist, bucket,
                                            xb, w1t_h, w1t_l, w2t_h, w2t_l, bsum);
    k_rednorm<<<(N_SCAN + 255) / 256, 256, 0, stream>>>(deg_out, cnt_in, norm_out, norm_in);

    // ---- layer 1: bucket agg (bf16 gather) then split-bf16 MFMA GEMM into h1 ----
    for (int r = 0; r < R_REL; r++) {
        k_agg128<<<NB_WAVE, 256, 0, stream>>>(cnt_in + r * N_NODES,
                                              bucket + r * N_NODES * BCAP,
                                              norm_out + r * N_NODES,
                                              norm_in + r * N_NODES,
                                              ov_cnt, ovlist, r * N_NODES, xb, agg);
        if (r == 0)
            k_mm1<0><<<NB_MM, 256, 0, stream>>>(agg, w1t_h, w1t_l, bsum, h1f, h1h, h1l, N_NODES);
        else if (r == 1)
            k_mm1<1><<<NB_MM, 256, 0, stream>>>(agg, w1t_h + 16384, w1t_l + 16384, bsum, h1f, h1h, h1l, N_NODES);
        else
            k_mm1<2><<<NB_MM, 256, 0, stream>>>(agg, w1t_h + 32768, w1t_l + 32768, bsum, h1f, h1h, h1l, N_NODES);
    }

    // ---- layer 2: GEMM [N,128]@[128,192] -> bf16 (norm_out folded), then aggregation ----
    k_mm2<<<NB_MM, 256, 0, stream>>>(h1h, h1l, w2t_h, w2t_l, norm_out, xwb2, N_NODES);
    k_agg64f<<<NB_WAVE, 256, 0, stream>>>(cnt_in, bucket, norm_in, ov_cnt, ovlist,
                                          xwb2, b2, h2b);

    // ---- predictor ----
    k_predict<<<(2 * E_EDGES * 16 + 255) / 256, 256, 0, stream>>>(
        src, dst, neg_src, neg_dst, h2b, out);
}

// Round 8
// 259.489 us; speedup vs baseline: 6.8391x; 1.0491x over previous
//
#include <hip/hip_runtime.h>

#define N_NODES 50000
#define E_EDGES 200000
#define R_REL 3
#define D_IN 128
#define D_HID 128
#define D_OUT 64
#define N_SCAN (R_REL * N_NODES)          // 150000
#define BCAP 16
#define OVCAP 4096
#define NBE 2344                          // edge blocks (600000/256)
#define NBP 1563                          // prep blocks (400128/256)

typedef __attribute__((ext_vector_type(8))) short bf16x8;
typedef __attribute__((ext_vector_type(4))) float f32x4;

__device__ inline unsigned short f2bf(float v) {
    union { float f; unsigned int u; } x; x.f = v;
    unsigned int r = x.u + 0x7fffu + ((x.u >> 16) & 1u);
    return (unsigned short)(r >> 16);
}
__device__ inline float bf2f(unsigned short h) {
    union { unsigned int u; float f; } x; x.u = ((unsigned int)h) << 16; return x.f;
}
__device__ inline float bf_lo(unsigned int p) {
    union { unsigned int u; float f; } x; x.u = p << 16; return x.f;
}
__device__ inline float bf_hi(unsigned int p) {
    union { unsigned int u; float f; } x; x.u = p & 0xffff0000u; return x.f;
}

// ---------------- zero counters ----------------
__global__ __launch_bounds__(256) void k_zero_i32(int* __restrict__ p, int n) {
    int i = blockIdx.x * 256 + threadIdx.x;
    if (i < n) p[i] = 0;
}

// ---------------- fused count/bucket + prep, role-split blocks ----------------
// 5-block groups: 3 edge blocks, 2 prep blocks -> atomic waves and streaming waves overlap.
__global__ __launch_bounds__(256) void k_count_prep(const int* __restrict__ src,
                                                    const int* __restrict__ dst,
                                                    const float* __restrict__ x,
                                                    const float* __restrict__ W1,
                                                    const float* __restrict__ W2,
                                                    const float* __restrict__ b1,
                                                    int* __restrict__ deg_out,
                                                    int* __restrict__ cnt_in,
                                                    int* __restrict__ ov_cnt,
                                                    uint2* __restrict__ ovlist,
                                                    int* __restrict__ bucket,
                                                    unsigned int* __restrict__ xb,
                                                    unsigned short* __restrict__ w1t_h,
                                                    unsigned short* __restrict__ w1t_l,
                                                    unsigned short* __restrict__ w2t_h,
                                                    unsigned short* __restrict__ w2t_l,
                                                    float* __restrict__ bsum) {
    int g = blockIdx.x / 5;
    int m = blockIdx.x % 5;
    int t = threadIdx.x;
    if (m < 3) {
        // ---- edge path: count + bucket scatter ----
        int eb = g * 3 + m;
        int i = eb * 256 + t;
        if (i >= R_REL * E_EDGES) return;
        int r = i / E_EDGES;
        int s = src[i];
        int d = dst[i];
        atomicAdd(&deg_out[r * N_NODES + s], 1);
        int bin = r * N_NODES + d;
        int pos = atomicAdd(&cnt_in[bin], 1);
        if (pos < BCAP) {
            bucket[bin * BCAP + pos] = s;
        } else {
            int oi = atomicAdd(ov_cnt, 1);
            if (oi < OVCAP) {
                uint2 e;
                e.x = (unsigned int)bin;
                e.y = (unsigned int)s;
                ovlist[oi] = e;
            }
        }
    } else {
        // ---- streaming prep path ----
        int pb = g * 2 + (m - 3);
        int i = pb * 256 + t;
        if (i < 400000) {
#pragma unroll
            for (int k = 0; k < 4; k++) {
                int q = i * 4 + k;
                float4 v = ((const float4*)x)[q];
                uint2 u;
                u.x = ((unsigned int)f2bf(v.y) << 16) | f2bf(v.x);
                u.y = ((unsigned int)f2bf(v.w) << 16) | f2bf(v.z);
                ((uint2*)xb)[q] = u;
            }
        }
        if (i < R_REL * D_IN * D_HID) {  // 49152
            int r = i >> 14;
            int kk = (i >> 7) & 127;
            int c = i & 127;
            float v = W1[i];
            unsigned short h = f2bf(v);
            unsigned short l = f2bf(v - bf2f(h));
            int o = r * 16384 + c * 128 + kk;
            w1t_h[o] = h;
            w1t_l[o] = l;
        }
        if (i < R_REL * D_HID * D_OUT) {  // 24576
            int r = i >> 13;
            int kk = (i >> 6) & 127;
            int cl = i & 63;
            float v = W2[i];
            unsigned short h = f2bf(v);
            unsigned short l = f2bf(v - bf2f(h));
            int o = (r * 64 + cl) * 128 + kk;
            w2t_h[o] = h;
            w2t_l[o] = l;
        }
        if (i < 128) bsum[i] = b1[i] + b1[128 + i] + b1[256 + i];
    }
}

// ---------------- norms from counts ----------------
__global__ __launch_bounds__(256) void k_rednorm(const int* __restrict__ deg_out,
                                                 const int* __restrict__ cnt_in,
                                                 float* __restrict__ norm_out,
                                                 float* __restrict__ norm_in) {
    int b = blockIdx.x * 256 + threadIdx.x;
    if (b >= N_SCAN) return;
    int o = deg_out[b];
    int d = cnt_in[b];
    norm_out[b] = rsqrtf((float)(o > 1 ? o : 1));
    norm_in[b] = rsqrtf((float)(d > 1 ? d : 1));
}

// ---------------- layer-1 aggregation, all relations, bf16-hi output ----------------
// grid (12500, 3); one wave per (node, relation). Full bucket prefetch (16 slots).
__global__ __launch_bounds__(256) void k_aggall(const int* __restrict__ cnt_in,
                                                const int* __restrict__ bucket,
                                                const float* __restrict__ norm_out,
                                                const float* __restrict__ norm_in,
                                                const int* __restrict__ ov_cnt,
                                                const uint2* __restrict__ ovlist,
                                                const unsigned int* __restrict__ xb,
                                                unsigned int* __restrict__ aggh) {
    int w = (blockIdx.x * 256 + threadIdx.x) >> 6;
    if (w >= N_NODES) return;
    int r = blockIdx.y;
    int lane = threadIdx.x & 63;
    const unsigned int* tab = xb + lane;
    const float* nout = norm_out + r * N_NODES;
    int bin = r * N_NODES + w;
    int n = cnt_in[bin];
    const uint4* bp = (const uint4*)(bucket + bin * BCAP);
    uint4 q0 = bp[0], q1 = bp[1], q2 = bp[2], q3 = bp[3];
    unsigned int sl[16] = {q0.x, q0.y, q0.z, q0.w, q1.x, q1.y, q1.z, q1.w,
                           q2.x, q2.y, q2.z, q2.w, q3.x, q3.y, q3.z, q3.w};
    int nn = n < BCAP ? n : BCAP;
    float ax = 0.f, ay = 0.f;
#pragma unroll
    for (int j = 0; j < BCAP; j++) {
        if (j < nn) {
            unsigned int s = sl[j];
            float c = nout[s];
            unsigned int p = tab[s * 64];
            ax += c * bf_lo(p);
            ay += c * bf_hi(p);
        }
    }
    int oc = *ov_cnt;
    if (oc > 0) {
        if (oc > OVCAP) oc = OVCAP;
        for (int k = 0; k < oc; k++) {
            uint2 e = ovlist[k];
            if ((int)e.x == bin) {
                float c = nout[e.y];
                unsigned int p = tab[e.y * 64];
                ax += c * bf_lo(p);
                ay += c * bf_hi(p);
            }
        }
    }
    float ni = norm_in[bin];
    unsigned int o = ((unsigned int)f2bf(ay * ni) << 16) | f2bf(ax * ni);
    aggh[bin * 64 + lane] = o;
}

// ---------------- layer-1 GEMM: h1 = relu([A0|A1|A2](N,384) @ W1cat(384,128) + bsum) ----------------
// A is bf16 (hi-only); W split hi/lo. 64-row tile, 4 waves (2x2), 12 K-steps.
__global__ __launch_bounds__(256) void k_mm1f(const unsigned short* __restrict__ aggh,
                                              const unsigned short* __restrict__ wt_h,
                                              const unsigned short* __restrict__ wt_l,
                                              const float* __restrict__ bsum,
                                              unsigned short* __restrict__ h1h,
                                              unsigned short* __restrict__ h1l,
                                              int M) {
    __shared__ short sA[2048];                 // [4 kg][64 row][8]
    __shared__ short sWh[4096], sWl[4096];     // [4 kg][128 col][8]
    int t = threadIdx.x;
    int row0 = blockIdx.x * 64;
    int wid = t >> 6;
    int lane = t & 63;
    int lr = lane & 15;
    int lkg = lane >> 4;
    int wr = (wid & 1) * 32;
    int wc = (wid >> 1) * 64;

    f32x4 acc[2][4];
#pragma unroll
    for (int i = 0; i < 2; i++)
#pragma unroll
        for (int j = 0; j < 4; j++) acc[i][j] = (f32x4)(0.f);

    int arow = t >> 2;       // 0..63
    int akg = t & 3;         // 0..3

    for (int k0 = 0; k0 < 384; k0 += 32) {
        int rr = k0 >> 7;
        int kk = k0 & 127;
        {
            int gr = row0 + arow;
            int cidx = akg * 64 + arow;
            if (gr < M)
                *(bf16x8*)&sA[cidx * 8] =
                    *(const bf16x8*)&aggh[(rr * N_NODES + gr) * 128 + kk + akg * 8];
            else
                *(bf16x8*)&sA[cidx * 8] = (bf16x8)(short)0;
        }
#pragma unroll
        for (int itr = 0; itr < 2; itr++) {
            int cc = t + itr * 256;       // 0..511
            int col = cc >> 2;            // 0..127
            int kg = cc & 3;
            int go = rr * 16384 + col * 128 + kk + kg * 8;
            int cidx = kg * 128 + col;
            *(bf16x8*)&sWh[cidx * 8] = *(const bf16x8*)&wt_h[go];
            *(bf16x8*)&sWl[cidx * 8] = *(const bf16x8*)&wt_l[go];
        }
        __syncthreads();
        bf16x8 a[2], bh[4], bl[4];
#pragma unroll
        for (int i = 0; i < 2; i++) {
            int cidx = lkg * 64 + wr + i * 16 + lr;
            a[i] = *(const bf16x8*)&sA[cidx * 8];
        }
#pragma unroll
        for (int j = 0; j < 4; j++) {
            int cidx = lkg * 128 + wc + j * 16 + lr;
            bh[j] = *(const bf16x8*)&sWh[cidx * 8];
            bl[j] = *(const bf16x8*)&sWl[cidx * 8];
        }
#pragma unroll
        for (int i = 0; i < 2; i++)
#pragma unroll
            for (int j = 0; j < 4; j++) {
                acc[i][j] = __builtin_amdgcn_mfma_f32_16x16x32_bf16(a[i], bh[j], acc[i][j], 0, 0, 0);
                acc[i][j] = __builtin_amdgcn_mfma_f32_16x16x32_bf16(a[i], bl[j], acc[i][j], 0, 0, 0);
            }
        __syncthreads();
    }
#pragma unroll
    for (int i = 0; i < 2; i++)
#pragma unroll
        for (int q = 0; q < 4; q++) {
            int gr = row0 + wr + i * 16 + lkg * 4 + q;
            if (gr >= M) continue;
#pragma unroll
            for (int j = 0; j < 4; j++) {
                int gc = wc + j * 16 + lr;
                float u = fmaxf(acc[i][j][q] + bsum[gc], 0.f);
                unsigned short h = f2bf(u);
                h1h[gr * 128 + gc] = h;
                h1l[gr * 128 + gc] = f2bf(u - bf2f(h));
            }
        }
}

// ---------------- MFMA split-bf16 GEMM, layer 2 (bf16 out, norm_out folded) ----------------
__global__ __launch_bounds__(256) void k_mm2(const unsigned short* __restrict__ h1h,
                                             const unsigned short* __restrict__ h1l,
                                             const unsigned short* __restrict__ wt_h,
                                             const unsigned short* __restrict__ wt_l,
                                             const float* __restrict__ norm_out,
                                             unsigned short* __restrict__ xwb2, int M) {
    __shared__ short sAh[2048], sAl[2048];
    __shared__ short sWh[6144], sWl[6144];
    int t = threadIdx.x;
    int row0 = blockIdx.x * 64;
    int wid = t >> 6;
    int lane = t & 63;
    int lr = lane & 15;
    int lkg = lane >> 4;
    int wr = (wid & 1) * 32;
    int wc = (wid >> 1) * 96;

    f32x4 acc[2][6];
#pragma unroll
    for (int i = 0; i < 2; i++)
#pragma unroll
        for (int j = 0; j < 6; j++) acc[i][j] = (f32x4)(0.f);

    int arow = t >> 2;
    int akg = t & 3;

    for (int k0 = 0; k0 < 128; k0 += 32) {
        {
            int gr = row0 + arow;
            int cidx = akg * 64 + arow;
            if (gr < M) {
                int go = gr * 128 + k0 + akg * 8;
                *(bf16x8*)&sAh[cidx * 8] = *(const bf16x8*)&h1h[go];
                *(bf16x8*)&sAl[cidx * 8] = *(const bf16x8*)&h1l[go];
            } else {
                *(bf16x8*)&sAh[cidx * 8] = (bf16x8)(short)0;
                *(bf16x8*)&sAl[cidx * 8] = (bf16x8)(short)0;
            }
        }
#pragma unroll
        for (int itr = 0; itr < 3; itr++) {
            int cc = t + itr * 256;       // 0..767
            int col = cc >> 2;
            int kg = cc & 3;
            int go = col * 128 + k0 + kg * 8;
            int cidx = kg * 192 + col;
            *(bf16x8*)&sWh[cidx * 8] = *(const bf16x8*)&wt_h[go];
            *(bf16x8*)&sWl[cidx * 8] = *(const bf16x8*)&wt_l[go];
        }
        __syncthreads();
        bf16x8 ah[2], al[2];
#pragma unroll
        for (int i = 0; i < 2; i++) {
            int cidx = lkg * 64 + wr + i * 16 + lr;
            ah[i] = *(const bf16x8*)&sAh[cidx * 8];
            al[i] = *(const bf16x8*)&sAl[cidx * 8];
        }
#pragma unroll
        for (int j = 0; j < 6; j++) {
            int cidx = lkg * 192 + wc + j * 16 + lr;
            bf16x8 bh = *(const bf16x8*)&sWh[cidx * 8];
            bf16x8 bl = *(const bf16x8*)&sWl[cidx * 8];
#pragma unroll
            for (int i = 0; i < 2; i++) {
                acc[i][j] = __builtin_amdgcn_mfma_f32_16x16x32_bf16(ah[i], bh, acc[i][j], 0, 0, 0);
                acc[i][j] = __builtin_amdgcn_mfma_f32_16x16x32_bf16(ah[i], bl, acc[i][j], 0, 0, 0);
                acc[i][j] = __builtin_amdgcn_mfma_f32_16x16x32_bf16(al[i], bh, acc[i][j], 0, 0, 0);
            }
        }
        __syncthreads();
    }
#pragma unroll
    for (int i = 0; i < 2; i++)
#pragma unroll
        for (int q = 0; q < 4; q++) {
            int gr = row0 + wr + i * 16 + lkg * 4 + q;
            if (gr >= M) continue;
#pragma unroll
            for (int j = 0; j < 6; j++) {
                int gc = wc + j * 16 + lr;
                float sc = norm_out[(gc >> 6) * N_NODES + gr];
                xwb2[gr * 192 + gc] = f2bf(acc[i][j][q] * sc);
            }
        }
}

// ---------------- fused layer-2 aggregation (bf16 gather, bucket prefetch) ----------------
__global__ __launch_bounds__(256) void k_agg64f(const int* __restrict__ cnt_in,
                                                const int* __restrict__ bucket,
                                                const float* __restrict__ norm_in,
                                                const int* __restrict__ ov_cnt,
                                                const uint2* __restrict__ ovlist,
                                                const unsigned short* __restrict__ xwb,
                                                const float* __restrict__ b2,
                                                unsigned short* __restrict__ h2b) {
    int w = (blockIdx.x * 256 + threadIdx.x) >> 6;
    if (w >= N_NODES) return;
    int lane = threadIdx.x & 63;
    float acc = b2[lane] + b2[64 + lane] + b2[128 + lane];
    int oc = *ov_cnt;
    if (oc > OVCAP) oc = OVCAP;
#pragma unroll
    for (int r = 0; r < R_REL; r++) {
        const unsigned short* tab = xwb + r * 64 + lane;
        int bin = r * N_NODES + w;
        int n = cnt_in[bin];
        const uint4* bp = (const uint4*)(bucket + bin * BCAP);
        uint4 q0 = bp[0], q1 = bp[1], q2 = bp[2], q3 = bp[3];
        unsigned int sl[16] = {q0.x, q0.y, q0.z, q0.w, q1.x, q1.y, q1.z, q1.w,
                               q2.x, q2.y, q2.z, q2.w, q3.x, q3.y, q3.z, q3.w};
        int nn = n < BCAP ? n : BCAP;
        float a = 0.f;
#pragma unroll
        for (int j = 0; j < BCAP; j++) {
            if (j < nn) a += bf2f(tab[sl[j] * 192]);
        }
        if (oc > 0) {
            for (int k = 0; k < oc; k++) {
                uint2 e = ovlist[k];
                if ((int)e.x == bin) a += bf2f(tab[e.y * 192]);
            }
        }
        acc += norm_in[bin] * a;
    }
    h2b[w * 64 + lane] = f2bf(acc);
}

// ---------------- predictor (bf16 h2) ----------------
__global__ __launch_bounds__(256) void k_predict(const int* __restrict__ sa,
                                                 const int* __restrict__ sb,
                                                 const int* __restrict__ na,
                                                 const int* __restrict__ nb,
                                                 const unsigned short* __restrict__ h2b,
                                                 float* __restrict__ out) {
    int tid = blockIdx.x * 256 + threadIdx.x;
    int p = tid >> 4;
    if (p >= 2 * E_EDGES) return;
    int lane = tid & 15;
    int ia, ib;
    if (p < E_EDGES) { ia = sa[p]; ib = sb[p]; }
    else             { ia = na[p - E_EDGES]; ib = nb[p - E_EDGES]; }
    uint2 ua = *(const uint2*)&h2b[ia * 64 + lane * 4];
    uint2 ub = *(const uint2*)&h2b[ib * 64 + lane * 4];
    float d = bf_lo(ua.x) * bf_lo(ub.x) + bf_hi(ua.x) * bf_hi(ub.x)
            + bf_lo(ua.y) * bf_lo(ub.y) + bf_hi(ua.y) * bf_hi(ub.y);
    d += __shfl_xor(d, 1);
    d += __shfl_xor(d, 2);
    d += __shfl_xor(d, 4);
    d += __shfl_xor(d, 8);
    if (lane == 0) out[p] = d;
}

// ---------------- launch ----------------

extern "C" void kernel_launch(void* const* d_in, const int* in_sizes, int n_in,
                              void* d_out, int out_size, void* d_ws, size_t ws_size,
                              hipStream_t stream) {
    (void)in_sizes; (void)n_in; (void)out_size; (void)ws_size;
    const float* x       = (const float*)d_in[0];
    const int*   src     = (const int*)d_in[1];
    const int*   dst     = (const int*)d_in[2];
    const int*   neg_src = (const int*)d_in[3];
    const int*   neg_dst = (const int*)d_in[4];
    const float* W1      = (const float*)d_in[5];
    const float* b1      = (const float*)d_in[6];
    const float* W2      = (const float*)d_in[7];
    const float* b2      = (const float*)d_in[8];
    float* out = (float*)d_out;
    float* ws  = (float*)d_ws;

    // float-offset layout (total 19,082,064 floats = 76.3 MB; 96.8 MB proven):
    // 0        : norm_out [150000]   150000: norm_in [150000]
    // 300000   : deg_out int [150000]  450000: cnt_in [150000]  600000: ov_cnt [16]
    // 600016   : ovlist uint2 [4096] = 8192 ints
    // 608208   : bucket int [2.4M]
    // 3008208  : w1t_h [24576] 3032784: w1t_l [24576] 3057360: w2t_h [12288]
    // 3069648  : w2t_l [12288] 3081936: bsum [128]
    // 3082064  : aggh bf16 [3 planes, 9.6M floats]   (alias: xwb2 4.8M floats late)
    // 12682064 : h1h [3.2M]                          (alias: h2b 1.6M floats late)
    // 15882064 : h1l [3.2M]                          (alias: xb 3.2M early)
    float* norm_out = ws;
    float* norm_in  = ws + N_SCAN;
    int*   deg_out  = (int*)(ws + 300000);
    int*   cnt_in   = (int*)(ws + 450000);
    int*   ov_cnt   = (int*)(ws + 600000);
    uint2* ovlist   = (uint2*)(ws + 600016);
    int*   bucket   = (int*)(ws + 608208);
    unsigned short* w1t_h = (unsigned short*)(ws + 3008208);
    unsigned short* w1t_l = (unsigned short*)(ws + 3032784);
    unsigned short* w2t_h = (unsigned short*)(ws + 3057360);
    unsigned short* w2t_l = (unsigned short*)(ws + 3069648);
    float* bsum     = ws + 3081936;
    unsigned int*   aggh = (unsigned int*)(ws + 3082064);
    unsigned short* xwb2 = (unsigned short*)(ws + 3082064);
    unsigned short* h1h  = (unsigned short*)(ws + 12682064);
    unsigned short* h2b  = (unsigned short*)(ws + 12682064);
    unsigned short* h1l  = (unsigned short*)(ws + 15882064);
    unsigned int*   xb   = (unsigned int*)(ws + 15882064);

    const int NB_WAVE = (N_NODES * 64 + 255) / 256;      // 12500
    const int NB_MM   = (N_NODES + 63) / 64;             // 782

    // zero counters (deg_out, cnt_in, ov_cnt contiguous)
    k_zero_i32<<<(300016 + 255) / 256, 256, 0, stream>>>(deg_out, 300016);
    // fused count + bucket-scatter + prep (role-split, 782 groups of 5 blocks)
    k_count_prep<<<782 * 5, 256, 0, stream>>>(src, dst, x, W1, W2, b1,
                                              deg_out, cnt_in, ov_cnt, ovlist, bucket,
                                              xb, w1t_h, w1t_l, w2t_h, w2t_l, bsum);
    k_rednorm<<<(N_SCAN + 255) / 256, 256, 0, stream>>>(deg_out, cnt_in, norm_out, norm_in);

    // ---- layer 1: one aggregation kernel (3 planes) + one K=384 GEMM ----
    dim3 gagg(NB_WAVE, R_REL);
    k_aggall<<<gagg, 256, 0, stream>>>(cnt_in, bucket, norm_out, norm_in,
                                       ov_cnt, ovlist, xb, aggh);
    k_mm1f<<<NB_MM, 256, 0, stream>>>((const unsigned short*)aggh, w1t_h, w1t_l, bsum,
                                      h1h, h1l, N_NODES);

    // ---- layer 2: GEMM [N,128]@[128,192] -> bf16 (norm_out folded), then aggregation ----
    k_mm2<<<NB_MM, 256, 0, stream>>>(h1h, h1l, w2t_h, w2t_l, norm_out, xwb2, N_NODES);
    k_agg64f<<<NB_WAVE, 256, 0, stream>>>(cnt_in, bucket, norm_in, ov_cnt, ovlist,
                                          xwb2, b2, h2b);

    // ---- predictor ----
    k_predict<<<(2 * E_EDGES * 16 + 255) / 256, 256, 0, stream>>>(
        src, dst, neg_src, neg_dst, h2b, out);
}

// Round 9
// 250.286 us; speedup vs baseline: 7.0906x; 1.0368x over previous
//
#include <hip/hip_runtime.h>

#define N_NODES 50000
#define E_EDGES 200000
#define R_REL 3
#define D_IN 128
#define D_HID 128
#define D_OUT 64
#define N_SCAN (R_REL * N_NODES)          // 150000
#define BCAP 16
#define OVCAP 4096

typedef __attribute__((ext_vector_type(8))) short bf16x8;
typedef __attribute__((ext_vector_type(4))) float f32x4;

__device__ inline unsigned short f2bf(float v) {
    union { float f; unsigned int u; } x; x.f = v;
    unsigned int r = x.u + 0x7fffu + ((x.u >> 16) & 1u);
    return (unsigned short)(r >> 16);
}
__device__ inline float bf2f(unsigned short h) {
    union { unsigned int u; float f; } x; x.u = ((unsigned int)h) << 16; return x.f;
}
__device__ inline float bf_lo(unsigned int p) {
    union { unsigned int u; float f; } x; x.u = p << 16; return x.f;
}
__device__ inline float bf_hi(unsigned int p) {
    union { unsigned int u; float f; } x; x.u = p & 0xffff0000u; return x.f;
}

// ---------------- zero counters ----------------
__global__ __launch_bounds__(256) void k_zero_i32(int* __restrict__ p, int n) {
    int i = blockIdx.x * 256 + threadIdx.x;
    if (i < n) p[i] = 0;
}

// ---------------- fused count/bucket + prep, role-split blocks ----------------
// 5-block groups: 3 edge blocks, 2 prep blocks (atomic waves overlap streaming waves).
__global__ __launch_bounds__(256) void k_count_prep(const int* __restrict__ src,
                                                    const int* __restrict__ dst,
                                                    const float* __restrict__ x,
                                                    const float* __restrict__ W1,
                                                    const float* __restrict__ W2,
                                                    const float* __restrict__ b1,
                                                    int* __restrict__ deg_out,
                                                    int* __restrict__ cnt_in,
                                                    int* __restrict__ ov_cnt,
                                                    uint2* __restrict__ ovlist,
                                                    int* __restrict__ bucket,
                                                    unsigned int* __restrict__ xb,
                                                    unsigned short* __restrict__ w1t_h,
                                                    unsigned short* __restrict__ w1t_l,
                                                    unsigned short* __restrict__ w2t_h,
                                                    unsigned short* __restrict__ w2t_l,
                                                    float* __restrict__ bsum) {
    int g = blockIdx.x / 5;
    int m = blockIdx.x % 5;
    int t = threadIdx.x;
    if (m < 3) {
        // ---- edge path: count + bucket scatter ----
        int eb = g * 3 + m;
        int i = eb * 256 + t;
        if (i >= R_REL * E_EDGES) return;
        int r = i / E_EDGES;
        int s = src[i];
        int d = dst[i];
        atomicAdd(&deg_out[r * N_NODES + s], 1);
        int bin = r * N_NODES + d;
        int pos = atomicAdd(&cnt_in[bin], 1);
        if (pos < BCAP) {
            bucket[bin * BCAP + pos] = s;
        } else {
            int oi = atomicAdd(ov_cnt, 1);
            if (oi < OVCAP) {
                uint2 e;
                e.x = (unsigned int)bin;
                e.y = (unsigned int)s;
                ovlist[oi] = e;
            }
        }
    } else {
        // ---- streaming prep path (coalesced: 4 lane-consecutive passes) ----
        int pb = g * 2 + (m - 3);
        int qbase = pb * 1024;
#pragma unroll
        for (int k = 0; k < 4; k++) {
            int q = qbase + k * 256 + t;
            if (q < N_NODES * 32) {
                float4 v = ((const float4*)x)[q];
                uint2 u;
                u.x = ((unsigned int)f2bf(v.y) << 16) | f2bf(v.x);
                u.y = ((unsigned int)f2bf(v.w) << 16) | f2bf(v.z);
                ((uint2*)xb)[q] = u;
            }
        }
        int i = pb * 256 + t;
        if (i < R_REL * D_IN * D_HID) {  // 49152
            int r = i >> 14;
            int kk = (i >> 7) & 127;
            int c = i & 127;
            float v = W1[i];
            unsigned short h = f2bf(v);
            unsigned short l = f2bf(v - bf2f(h));
            int o = r * 16384 + c * 128 + kk;
            w1t_h[o] = h;
            w1t_l[o] = l;
        }
        if (i < R_REL * D_HID * D_OUT) {  // 24576
            int r = i >> 13;
            int kk = (i >> 6) & 127;
            int cl = i & 63;
            float v = W2[i];
            unsigned short h = f2bf(v);
            unsigned short l = f2bf(v - bf2f(h));
            int o = (r * 64 + cl) * 128 + kk;
            w2t_h[o] = h;
            w2t_l[o] = l;
        }
        if (i < 128) bsum[i] = b1[i] + b1[128 + i] + b1[256 + i];
    }
}

// ---------------- norms from counts ----------------
__global__ __launch_bounds__(256) void k_rednorm(const int* __restrict__ deg_out,
                                                 const int* __restrict__ cnt_in,
                                                 float* __restrict__ norm_out,
                                                 float* __restrict__ norm_in) {
    int b = blockIdx.x * 256 + threadIdx.x;
    if (b >= N_SCAN) return;
    int o = deg_out[b];
    int d = cnt_in[b];
    norm_out[b] = rsqrtf((float)(o > 1 ? o : 1));
    norm_in[b] = rsqrtf((float)(d > 1 ? d : 1));
}

// ---------------- layer-1 aggregation: one wave per node, 3 relations ----------------
// Two-phase per relation: issue all slot gathers (pure loads) then consume (FMA).
__global__ __launch_bounds__(256) void k_aggall(const int* __restrict__ cnt_in,
                                                const int* __restrict__ bucket,
                                                const float* __restrict__ norm_out,
                                                const float* __restrict__ norm_in,
                                                const int* __restrict__ ov_cnt,
                                                const uint2* __restrict__ ovlist,
                                                const unsigned int* __restrict__ xb,
                                                unsigned int* __restrict__ aggh) {
    int w = (blockIdx.x * 256 + threadIdx.x) >> 6;
    if (w >= N_NODES) return;
    int lane = threadIdx.x & 63;
    const unsigned int* tab = xb + lane;
    int nn[R_REL];
    uint4 q[R_REL][4];
#pragma unroll
    for (int r = 0; r < R_REL; r++) {
        int bin = r * N_NODES + w;
        int n = cnt_in[bin];
        nn[r] = n < BCAP ? n : BCAP;
        const uint4* bp = (const uint4*)(bucket + bin * BCAP);
        q[r][0] = bp[0]; q[r][1] = bp[1]; q[r][2] = bp[2]; q[r][3] = bp[3];
    }
    int oc = *ov_cnt;
    if (oc > OVCAP) oc = OVCAP;
#pragma unroll
    for (int r = 0; r < R_REL; r++) {
        const float* nout = norm_out + r * N_NODES;
        unsigned int sl[BCAP] = {q[r][0].x, q[r][0].y, q[r][0].z, q[r][0].w,
                                 q[r][1].x, q[r][1].y, q[r][1].z, q[r][1].w,
                                 q[r][2].x, q[r][2].y, q[r][2].z, q[r][2].w,
                                 q[r][3].x, q[r][3].y, q[r][3].z, q[r][3].w};
        unsigned int p[BCAP];
        float c[BCAP];
        // phase 1: issue all gathers
#pragma unroll
        for (int j = 0; j < BCAP; j++) {
            if (j < nn[r]) {
                c[j] = nout[sl[j]];
                p[j] = tab[sl[j] * 64];
            }
        }
        // phase 2: consume
        float ax = 0.f, ay = 0.f;
#pragma unroll
        for (int j = 0; j < BCAP; j++) {
            if (j < nn[r]) {
                ax += c[j] * bf_lo(p[j]);
                ay += c[j] * bf_hi(p[j]);
            }
        }
        int bin = r * N_NODES + w;
        if (oc > 0) {
            for (int k = 0; k < oc; k++) {
                uint2 e = ovlist[k];
                if ((int)e.x == bin) {
                    float cc = nout[e.y];
                    unsigned int pp = tab[e.y * 64];
                    ax += cc * bf_lo(pp);
                    ay += cc * bf_hi(pp);
                }
            }
        }
        float ni = norm_in[bin];
        aggh[bin * 64 + lane] = ((unsigned int)f2bf(ay * ni) << 16) | f2bf(ax * ni);
    }
}

// ---------------- layer-1 GEMM: h1 = relu([A0|A1|A2](N,384) @ W1cat(384,128) + bsum) ----------------
__global__ __launch_bounds__(256) void k_mm1f(const unsigned short* __restrict__ aggh,
                                              const unsigned short* __restrict__ wt_h,
                                              const unsigned short* __restrict__ wt_l,
                                              const float* __restrict__ bsum,
                                              unsigned short* __restrict__ h1h,
                                              unsigned short* __restrict__ h1l,
                                              int M) {
    __shared__ short sA[2048];                 // [4 kg][64 row][8]
    __shared__ short sWh[4096], sWl[4096];     // [4 kg][128 col][8]
    int t = threadIdx.x;
    int row0 = blockIdx.x * 64;
    int wid = t >> 6;
    int lane = t & 63;
    int lr = lane & 15;
    int lkg = lane >> 4;
    int wr = (wid & 1) * 32;
    int wc = (wid >> 1) * 64;

    f32x4 acc[2][4];
#pragma unroll
    for (int i = 0; i < 2; i++)
#pragma unroll
        for (int j = 0; j < 4; j++) acc[i][j] = (f32x4)(0.f);

    int arow = t >> 2;       // 0..63
    int akg = t & 3;         // 0..3

    for (int k0 = 0; k0 < 384; k0 += 32) {
        int rr = k0 >> 7;
        int kk = k0 & 127;
        {
            int gr = row0 + arow;
            int cidx = akg * 64 + arow;
            if (gr < M)
                *(bf16x8*)&sA[cidx * 8] =
                    *(const bf16x8*)&aggh[(rr * N_NODES + gr) * 128 + kk + akg * 8];
            else
                *(bf16x8*)&sA[cidx * 8] = (bf16x8)(short)0;
        }
#pragma unroll
        for (int itr = 0; itr < 2; itr++) {
            int cc = t + itr * 256;       // 0..511
            int col = cc >> 2;            // 0..127
            int kg = cc & 3;
            int go = rr * 16384 + col * 128 + kk + kg * 8;
            int cidx = kg * 128 + col;
            *(bf16x8*)&sWh[cidx * 8] = *(const bf16x8*)&wt_h[go];
            *(bf16x8*)&sWl[cidx * 8] = *(const bf16x8*)&wt_l[go];
        }
        __syncthreads();
        bf16x8 a[2], bh[4], bl[4];
#pragma unroll
        for (int i = 0; i < 2; i++) {
            int cidx = lkg * 64 + wr + i * 16 + lr;
            a[i] = *(const bf16x8*)&sA[cidx * 8];
        }
#pragma unroll
        for (int j = 0; j < 4; j++) {
            int cidx = lkg * 128 + wc + j * 16 + lr;
            bh[j] = *(const bf16x8*)&sWh[cidx * 8];
            bl[j] = *(const bf16x8*)&sWl[cidx * 8];
        }
#pragma unroll
        for (int i = 0; i < 2; i++)
#pragma unroll
            for (int j = 0; j < 4; j++) {
                acc[i][j] = __builtin_amdgcn_mfma_f32_16x16x32_bf16(a[i], bh[j], acc[i][j], 0, 0, 0);
                acc[i][j] = __builtin_amdgcn_mfma_f32_16x16x32_bf16(a[i], bl[j], acc[i][j], 0, 0, 0);
            }
        __syncthreads();
    }
#pragma unroll
    for (int i = 0; i < 2; i++)
#pragma unroll
        for (int q = 0; q < 4; q++) {
            int gr = row0 + wr + i * 16 + lkg * 4 + q;
            if (gr >= M) continue;
#pragma unroll
            for (int j = 0; j < 4; j++) {
                int gc = wc + j * 16 + lr;
                float u = fmaxf(acc[i][j][q] + bsum[gc], 0.f);
                unsigned short h = f2bf(u);
                h1h[gr * 128 + gc] = h;
                h1l[gr * 128 + gc] = f2bf(u - bf2f(h));
            }
        }
}

// ---------------- MFMA split-bf16 GEMM, layer 2 (bf16 out, norm_out folded) ----------------
__global__ __launch_bounds__(256) void k_mm2(const unsigned short* __restrict__ h1h,
                                             const unsigned short* __restrict__ h1l,
                                             const unsigned short* __restrict__ wt_h,
                                             const unsigned short* __restrict__ wt_l,
                                             const float* __restrict__ norm_out,
                                             unsigned short* __restrict__ xwb2, int M) {
    __shared__ short sAh[2048], sAl[2048];
    __shared__ short sWh[6144], sWl[6144];
    int t = threadIdx.x;
    int row0 = blockIdx.x * 64;
    int wid = t >> 6;
    int lane = t & 63;
    int lr = lane & 15;
    int lkg = lane >> 4;
    int wr = (wid & 1) * 32;
    int wc = (wid >> 1) * 96;

    f32x4 acc[2][6];
#pragma unroll
    for (int i = 0; i < 2; i++)
#pragma unroll
        for (int j = 0; j < 6; j++) acc[i][j] = (f32x4)(0.f);

    int arow = t >> 2;
    int akg = t & 3;

    for (int k0 = 0; k0 < 128; k0 += 32) {
        {
            int gr = row0 + arow;
            int cidx = akg * 64 + arow;
            if (gr < M) {
                int go = gr * 128 + k0 + akg * 8;
                *(bf16x8*)&sAh[cidx * 8] = *(const bf16x8*)&h1h[go];
                *(bf16x8*)&sAl[cidx * 8] = *(const bf16x8*)&h1l[go];
            } else {
                *(bf16x8*)&sAh[cidx * 8] = (bf16x8)(short)0;
                *(bf16x8*)&sAl[cidx * 8] = (bf16x8)(short)0;
            }
        }
#pragma unroll
        for (int itr = 0; itr < 3; itr++) {
            int cc = t + itr * 256;       // 0..767
            int col = cc >> 2;
            int kg = cc & 3;
            int go = col * 128 + k0 + kg * 8;
            int cidx = kg * 192 + col;
            *(bf16x8*)&sWh[cidx * 8] = *(const bf16x8*)&wt_h[go];
            *(bf16x8*)&sWl[cidx * 8] = *(const bf16x8*)&wt_l[go];
        }
        __syncthreads();
        bf16x8 ah[2], al[2];
#pragma unroll
        for (int i = 0; i < 2; i++) {
            int cidx = lkg * 64 + wr + i * 16 + lr;
            ah[i] = *(const bf16x8*)&sAh[cidx * 8];
            al[i] = *(const bf16x8*)&sAl[cidx * 8];
        }
#pragma unroll
        for (int j = 0; j < 6; j++) {
            int cidx = lkg * 192 + wc + j * 16 + lr;
            bf16x8 bh = *(const bf16x8*)&sWh[cidx * 8];
            bf16x8 bl = *(const bf16x8*)&sWl[cidx * 8];
#pragma unroll
            for (int i = 0; i < 2; i++) {
                acc[i][j] = __builtin_amdgcn_mfma_f32_16x16x32_bf16(ah[i], bh, acc[i][j], 0, 0, 0);
                acc[i][j] = __builtin_amdgcn_mfma_f32_16x16x32_bf16(ah[i], bl, acc[i][j], 0, 0, 0);
                acc[i][j] = __builtin_amdgcn_mfma_f32_16x16x32_bf16(al[i], bh, acc[i][j], 0, 0, 0);
            }
        }
        __syncthreads();
    }
#pragma unroll
    for (int i = 0; i < 2; i++)
#pragma unroll
        for (int q = 0; q < 4; q++) {
            int gr = row0 + wr + i * 16 + lkg * 4 + q;
            if (gr >= M) continue;
#pragma unroll
            for (int j = 0; j < 6; j++) {
                int gc = wc + j * 16 + lr;
                float sc = norm_out[(gc >> 6) * N_NODES + gr];
                xwb2[gr * 192 + gc] = f2bf(acc[i][j][q] * sc);
            }
        }
}

// ---------------- fused layer-2 aggregation (two-phase staged gather) ----------------
__global__ __launch_bounds__(256) void k_agg64f(const int* __restrict__ cnt_in,
                                                const int* __restrict__ bucket,
                                                const float* __restrict__ norm_in,
                                                const int* __restrict__ ov_cnt,
                                                const uint2* __restrict__ ovlist,
                                                const unsigned short* __restrict__ xwb,
                                                const float* __restrict__ b2,
                                                unsigned short* __restrict__ h2b) {
    int w = (blockIdx.x * 256 + threadIdx.x) >> 6;
    if (w >= N_NODES) return;
    int lane = threadIdx.x & 63;
    float acc = b2[lane] + b2[64 + lane] + b2[128 + lane];
    int oc = *ov_cnt;
    if (oc > OVCAP) oc = OVCAP;
#pragma unroll
    for (int r = 0; r < R_REL; r++) {
        const unsigned short* tab = xwb + r * 64 + lane;
        int bin = r * N_NODES + w;
        int n = cnt_in[bin];
        const uint4* bp = (const uint4*)(bucket + bin * BCAP);
        uint4 q0 = bp[0], q1 = bp[1], q2 = bp[2], q3 = bp[3];
        unsigned int sl[BCAP] = {q0.x, q0.y, q0.z, q0.w, q1.x, q1.y, q1.z, q1.w,
                                 q2.x, q2.y, q2.z, q2.w, q3.x, q3.y, q3.z, q3.w};
        int nn = n < BCAP ? n : BCAP;
        unsigned int pv[BCAP];
        // phase 1: issue all gathers
#pragma unroll
        for (int j = 0; j < BCAP; j++) {
            if (j < nn) pv[j] = tab[sl[j] * 192];
        }
        // phase 2: consume
        float a = 0.f;
#pragma unroll
        for (int j = 0; j < BCAP; j++) {
            if (j < nn) a += bf2f((unsigned short)pv[j]);
        }
        if (oc > 0) {
            for (int k = 0; k < oc; k++) {
                uint2 e = ovlist[k];
                if ((int)e.x == bin) a += bf2f(tab[e.y * 192]);
            }
        }
        acc += norm_in[bin] * a;
    }
    h2b[w * 64 + lane] = f2bf(acc);
}

// ---------------- predictor (bf16 h2) ----------------
__global__ __launch_bounds__(256) void k_predict(const int* __restrict__ sa,
                                                 const int* __restrict__ sb,
                                                 const int* __restrict__ na,
                                                 const int* __restrict__ nb,
                                                 const unsigned short* __restrict__ h2b,
                                                 float* __restrict__ out) {
    int tid = blockIdx.x * 256 + threadIdx.x;
    int p = tid >> 4;
    if (p >= 2 * E_EDGES) return;
    int lane = tid & 15;
    int ia, ib;
    if (p < E_EDGES) { ia = sa[p]; ib = sb[p]; }
    else             { ia = na[p - E_EDGES]; ib = nb[p - E_EDGES]; }
    uint2 ua = *(const uint2*)&h2b[ia * 64 + lane * 4];
    uint2 ub = *(const uint2*)&h2b[ib * 64 + lane * 4];
    float d = bf_lo(ua.x) * bf_lo(ub.x) + bf_hi(ua.x) * bf_hi(ub.x)
            + bf_lo(ua.y) * bf_lo(ub.y) + bf_hi(ua.y) * bf_hi(ub.y);
    d += __shfl_xor(d, 1);
    d += __shfl_xor(d, 2);
    d += __shfl_xor(d, 4);
    d += __shfl_xor(d, 8);
    if (lane == 0) out[p] = d;
}

// ---------------- launch ----------------

extern "C" void kernel_launch(void* const* d_in, const int* in_sizes, int n_in,
                              void* d_out, int out_size, void* d_ws, size_t ws_size,
                              hipStream_t stream) {
    (void)in_sizes; (void)n_in; (void)out_size; (void)ws_size;
    const float* x       = (const float*)d_in[0];
    const int*   src     = (const int*)d_in[1];
    const int*   dst     = (const int*)d_in[2];
    const int*   neg_src = (const int*)d_in[3];
    const int*   neg_dst = (const int*)d_in[4];
    const float* W1      = (const float*)d_in[5];
    const float* b1      = (const float*)d_in[6];
    const float* W2      = (const float*)d_in[7];
    const float* b2      = (const float*)d_in[8];
    float* out = (float*)d_out;
    float* ws  = (float*)d_ws;

    // float-offset layout (total 19,082,064 floats = 76.3 MB; 96.8 MB proven):
    // 0        : norm_out [150000]   150000: norm_in [150000]
    // 300000   : deg_out int [150000]  450000: cnt_in [150000]  600000: ov_cnt [16]
    // 600016   : ovlist uint2 [4096] = 8192 ints
    // 608208   : bucket int [2.4M]
    // 3008208  : w1t_h [24576] 3032784: w1t_l [24576] 3057360: w2t_h [12288]
    // 3069648  : w2t_l [12288] 3081936: bsum [128]
    // 3082064  : aggh bf16 [3 planes, 9.6M floats]   (alias: xwb2 4.8M floats late)
    // 12682064 : h1h [3.2M]                          (alias: h2b 1.6M floats late)
    // 15882064 : h1l [3.2M]                          (alias: xb 3.2M early)
    float* norm_out = ws;
    float* norm_in  = ws + N_SCAN;
    int*   deg_out  = (int*)(ws + 300000);
    int*   cnt_in   = (int*)(ws + 450000);
    int*   ov_cnt   = (int*)(ws + 600000);
    uint2* ovlist   = (uint2*)(ws + 600016);
    int*   bucket   = (int*)(ws + 608208);
    unsigned short* w1t_h = (unsigned short*)(ws + 3008208);
    unsigned short* w1t_l = (unsigned short*)(ws + 3032784);
    unsigned short* w2t_h = (unsigned short*)(ws + 3057360);
    unsigned short* w2t_l = (unsigned short*)(ws + 3069648);
    float* bsum     = ws + 3081936;
    unsigned int*   aggh = (unsigned int*)(ws + 3082064);
    unsigned short* xwb2 = (unsigned short*)(ws + 3082064);
    unsigned short* h1h  = (unsigned short*)(ws + 12682064);
    unsigned short* h2b  = (unsigned short*)(ws + 12682064);
    unsigned short* h1l  = (unsigned short*)(ws + 15882064);
    unsigned int*   xb   = (unsigned int*)(ws + 15882064);

    const int NB_WAVE = (N_NODES * 64 + 255) / 256;      // 12500
    const int NB_MM   = (N_NODES + 63) / 64;             // 782

    // zero counters (deg_out, cnt_in, ov_cnt contiguous)
    k_zero_i32<<<(300016 + 255) / 256, 256, 0, stream>>>(deg_out, 300016);
    // fused count + bucket-scatter + prep (role-split, 782 groups of 5 blocks)
    k_count_prep<<<782 * 5, 256, 0, stream>>>(src, dst, x, W1, W2, b1,
                                              deg_out, cnt_in, ov_cnt, ovlist, bucket,
                                              xb, w1t_h, w1t_l, w2t_h, w2t_l, bsum);
    k_rednorm<<<(N_SCAN + 255) / 256, 256, 0, stream>>>(deg_out, cnt_in, norm_out, norm_in);

    // ---- layer 1: one aggregation kernel (1 wave/node, 3 planes) + one K=384 GEMM ----
    k_aggall<<<NB_WAVE, 256, 0, stream>>>(cnt_in, bucket, norm_out, norm_in,
                                          ov_cnt, ovlist, xb, aggh);
    k_mm1f<<<NB_MM, 256, 0, stream>>>((const unsigned short*)aggh, w1t_h, w1t_l, bsum,
                                      h1h, h1l, N_NODES);

    // ---- layer 2: GEMM [N,128]@[128,192] -> bf16 (norm_out folded), then aggregation ----
    k_mm2<<<NB_MM, 256, 0, stream>>>(h1h, h1l, w2t_h, w2t_l, norm_out, xwb2, N_NODES);
    k_agg64f<<<NB_WAVE, 256, 0, stream>>>(cnt_in, bucket, norm_in, ov_cnt, ovlist,
                                          xwb2, b2, h2b);

    // ---- predictor ----
    k_predict<<<(2 * E_EDGES * 16 + 255) / 256, 256, 0, stream>>>(
        src, dst, neg_src, neg_dst, h2b, out);
}